// Round 15
// baseline (600.029 us; speedup 1.0000x reference)
//
#include <hip/hip_runtime.h>
#include <hip/hip_bf16.h>

#define DI __device__ __forceinline__

DI float gelu_f(float x){ return 0.5f*x*(1.0f + erff(x*0.7071067811865476f)); }
DI float bf2f(__hip_bfloat16 b){ return __bfloat162float(b); }
DI __hip_bfloat16 f2bf(float f){ return __float2bfloat16(f); }
DI float bflo(unsigned u){ return __uint_as_float(u<<16); }
DI float bfhi(unsigned u){ return __uint_as_float(u & 0xffff0000u); }
DI unsigned pack2bf(float a, float b){
  __hip_bfloat16 ha = f2bf(a), hb = f2bf(b);
  unsigned short ua = *reinterpret_cast<unsigned short*>(&ha);
  unsigned short ub = *reinterpret_cast<unsigned short*>(&hb);
  return (unsigned)ua | ((unsigned)ub<<16);
}

typedef __attribute__((ext_vector_type(8))) short bf16x8;
typedef __attribute__((ext_vector_type(4))) float f32x4;

template<typename T>
DI void load_lds16(const T* g, T* l){
  __builtin_amdgcn_global_load_lds((const __attribute__((address_space(1))) void*)g,
                                   (__attribute__((address_space(3))) void*)l, 16, 0, 0);
}

DI int kvmap(int j){ int h=j>>5, idx=j&31; return idx<16 ? h*16+idx : 256+h*16+(idx-16); }

// ---------------- conv1: inp -> featP (4096 pix, 64 ch) bf16 pixel-major ----------------
__global__ __launch_bounds__(256) void k_conv1(const float* __restrict__ inp, const float* __restrict__ w,
                                               const float* __restrict__ b, __hip_bfloat16* __restrict__ featP){
  int idx = blockIdx.x*256 + threadIdx.x;
  int o = idx & 63, p = idx >> 6, y = p >> 6, x = p & 63;
  float acc = b[o];
  #pragma unroll
  for(int c=0;c<3;c++){
    #pragma unroll
    for(int ky=0;ky<3;ky++){
      int yy = y+ky-1; if((unsigned)yy >= 64u) continue;
      #pragma unroll
      for(int kx=0;kx<3;kx++){
        int xx = x+kx-1; if((unsigned)xx >= 64u) continue;
        acc += inp[c*4096 + yy*64 + xx] * w[o*27 + c*9 + ky*3 + kx];
      }
    }
  }
  featP[p*64 + o] = f2bf(acc);
}

// ---------------- wfreq permute: freq_w[256][576] -> wfreqT[256][640] ([o][tap*64+c]) ----------------
__global__ __launch_bounds__(256) void k_wfreq(const float* __restrict__ fw, __hip_bfloat16* __restrict__ wt){
  int o = blockIdx.x, t = threadIdx.x;
  #pragma unroll
  for(int it=0; it<3; it++){
    int k = it*256 + t;
    if(k >= 640) break;
    float v = 0.0f;
    if(k < 576){
      int tap = k>>6, c = k&63;
      v = fw[o*576 + c*9 + tap];
    }
    wt[(size_t)o*640 + k] = f2bf(v);
  }
}

// ---------------- wblkT ----------------
__global__ __launch_bounds__(256) void k_wblk(const float* __restrict__ w0, const float* __restrict__ w1,
                                              __hip_bfloat16* __restrict__ wt){
  int j = blockIdx.x, kk = threadIdx.x;
  float v;
  if(j < 1024){
    int s = j>>8, n = j&255;
    v = w0[(8 + 256*s + kk)*256 + n];
  } else {
    v = w1[(2 + kk)*256 + (j-1024)];
  }
  wt[(size_t)j*256 + kk] = f2bf(v);
}

// ---------------- batched weight transpose / qkv head-permute ----------------
struct PrepDesc { const float* src; __hip_bfloat16* dst; int mode; int pad; };
struct PrepArgs { PrepDesc d[13]; };
__global__ __launch_bounds__(256) void k_prep(PrepArgs a){
  int u = blockIdx.x >> 8, b = blockIdx.x & 255, t = threadIdx.x;
  PrepDesc d = a.d[u];
  float v;
  if(d.mode == 0) v = d.src[t*256 + b];
  else { int col = 48*(b>>4) + (d.mode-1) + (b&15); v = d.src[t*768 + col]; }
  d.dst[b*256 + t] = f2bf(v);
}

// permuted qkv biases + reordered LN params + zero guard page
__global__ __launch_bounds__(256) void k_biasperm(const float* __restrict__ b0, const float* __restrict__ b1,
    const float* kw0, const float* kb0, const float* vw0, const float* vb0,
    const float* kw1, const float* kb1, const float* vw1, const float* vb1,
    float* __restrict__ dstB, float* __restrict__ lnw2, float* __restrict__ lnb2,
    __hip_bfloat16* __restrict__ zpage){
  int t = threadIdx.x;
  zpage[t] = f2bf(0.0f);
  #pragma unroll
  for(int br=0;br<2;br++){
    const float* s = br ? b1 : b0;
    #pragma unroll
    for(int part=0;part<3;part++)
      dstB[br*768 + part*256 + t] = s[48*(t>>4) + part*16 + (t&15)];
  }
  #pragma unroll
  for(int br=0;br<2;br++){
    #pragma unroll
    for(int half=0;half<2;half++){
      int j = half*256 + t;
      int h = j>>5, idx = j&31;
      bool isK = idx<16;
      int c = isK ? idx : idx-16;
      const float* w = isK ? (br?kw1:kw0) : (br?vw1:vw0);
      const float* bb= isK ? (br?kb1:kb0) : (br?vb1:vb0);
      lnw2[br*512 + j] = w[h*16+c];
      lnb2[br*512 + j] = bb[h*16+c];
    }
  }
}

// ---------------- small row-major matmul: C = (A[+I]) @ B ----------------
template<int ADDI>
__global__ __launch_bounds__(256) void k_smallmm(const __hip_bfloat16* __restrict__ A,
    const __hip_bfloat16* __restrict__ B, __hip_bfloat16* __restrict__ C){
  __shared__ float ar[256];
  int i = blockIdx.x, t = threadIdx.x;
  float a = bf2f(A[(size_t)i*256 + t]);
  if(ADDI && t==i) a += 1.0f;
  ar[t] = a;
  __syncthreads();
  float a0=0.f,a1=0.f,a2=0.f,a3=0.f;
  for(int l=0;l<256;l+=4){
    a0 += ar[l+0]*bf2f(B[(l+0)*256 + t]);
    a1 += ar[l+1]*bf2f(B[(l+1)*256 + t]);
    a2 += ar[l+2]*bf2f(B[(l+2)*256 + t]);
    a3 += ar[l+3]*bf2f(B[(l+3)*256 + t]);
  }
  C[(size_t)i*256 + t] = f2bf((a0+a1)+(a2+a3));
}

__global__ __launch_bounds__(256) void k_smallmmR(const __hip_bfloat16* __restrict__ A,
    const __hip_bfloat16* __restrict__ B, __hip_bfloat16* __restrict__ C){
  __shared__ float ar[256];
  int j = blockIdx.x, t = threadIdx.x;
  int src = kvmap(j);
  ar[t] = bf2f(A[(size_t)src*256 + t]);
  __syncthreads();
  float a0=0.f,a1=0.f,a2=0.f,a3=0.f;
  for(int l=0;l<256;l+=4){
    a0 += ar[l+0]*bf2f(B[(l+0)*256 + t]);
    a1 += ar[l+1]*bf2f(B[(l+1)*256 + t]);
    a2 += ar[l+2]*bf2f(B[(l+2)*256 + t]);
    a3 += ar[l+3]*bf2f(B[(l+3)*256 + t]);
  }
  C[(size_t)j*256 + t] = f2bf((a0+a1)+(a2+a3));
}

__global__ __launch_bounds__(256) void k_bkv2R(const float* __restrict__ b2, const float* __restrict__ biaskv,
    const __hip_bfloat16* __restrict__ kvT_, float* __restrict__ outb){
  __shared__ float s_b2[256];
  int t = threadIdx.x; int n = blockIdx.x*256 + t;
  int src = kvmap(n);
  s_b2[t] = b2[t];
  __syncthreads();
  float v = biaskv[src];
  for(int l=0;l<256;l++) v += s_b2[l]*bf2f(kvT_[(size_t)src*256 + l]);
  outb[n] = v;
}

// ---------------- c1 = ((b2@(Wfold+I)+bfold) @ Wp) + bp ----------------
__global__ __launch_bounds__(256) void k_cvec(const float* __restrict__ b2, const float* __restrict__ bfold,
    const __hip_bfloat16* __restrict__ WfoldT, const __hip_bfloat16* __restrict__ projT_,
    const float* __restrict__ bp, float* __restrict__ c1){
  __shared__ float s_b2[256], s_r[256];
  int t = threadIdx.x;
  s_b2[t] = b2[t];
  __syncthreads();
  float r = s_b2[t] + bfold[t];
  for(int l=0;l<256;l++) r += s_b2[l]*bf2f(WfoldT[(size_t)t*256 + l]);
  s_r[t] = r;
  __syncthreads();
  float c = bp[t];
  for(int l=0;l<256;l++) c += s_r[l]*bf2f(projT_[(size_t)t*256 + l]);
  c1[t] = c;
}

// ---------------- per-query sampling geometry + result_bil ----------------
__global__ __launch_bounds__(256) void k_sample(const float* __restrict__ coord, const float* __restrict__ inp,
    float* __restrict__ mf, int* __restrict__ mi, float* __restrict__ bil){
  int q = blockIdx.x*256 + threadIdx.x;
  float cy = coord[2*q], cx = coord[2*q+1];
  const float LO = (float)(-1.0 + 1e-6), HI = (float)(1.0 - 1e-6);
  const float ONEG = (float)(-1.0/64.0 + 1e-6), OPOS = (float)(1.0/64.0 + 1e-6);
  float areas[4];
  #pragma unroll
  for(int s=0;s<4;s++){
    float oy = (s<2)?ONEG:OPOS;
    float ox = (s&1)?OPOS:ONEG;
    float csy = fminf(fmaxf(cy+oy, LO), HI);
    float csx = fminf(fmaxf(cx+ox, LO), HI);
    float fy = ((csy+1.0f)*64.0f - 1.0f)*0.5f;
    float fx = ((csx+1.0f)*64.0f - 1.0f)*0.5f;
    int iy = (int)rintf(fy); iy = iy<0?0:(iy>63?63:iy);
    int ix = (int)rintf(fx); ix = ix<0?0:(ix>63?63:ix);
    float qcy = -1.0f + (float)(2*iy+1)*0.015625f;
    float qcx = -1.0f + (float)(2*ix+1)*0.015625f;
    float ry = (cy-qcy)*64.0f, rx = (cx-qcx)*64.0f;
    mf[q*16 + 4 + 2*s] = ry; mf[q*16 + 5 + 2*s] = rx;
    areas[s] = fabsf(ry*rx) + 1e-9f;
    mi[q*8 + s] = iy*64 + ix;
  }
  float tot = areas[0]+areas[1]+areas[2]+areas[3];
  #pragma unroll
  for(int s=0;s<4;s++) mf[q*16 + s] = areas[3-s] / tot;

  float fy = ((cy+1.0f)*64.0f - 1.0f)*0.5f;
  float fx = ((cx+1.0f)*64.0f - 1.0f)*0.5f;
  {
    float y0 = floorf(fy), x0 = floorf(fx);
    float wy = fy-y0, wx = fx-x0;
    int y0i = (int)y0, x0i = (int)x0;
    float cw[4] = {(1.0f-wy)*(1.0f-wx), (1.0f-wy)*wx, wy*(1.0f-wx), wy*wx};
    #pragma unroll
    for(int c2=0;c2<4;c2++){
      int yi = y0i + (c2>>1), xi = x0i + (c2&1);
      bool ok = (yi>=0 && yi<64 && xi>=0 && xi<64);
      int yc = yi<0?0:(yi>63?63:yi), xc = xi<0?0:(xi>63?63:xi);
      mf[q*16 + 12 + c2] = ok ? cw[c2] : 0.0f;
      mi[q*8 + 4 + c2] = yc*64 + xc;
    }
  }
  {
    float fyb = fminf(fmaxf(fy, 0.0f), 63.0f);
    float fxb = fminf(fmaxf(fx, 0.0f), 63.0f);
    float y0 = floorf(fyb), x0 = floorf(fxb);
    float wy = fyb-y0, wx = fxb-x0;
    int y0i = (int)y0, x0i = (int)x0;
    float cw[4] = {(1.0f-wy)*(1.0f-wx), (1.0f-wy)*wx, wy*(1.0f-wx), wy*wx};
    float a0=0,a1=0,a2=0;
    #pragma unroll
    for(int c2=0;c2<4;c2++){
      int yi = y0i + (c2>>1), xi = x0i + (c2&1);
      if(yi>=0 && yi<64 && xi>=0 && xi<64){
        int idx = yi*64+xi; float wgt = cw[c2];
        a0 += inp[idx]*wgt; a1 += inp[4096+idx]*wgt; a2 += inp[8192+idx]*wgt;
      }
    }
    bil[q*3+0]=a0; bil[q*3+1]=a1; bil[q*3+2]=a2;
  }
}

// ---------------- stage-1 MLP via P-gather ----------------
template<int BR>
__global__ __launch_bounds__(256) void k_stage1(const __hip_bfloat16* __restrict__ P, const float* __restrict__ mf,
    const int* __restrict__ mi, const float* __restrict__ coord, const float* __restrict__ cell,
    const float* __restrict__ W1, const float* __restrict__ b1, __hip_bfloat16* __restrict__ out){
  __shared__ float wsm[11][256];
  int j = threadIdx.x;
  if(BR==0){
    #pragma unroll
    for(int r=0;r<8;r++) wsm[r][j] = W1[r*256 + j];
    wsm[8][j] = W1[1032*256 + j];
    wsm[9][j] = W1[1033*256 + j];
    wsm[10][j] = b1[j];
  } else {
    wsm[0][j] = W1[0*256 + j];
    wsm[1][j] = W1[1*256 + j];
    wsm[2][j] = W1[258*256 + j];
    wsm[3][j] = W1[259*256 + j];
    wsm[4][j] = b1[j];
  }
  __syncthreads();
  int q0 = blockIdx.x*32;
  for(int qq=0;qq<32;qq++){
    int q = q0+qq;
    float acc;
    const float* m = mf + q*16;
    const int* ii = mi + q*8;
    if(BR==0){
      acc = wsm[10][j];
      #pragma unroll
      for(int r=0;r<8;r++) acc += m[4+r]*wsm[r][j];
      float cly = cell[2*q]*64.0f, clx = cell[2*q+1]*64.0f;
      acc += cly*wsm[8][j] + clx*wsm[9][j];
      #pragma unroll
      for(int s=0;s<4;s++) acc += m[s]*bf2f(P[(size_t)ii[s]*1280 + s*256 + j]);
    } else {
      acc = wsm[4][j];
      float cy = coord[2*q], cx = coord[2*q+1];
      float cly = cell[2*q]*64.0f, clx = cell[2*q+1]*64.0f;
      acc += cy*wsm[0][j] + cx*wsm[1][j] + cly*wsm[2][j] + clx*wsm[3][j];
      #pragma unroll
      for(int c2=0;c2<4;c2++) acc += m[12+c2]*bf2f(P[(size_t)ii[4+c2]*1280 + 1024 + j]);
    }
    out[(size_t)q*256 + j] = f2bf(gelu_f(acc));
  }
}

// ---------------- MFMA bf16 GEMM v3: 34 KB LDS, half-tile epilogue w/ bank rotation ----------------
template<int ACT,int NRES>
__global__ __launch_bounds__(256) void k_gemm_mfma(
    const __hip_bfloat16* __restrict__ A, const __hip_bfloat16* __restrict__ BT,
    const float* __restrict__ bias, const __hip_bfloat16* __restrict__ R1,
    const __hip_bfloat16* __restrict__ R2, __hip_bfloat16* __restrict__ C,
    int M, int N, int K, int ldc){
  __shared__ __align__(1024) char smem[64*133*4];
  const int t = threadIdx.x, wave = t>>6, lane = t&63;
  const int MT = M>>7, NT = N>>7;
  const int b = blockIdx.x, xcd = b&7, i = b>>3;
  const int nt = i % NT, mtl = i / NT;
  const int m0 = (xcd*(MT>>3) + mtl) << 7, n0 = nt << 7;
  const int wr = (wave>>1)*64, wc = (wave&1)*64;
  const int lr = lane&15, lh = lane>>4;

  f32x4 acc[4][4] = {};
  const int ntiles = K>>6;
  for(int kt=0; kt<ntiles; ++kt){
    __syncthreads();
    #pragma unroll
    for(int q2=0;q2<4;q2++){
      int c = (wave*4+q2)*64 + lane;
      int row = c>>3; int k8 = (c&7) ^ (row&7);
      __hip_bfloat16* la = (__hip_bfloat16*)smem + (size_t)(wave*4+q2)*512;
      __hip_bfloat16* lb = (__hip_bfloat16*)(smem + 16384) + (size_t)(wave*4+q2)*512;
      load_lds16(A  + (size_t)(m0+row)*K + (kt*64 + k8*8), la);
      load_lds16(BT + (size_t)(n0+row)*K + (kt*64 + k8*8), lb);
    }
    __syncthreads();
    const __hip_bfloat16* Ab = (const __hip_bfloat16*)smem;
    const __hip_bfloat16* Bb = (const __hip_bfloat16*)(smem + 16384);
    #pragma unroll
    for(int kk=0;kk<2;kk++){
      bf16x8 af[4], bfr[4];
      #pragma unroll
      for(int m=0;m<4;m++){
        int row = wr + m*16 + lr;
        int p = (kk*4 + lh) ^ (row&7);
        af[m] = *reinterpret_cast<const bf16x8*>(Ab + row*64 + p*8);
      }
      #pragma unroll
      for(int n=0;n<4;n++){
        int row = wc + n*16 + lr;
        int p = (kk*4 + lh) ^ (row&7);
        bfr[n] = *reinterpret_cast<const bf16x8*>(Bb + row*64 + p*8);
      }
      #pragma unroll
      for(int m=0;m<4;m++)
        #pragma unroll
        for(int n=0;n<4;n++)
          acc[m][n] = __builtin_amdgcn_mfma_f32_16x16x32_bf16(af[m], bfr[n], acc[m][n], 0,0,0);
    }
  }

  float* epi = (float*)smem;
  const int cg = t&3;
  #pragma unroll
  for(int hf=0; hf<2; ++hf){
    __syncthreads();
    if((wave>>1) == hf){
      #pragma unroll
      for(int m=0;m<4;m++)
        #pragma unroll
        for(int n=0;n<4;n++){
          int col = wc + n*16 + lr;
          #pragma unroll
          for(int j=0;j<4;j++)
            epi[(m*16 + lh*4 + j)*133 + col] = acc[m][n][j];
        }
    }
    __syncthreads();
    const int lrow = t>>2, c0 = cg*32;
    const size_t grow = (size_t)(m0 + hf*64 + lrow);
    const float* er = epi + lrow*133;
    #pragma unroll
    for(int g0=0; g0<4; g0++){
      int g = (g0 + cg) & 3;                 // bank-conflict rotation
      int cb = c0 + g*8;
      int gc = n0 + cb;
      float v[8];
      #pragma unroll
      for(int e=0;e<8;e++) v[e] = er[cb+e];
      if(bias){
        #pragma unroll
        for(int e=0;e<8;e++) v[e] += bias[gc+e];
      }
      if(ACT==1){
        #pragma unroll
        for(int e=0;e<8;e++) v[e] = gelu_f(v[e]);
      }
      if(NRES==1 || NRES==2){
        uint4 r = *reinterpret_cast<const uint4*>(R1 + grow*ldc + gc);
        unsigned rw[4] = {r.x,r.y,r.z,r.w};
        #pragma unroll
        for(int q2=0;q2<4;q2++){ v[2*q2] += bflo(rw[q2]); v[2*q2+1] += bfhi(rw[q2]); }
      }
      if(NRES==2){
        uint4 r = *reinterpret_cast<const uint4*>(R2 + grow*ldc + gc);
        unsigned rw[4] = {r.x,r.y,r.z,r.w};
        #pragma unroll
        for(int q2=0;q2<4;q2++){ v[2*q2] += bflo(rw[q2]); v[2*q2+1] += bfhi(rw[q2]); }
      }
      uint4 o;
      o.x = pack2bf(v[0],v[1]); o.y = pack2bf(v[2],v[3]);
      o.z = pack2bf(v[4],v[5]); o.w = pack2bf(v[6],v[7]);
      *reinterpret_cast<uint4*>(C + grow*ldc + gc) = o;
    }
  }
}

// ---------------- freq conv GEMM: A gathered from featP via tap-offset (im2col fused into staging) ----
__global__ __launch_bounds__(256) void k_gfreq(
    const __hip_bfloat16* __restrict__ featP, const __hip_bfloat16* __restrict__ zpage,
    const __hip_bfloat16* __restrict__ BT, const float* __restrict__ bias,
    __hip_bfloat16* __restrict__ C){
  __shared__ __align__(1024) char smem[64*133*4];
  const int t = threadIdx.x, wave = t>>6, lane = t&63;
  const int MT = 32, NT = 2;
  const int b = blockIdx.x, xcd = b&7, i = b>>3;
  const int nt = i % NT, mtl = i / NT;
  const int m0 = (xcd*(MT>>3) + mtl) << 7, n0 = nt << 7;
  const int wr = (wave>>1)*64, wc = (wave&1)*64;
  const int lr = lane&15, lh = lane>>4;

  f32x4 acc[4][4] = {};
  for(int kt=0; kt<9; ++kt){
    int ky = kt/3, kx = kt - ky*3;
    __syncthreads();
    #pragma unroll
    for(int q2=0;q2<4;q2++){
      int c = (wave*4+q2)*64 + lane;
      int row = c>>3; int k8 = (c&7) ^ (row&7);
      __hip_bfloat16* la = (__hip_bfloat16*)smem + (size_t)(wave*4+q2)*512;
      __hip_bfloat16* lb = (__hip_bfloat16*)(smem + 16384) + (size_t)(wave*4+q2)*512;
      int pix = m0+row, y = pix>>6, x = pix&63;
      int yy = y+ky-1, xx = x+kx-1;
      const __hip_bfloat16* src = ((unsigned)yy<64u && (unsigned)xx<64u) ?
          (featP + (size_t)(yy*64+xx)*64 + k8*8) : (zpage + k8*8);
      load_lds16(src, la);
      load_lds16(BT + (size_t)(n0+row)*640 + (kt*64 + k8*8), lb);
    }
    __syncthreads();
    const __hip_bfloat16* Ab = (const __hip_bfloat16*)smem;
    const __hip_bfloat16* Bb = (const __hip_bfloat16*)(smem + 16384);
    #pragma unroll
    for(int kk=0;kk<2;kk++){
      bf16x8 af[4], bfr[4];
      #pragma unroll
      for(int m=0;m<4;m++){
        int row = wr + m*16 + lr;
        int p = (kk*4 + lh) ^ (row&7);
        af[m] = *reinterpret_cast<const bf16x8*>(Ab + row*64 + p*8);
      }
      #pragma unroll
      for(int n=0;n<4;n++){
        int row = wc + n*16 + lr;
        int p = (kk*4 + lh) ^ (row&7);
        bfr[n] = *reinterpret_cast<const bf16x8*>(Bb + row*64 + p*8);
      }
      #pragma unroll
      for(int m=0;m<4;m++)
        #pragma unroll
        for(int n=0;n<4;n++)
          acc[m][n] = __builtin_amdgcn_mfma_f32_16x16x32_bf16(af[m], bfr[n], acc[m][n], 0,0,0);
    }
  }

  float* epi = (float*)smem;
  const int cg = t&3;
  #pragma unroll
  for(int hf=0; hf<2; ++hf){
    __syncthreads();
    if((wave>>1) == hf){
      #pragma unroll
      for(int m=0;m<4;m++)
        #pragma unroll
        for(int n=0;n<4;n++){
          int col = wc + n*16 + lr;
          #pragma unroll
          for(int j=0;j<4;j++)
            epi[(m*16 + lh*4 + j)*133 + col] = acc[m][n][j];
        }
    }
    __syncthreads();
    const int lrow = t>>2, c0 = cg*32;
    const size_t grow = (size_t)(m0 + hf*64 + lrow);
    const float* er = epi + lrow*133;
    #pragma unroll
    for(int g0=0; g0<4; g0++){
      int g = (g0 + cg) & 3;
      int cb = c0 + g*8;
      int gc = n0 + cb;
      float v[8];
      #pragma unroll
      for(int e=0;e<8;e++) v[e] = er[cb+e] + bias[gc+e];
      uint4 o;
      o.x = pack2bf(v[0],v[1]); o.y = pack2bf(v[2],v[3]);
      o.z = pack2bf(v[4],v[5]); o.w = pack2bf(v[6],v[7]);
      *reinterpret_cast<uint4*>(C + grow*256 + gc) = o;
    }
  }
}

// ---------------- fused kv: GEMM(N=512 reordered) + bias + LDS-transposed LN + per-head MFMA outer product ----
__global__ __launch_bounds__(256) void k_kvln(
    const __hip_bfloat16* __restrict__ A, const __hip_bfloat16* __restrict__ BT,
    const float* __restrict__ bias, const float* __restrict__ lnw, const float* __restrict__ lnb,
    float* __restrict__ kvpart){
  __shared__ __align__(1024) char smem[34816];
  const int t = threadIdx.x, wave = t>>6, lane = t&63;
  const int MT = 512, NT = 4;
  const int b = blockIdx.x, xcd = b&7, i = b>>3;
  const int nt = i % NT, mtl = i / NT;
  const int m0 = (xcd*(MT>>3) + mtl) << 7, n0 = nt << 7;
  const int wr = (wave>>1)*64, wc = (wave&1)*64;
  const int lr = lane&15, lh = lane>>4;

  f32x4 acc[4][4] = {};
  for(int kt=0; kt<4; ++kt){
    __syncthreads();
    #pragma unroll
    for(int q2=0;q2<4;q2++){
      int c = (wave*4+q2)*64 + lane;
      int row = c>>3; int k8 = (c&7) ^ (row&7);
      __hip_bfloat16* la = (__hip_bfloat16*)smem + (size_t)(wave*4+q2)*512;
      __hip_bfloat16* lb = (__hip_bfloat16*)(smem + 16384) + (size_t)(wave*4+q2)*512;
      load_lds16(A  + (size_t)(m0+row)*256 + (kt*64 + k8*8), la);
      load_lds16(BT + (size_t)(n0+row)*256 + (kt*64 + k8*8), lb);
    }
    __syncthreads();
    const __hip_bfloat16* Ab = (const __hip_bfloat16*)smem;
    const __hip_bfloat16* Bb = (const __hip_bfloat16*)(smem + 16384);
    #pragma unroll
    for(int kk=0;kk<2;kk++){
      bf16x8 af[4], bfr[4];
      #pragma unroll
      for(int m=0;m<4;m++){
        int row = wr + m*16 + lr;
        int p = (kk*4 + lh) ^ (row&7);
        af[m] = *reinterpret_cast<const bf16x8*>(Ab + row*64 + p*8);
      }
      #pragma unroll
      for(int n=0;n<4;n++){
        int row = wc + n*16 + lr;
        int p = (kk*4 + lh) ^ (row&7);
        bfr[n] = *reinterpret_cast<const bf16x8*>(Bb + row*64 + p*8);
      }
      #pragma unroll
      for(int m=0;m<4;m++)
        #pragma unroll
        for(int n=0;n<4;n++)
          acc[m][n] = __builtin_amdgcn_mfma_f32_16x16x32_bf16(af[m], bfr[n], acc[m][n], 0,0,0);
    }
  }
  __syncthreads();

  __hip_bfloat16* knT = (__hip_bfloat16*)smem;            // [4 heads][16 cols][136 rows]
  __hip_bfloat16* vnT = (__hip_bfloat16*)(smem + 17408);
  #pragma unroll
  for(int m=0;m<4;m++){
    #pragma unroll
    for(int n=0;n<4;n++){
      int cl = wc + n*16 + lr;
      int gcol = n0 + cl;
      float bs = bias[gcol];
      int h2 = cl>>5, isV = (cl>>4)&1;
      short4 pk;
      #pragma unroll
      for(int j=0;j<4;j++) ((__hip_bfloat16*)&pk)[j] = f2bf(acc[m][n][j] + bs);
      int r = wr + m*16 + lh*4;
      __hip_bfloat16* dst = (isV ? vnT : knT) + (h2*16 + lr)*136 + r;
      *reinterpret_cast<short4*>(dst) = pk;
    }
  }
  __syncthreads();
  #pragma unroll
  for(int i4=0; i4<4; ++i4){
    int task = i4*256 + t;
    int r = task & 127, hv = task >> 7;
    int h2 = hv >> 1, isV = hv & 1;
    __hip_bfloat16* base = (isV ? vnT : knT) + (h2*16)*136 + r;
    float xs[16];
    float s=0.0f, s2=0.0f;
    #pragma unroll
    for(int c=0;c<16;c++){ xs[c] = bf2f(base[c*136]); s += xs[c]; s2 += xs[c]*xs[c]; }
    float mean = s*0.0625f;
    float var = (s2 - 16.0f*mean*mean)*(1.0f/15.0f); var = var<0.0f?0.0f:var;
    float inv = 1.0f/(sqrtf(var) + 1e-5f);
    int gbase = n0 + h2*32 + isV*16;
    #pragma unroll
    for(int c=0;c<16;c++)
      base[c*136] = f2bf(lnw[gbase+c]*((xs[c]-mean)*inv) + lnb[gbase+c]);
  }
  __syncthreads();
  f32x4 kacc = {};
  #pragma unroll
  for(int kk=0;kk<4;kk++){
    bf16x8 af  = *reinterpret_cast<const bf16x8*>(knT + (wave*16 + lr)*136 + kk*32 + lh*8);
    bf16x8 bf_ = *reinterpret_cast<const bf16x8*>(vnT + (wave*16 + lr)*136 + kk*32 + lh*8);
    kacc = __builtin_amdgcn_mfma_f32_16x16x32_bf16(af, bf_, kacc, 0,0,0);
  }
  const int mt = m0>>7;
  const int hglob = nt*4 + wave;
  #pragma unroll
  for(int j=0;j<4;j++)
    kvpart[(size_t)mt*4096 + hglob*256 + (lh*4+j)*16 + lr] = kacc[j];
}

// ---------------- G12 fused: C = gelu(A@B1^T + c1) + (A@B2^T + b2) [+R], v1 packed bf16 ----------------
template<int NRES>
__global__ __launch_bounds__(256) void k_gemm12(
    const __hip_bfloat16* __restrict__ A, const __hip_bfloat16* __restrict__ B1T,
    const float* __restrict__ c1, const __hip_bfloat16* __restrict__ B2T,
    const float* __restrict__ b2, const __hip_bfloat16* __restrict__ R,
    __hip_bfloat16* __restrict__ C){
  __shared__ __align__(1024) char smem[49152];
  const int t = threadIdx.x, wave = t>>6, lane = t&63;
  const int MT = 512, NT = 2;
  const int b = blockIdx.x, xcd = b&7, i = b>>3;
  const int nt = i % NT, mtl = i / NT;
  const int m0 = (xcd*(MT>>3) + mtl) << 7, n0 = nt << 7;
  const int wr = (wave>>1)*64, wc = (wave&1)*64;
  const int lr = lane&15, lh = lane>>4;
  f32x4 acc1[4][4] = {}, acc2[4][4] = {};
  for(int k0=0;k0<256;k0+=64){
    __syncthreads();
    #pragma unroll
    for(int q2=0;q2<4;q2++){
      int c = (wave*4+q2)*64 + lane;
      int row = c>>3; int k8 = (c&7) ^ (row&7);
      __hip_bfloat16* base = (__hip_bfloat16*)smem + (size_t)(wave*4+q2)*512;
      load_lds16(A   + (size_t)(m0+row)*256 + (k0 + k8*8), base);
      load_lds16(B1T + (size_t)(n0+row)*256 + (k0 + k8*8), base + 8192);
      load_lds16(B2T + (size_t)(n0+row)*256 + (k0 + k8*8), base + 16384);
    }
    __syncthreads();
    const __hip_bfloat16* Ab = (const __hip_bfloat16*)smem;
    #pragma unroll
    for(int kk=0;kk<2;kk++){
      bf16x8 af[4], bfr[4];
      #pragma unroll
      for(int m=0;m<4;m++){
        int row = wr + m*16 + lr;
        int p = (kk*4 + lh) ^ (row&7);
        af[m] = *reinterpret_cast<const bf16x8*>(Ab + row*64 + p*8);
      }
      #pragma unroll
      for(int n=0;n<4;n++){
        int row = wc + n*16 + lr;
        int p = (kk*4 + lh) ^ (row&7);
        bfr[n] = *reinterpret_cast<const bf16x8*>(Ab + 8192 + row*64 + p*8);
      }
      #pragma unroll
      for(int m=0;m<4;m++)
        #pragma unroll
        for(int n=0;n<4;n++)
          acc1[m][n] = __builtin_amdgcn_mfma_f32_16x16x32_bf16(af[m], bfr[n], acc1[m][n], 0,0,0);
      #pragma unroll
      for(int n=0;n<4;n++){
        int row = wc + n*16 + lr;
        int p = (kk*4 + lh) ^ (row&7);
        bfr[n] = *reinterpret_cast<const bf16x8*>(Ab + 16384 + row*64 + p*8);
      }
      #pragma unroll
      for(int m=0;m<4;m++)
        #pragma unroll
        for(int n=0;n<4;n++)
          acc2[m][n] = __builtin_amdgcn_mfma_f32_16x16x32_bf16(af[m], bfr[n], acc2[m][n], 0,0,0);
    }
  }
  float* epi = (float*)smem;
  const int cg = t&3;
  #pragma unroll
  for(int hf=0; hf<2; ++hf){
    const int lrow = t>>2, c0 = cg*32;
    const size_t grow = (size_t)(m0 + hf*64 + lrow);
    unsigned v1p[16];
    __syncthreads();
    if((wave>>1) == hf){
      #pragma unroll
      for(int m=0;m<4;m++)
        #pragma unroll
        for(int n=0;n<4;n++){
          int col = wc + n*16 + lr;
          #pragma unroll
          for(int j=0;j<4;j++)
            epi[(m*16 + lh*4 + j)*133 + col] = acc1[m][n][j];
        }
    }
    __syncthreads();
    {
      const float* er = epi + lrow*133;
      #pragma unroll
      for(int g0=0; g0<4; g0++){
        int g = (g0 + cg) & 3;
        int cb = c0 + g*8;
        float v[8];
        #pragma unroll
        for(int e=0;e<8;e++) v[e] = gelu_f(er[cb+e] + c1[n0+cb+e]);
        v1p[g*4+0] = pack2bf(v[0],v[1]);
        v1p[g*4+1] = pack2bf(v[2],v[3]);
        v1p[g*4+2] = pack2bf(v[4],v[5]);
        v1p[g*4+3] = pack2bf(v[6],v[7]);
      }
    }
    __syncthreads();
    if((wave>>1) == hf){
      #pragma unroll
      for(int m=0;m<4;m++)
        #pragma unroll
        for(int n=0;n<4;n++){
          int col = wc + n*16 + lr;
          #pragma unroll
          for(int j=0;j<4;j++)
            epi[(m*16 + lh*4 + j)*133 + col] = acc2[m][n][j];
        }
    }
    __syncthreads();
    {
      const float* er = epi + lrow*133;
      #pragma unroll
      for(int g0=0; g0<4; g0++){
        int g = (g0 + cg) & 3;
        int cb = c0 + g*8;
        int gc = n0 + cb;
        float v[8];
        #pragma unroll
        for(int e=0;e<8;e++) v[e] = er[cb+e] + b2[gc+e];
        #pragma unroll
        for(int q2=0;q2<4;q2++){ v[2*q2] += bflo(v1p[g*4+q2]); v[2*q2+1] += bfhi(v1p[g*4+q2]); }
        if(NRES==1){
          uint4 r = *reinterpret_cast<const uint4*>(R + grow*256 + gc);
          unsigned rw[4] = {r.x,r.y,r.z,r.w};
          #pragma unroll
          for(int q2=0;q2<4;q2++){ v[2*q2] += bflo(rw[q2]); v[2*q2+1] += bfhi(rw[q2]); }
        }
        uint4 o;
        o.x = pack2bf(v[0],v[1]); o.y = pack2bf(v[2],v[3]);
        o.z = pack2bf(v[4],v[5]); o.w = pack2bf(v[6],v[7]);
        *reinterpret_cast<uint4*>(C + grow*256 + gc) = o;
      }
    }
  }
}

// ---------------- fc3+final fused: part[nt][row][3] ----------------
__global__ __launch_bounds__(256) void k_gemmF(
    const __hip_bfloat16* __restrict__ A, const __hip_bfloat16* __restrict__ BT,
    const float* __restrict__ bias, const float* __restrict__ W4,
    float* __restrict__ part){
  __shared__ __align__(1024) char smem[64*133*4];
  __shared__ float w4s[768];
  const int t = threadIdx.x, wave = t>>6, lane = t&63;
  const int MT = 512, NT = 2;
  const int b = blockIdx.x, xcd = b&7, i = b>>3;
  const int nt = i % NT, mtl = i / NT;
  const int m0 = (xcd*(MT>>3) + mtl) << 7, n0 = nt << 7;
  const int wr = (wave>>1)*64, wc = (wave&1)*64;
  const int lr = lane&15, lh = lane>>4;
  for(int l=t;l<768;l+=256) w4s[l] = W4[l];

  f32x4 acc[4][4] = {};
  for(int kt=0; kt<4; ++kt){
    __syncthreads();
    #pragma unroll
    for(int q2=0;q2<4;q2++){
      int c = (wave*4+q2)*64 + lane;
      int row = c>>3; int k8 = (c&7) ^ (row&7);
      __hip_bfloat16* la = (__hip_bfloat16*)smem + (size_t)(wave*4+q2)*512;
      __hip_bfloat16* lb = (__hip_bfloat16*)(smem + 16384) + (size_t)(wave*4+q2)*512;
      load_lds16(A  + (size_t)(m0+row)*256 + (kt*64 + k8*8), la);
      load_lds16(BT + (size_t)(n0+row)*256 + (kt*64 + k8*8), lb);
    }
    __syncthreads();
    const __hip_bfloat16* Ab = (const __hip_bfloat16*)smem;
    const __hip_bfloat16* Bb = (const __hip_bfloat16*)(smem + 16384);
    #pragma unroll
    for(int kk=0;kk<2;kk++){
      bf16x8 af[4], bfr[4];
      #pragma unroll
      for(int m=0;m<4;m++){
        int row = wr + m*16 + lr;
        int p = (kk*4 + lh) ^ (row&7);
        af[m] = *reinterpret_cast<const bf16x8*>(Ab + row*64 + p*8);
      }
      #pragma unroll
      for(int n=0;n<4;n++){
        int row = wc + n*16 + lr;
        int p = (kk*4 + lh) ^ (row&7);
        bfr[n] = *reinterpret_cast<const bf16x8*>(Bb + row*64 + p*8);
      }
      #pragma unroll
      for(int m=0;m<4;m++)
        #pragma unroll
        for(int n=0;n<4;n++)
          acc[m][n] = __builtin_amdgcn_mfma_f32_16x16x32_bf16(af[m], bfr[n], acc[m][n], 0,0,0);
    }
  }

  float* epi = (float*)smem;
  const int cg = t&3;
  #pragma unroll
  for(int hf=0; hf<2; ++hf){
    __syncthreads();
    if((wave>>1) == hf){
      #pragma unroll
      for(int m=0;m<4;m++)
        #pragma unroll
        for(int n=0;n<4;n++){
          int col = wc + n*16 + lr;
          #pragma unroll
          for(int j=0;j<4;j++)
            epi[(m*16 + lh*4 + j)*133 + col] = acc[m][n][j];
        }
    }
    __syncthreads();
    {
      const int lrow = t>>2, c0 = cg*32;
      const float* er = epi + lrow*133;
      float s0=0.f, s1=0.f, s2=0.f;
      #pragma unroll
      for(int g0=0; g0<4; g0++){
        int g = (g0 + cg) & 3;
        int cb = c0 + g*8;
        int gc = n0 + cb;
        #pragma unroll
        for(int e=0;e<8;e++){
          float v = gelu_f(er[cb+e] + bias[gc+e]);
          s0 += v*w4s[(gc+e)*3+0];
          s1 += v*w4s[(gc+e)*3+1];
          s2 += v*w4s[(gc+e)*3+2];
        }
      }
      s0 += __shfl_xor(s0,1); s0 += __shfl_xor(s0,2);
      s1 += __shfl_xor(s1,1); s1 += __shfl_xor(s1,2);
      s2 += __shfl_xor(s2,1); s2 += __shfl_xor(s2,2);
      if((t&3)==0){
        float* pp = part + (size_t)nt*196608 + (size_t)(m0 + hf*64 + (t>>2))*3;
        pp[0]=s0; pp[1]=s1; pp[2]=s2;
      }
    }
  }
}

__global__ __launch_bounds__(256) void k_combine(const float* __restrict__ part, const float* __restrict__ b4,
    const float* __restrict__ bil, float* __restrict__ out){
  int i = blockIdx.x*256 + threadIdx.x;
  int j = i - (i/3)*3;
  out[i] = part[i] + part[196608 + i] + b4[j] + bil[i];
}

__global__ __launch_bounds__(256) void k_kvred(const float* __restrict__ kvpart, float* __restrict__ kv){
  __shared__ float sm[256];
  int b = blockIdx.x, t = threadIdx.x;
  int d = t & 15, seg = t >> 4;
  float s = 0.0f;
  for(int k=0;k<32;k++) s += kvpart[(size_t)(seg*32+k)*4096 + b*16 + d];
  sm[t] = s;
  __syncthreads();
  if(t < 16){
    float r = 0.0f;
    #pragma unroll
    for(int g=0; g<16; g++) r += sm[g*16 + t];
    kv[b*16 + t] = r * (1.0f/65536.0f);
  }
}

// ---------------- fold q-projection through kv ----------------
__global__ __launch_bounds__(256) void k_fold(const __hip_bfloat16* __restrict__ qT,
    const float* __restrict__ biasq, const float* __restrict__ kv,
    __hip_bfloat16* __restrict__ WfoldT, float* __restrict__ bfold){
  int n = blockIdx.x, t = threadIdx.x;
  int h = n>>4, d = n&15;
  float s = 0.0f;
  #pragma unroll
  for(int c=0;c<16;c++)
    s += bf2f(qT[(size_t)(h*16+c)*256 + t]) * kv[h*256 + c*16 + d];
  WfoldT[(size_t)n*256 + t] = f2bf(s);
  if(t==0){
    float b=0.0f;
    #pragma unroll
    for(int c=0;c<16;c++) b += biasq[h*16+c]*kv[h*256+c*16+d];
    bfold[n]=b;
  }
}

extern "C" void kernel_launch(void* const* d_in, const int* in_sizes, int n_in,
                              void* d_out, int out_size, void* d_ws, size_t ws_size,
                              hipStream_t stream){
  (void)in_sizes; (void)n_in; (void)out_size;
  const float* inp     = (const float*)d_in[0];
  const float* coord   = (const float*)d_in[1];
  const float* cell    = (const float*)d_in[2];
  const float* enc_w   = (const float*)d_in[3];
  const float* enc_b   = (const float*)d_in[4];
  const float* freq_w  = (const float*)d_in[5];
  const float* freq_b  = (const float*)d_in[6];
  const float* out0_w1 = (const float*)d_in[7];
  const float* out0_b1 = (const float*)d_in[8];
  const float* out0_w2 = (const float*)d_in[9];
  const float* out0_b2 = (const float*)d_in[10];
  const float* out1_w1 = (const float*)d_in[11];
  const float* out1_b1 = (const float*)d_in[12];
  const float* out1_w2 = (const float*)d_in[13];
  const float* out1_b2 = (const float*)d_in[14];
  const float* fc1_w1  = (const float*)d_in[15];
  const float* fc1_b1  = (const float*)d_in[16];
  const float* fc1_w2  = (const float*)d_in[17];
  const float* fc1_b2  = (const float*)d_in[18];
  const float* fc2_w1  = (const float*)d_in[19];
  const float* fc2_b1  = (const float*)d_in[20];
  const float* fc2_w2  = (const float*)d_in[21];
  const float* fc2_b2  = (const float*)d_in[22];
  const float* qkv_w[2] = {(const float*)d_in[23], (const float*)d_in[31]};
  const float* qkv_b[2] = {(const float*)d_in[24], (const float*)d_in[32]};
  const float* kln_w[2] = {(const float*)d_in[25], (const float*)d_in[33]};
  const float* kln_b[2] = {(const float*)d_in[26], (const float*)d_in[34]};
  const float* vln_w[2] = {(const float*)d_in[27], (const float*)d_in[35]};
  const float* vln_b[2] = {(const float*)d_in[28], (const float*)d_in[36]};
  const float* proj_w[2] = {(const float*)d_in[29], (const float*)d_in[37]};
  const float* proj_b[2] = {(const float*)d_in[30], (const float*)d_in[38]};
  const float* b2arr[2] = {out0_b2, out1_b2};

  char* wsp = (char*)d_ws; size_t off = 0;
  auto alloc = [&](size_t bytes)->void*{ void* p = wsp + off; off += (bytes + 255) & ~(size_t)255; return p; };
  __hip_bfloat16* featP = (__hip_bfloat16*)alloc(262144ull*2);
  __hip_bfloat16* zpage = (__hip_bfloat16*)alloc(256ull*2);
  __hip_bfloat16* wtb = (__hip_bfloat16*)alloc(2097152ull*2);
  __hip_bfloat16* P = (__hip_bfloat16*)alloc(5242880ull*2);
  float* mf     = (float*)alloc(65536ull*16*4);
  int*   mi     = (int*)alloc(65536ull*8*4);
  float* bil    = (float*)alloc(65536ull*3*4);
  float* kvpart = (float*)alloc(512ull*4096*4);
  float* kv0    = (float*)alloc(4096ull*4);
  float* kv1    = (float*)alloc(4096ull*4);
  float* biasbuf= (float*)alloc(1536ull*4);
  float* lnbuf  = (float*)alloc(2048ull*4);
  float* bfold  = (float*)alloc(256ull*4);
  float* c1     = (float*)alloc(256ull*4);
  float* bkvh   = (float*)alloc(1024ull*4);
  float* part   = (float*)alloc(2ull*196608*4);
  __hip_bfloat16* wfoldT = (__hip_bfloat16*)alloc(65536ull*2);
  __hip_bfloat16* bufA = (__hip_bfloat16*)alloc(65536ull*256*2);
  __hip_bfloat16* bufB = (__hip_bfloat16*)alloc(65536ull*256*2);
  __hip_bfloat16* bufC = (__hip_bfloat16*)alloc(65536ull*256*2);
  if(off > ws_size) return;

  __hip_bfloat16* w2T[2]   = {wtb,          wtb + 65536};
  __hip_bfloat16* projT[2] = {wtb + 131072, wtb + 196608};
  __hip_bfloat16* fc1w1T   =  wtb + 262144;
  __hip_bfloat16* fc1w2T   =  wtb + 327680;
  __hip_bfloat16* fc2w1T   =  wtb + 393216;
  __hip_bfloat16* qT[2]    = {wtb + 458752, wtb + 655360};
  __hip_bfloat16* kvT[2]   = {wtb + 524288, wtb + 720896};
  __hip_bfloat16* wfreqT   =  wtb + 851968;   // 256 x 640
  __hip_bfloat16* wblkT    =  wtb + 1015808;  // 1280 x 256
  __hip_bfloat16* kvh2T[2] = {wtb + 1343488, wtb + 1474560};
  __hip_bfloat16* Ubuf     =  wtb + 1605632;
  __hip_bfloat16* M1T      =  wtb + 1671168;
  __hip_bfloat16* freqB = bufB;               // 4096 x 256 (bufB dead until gemm12/fc)

  k_conv1<<<1024,256,0,stream>>>(inp, enc_w, enc_b, featP);
  k_wfreq<<<256,256,0,stream>>>(freq_w, wfreqT);
  k_wblk<<<1280,256,0,stream>>>(out0_w1, out1_w1, wblkT);

  PrepArgs pa;
  pa.d[0]  = {out0_w2,   w2T[0],   0, 0};
  pa.d[1]  = {out1_w2,   w2T[1],   0, 0};
  pa.d[2]  = {proj_w[0], projT[0], 0, 0};
  pa.d[3]  = {proj_w[1], projT[1], 0, 0};
  pa.d[4]  = {fc1_w1,    fc1w1T,   0, 0};
  pa.d[5]  = {fc1_w2,    fc1w2T,   0, 0};
  pa.d[6]  = {fc2_w1,    fc2w1T,   0, 0};
  pa.d[7]  = {qkv_w[0],  qT[0],    1, 0};
  pa.d[8]  = {qkv_w[0],  kvT[0],   17, 0};
  pa.d[9]  = {qkv_w[0],  kvT[0]+65536, 33, 0};
  pa.d[10] = {qkv_w[1],  qT[1],    1, 0};
  pa.d[11] = {qkv_w[1],  kvT[1],   17, 0};
  pa.d[12] = {qkv_w[1],  kvT[1]+65536, 33, 0};
  k_prep<<<13*256,256,0,stream>>>(pa);
  k_biasperm<<<1,256,0,stream>>>(qkv_b[0], qkv_b[1],
      kln_w[0], kln_b[0], vln_w[0], vln_b[0], kln_w[1], kln_b[1], vln_w[1], vln_b[1],
      biasbuf, lnbuf, lnbuf + 1024, zpage);

  for(int br=0;br<2;br++){
    k_smallmmR<<<512,256,0,stream>>>(kvT[br], w2T[br], kvh2T[br]);
    k_bkv2R<<<2,256,0,stream>>>(b2arr[br], biasbuf + br*768 + 256, kvT[br], bkvh + br*512);
  }

  // conv2 as GEMM with im2col fused into the staging address map
  k_gfreq<<<64,256,0,stream>>>(featP, zpage, wfreqT, freq_b, freqB);
  k_gemm_mfma<0,0><<<320,256,0,stream>>>(freqB, wblkT, nullptr, nullptr,nullptr, P, 4096,1280,256, 1280);

  k_sample<<<256,256,0,stream>>>(coord, inp, mf, mi, bil);

  for(int br=0;br<2;br++){
    if(br==0) k_stage1<0><<<2048,256,0,stream>>>(P, mf, mi, coord, cell, out0_w1, out0_b1, bufA);
    else      k_stage1<1><<<2048,256,0,stream>>>(P, mf, mi, coord, cell, out1_w1, out1_b1, bufA);
    k_kvln<<<2048,256,0,stream>>>(bufA, kvh2T[br], bkvh + br*512, lnbuf + br*512, lnbuf + 1024 + br*512, kvpart);
    float* kvf = br ? kv1 : kv0;
    k_kvred<<<256,256,0,stream>>>(kvpart, kvf);
    k_fold<<<256,256,0,stream>>>(qT[br], biasbuf + br*768, kvf, wfoldT, bfold);
    k_smallmm<1><<<256,256,0,stream>>>(wfoldT, w2T[br], Ubuf);
    k_smallmm<0><<<256,256,0,stream>>>(projT[br], Ubuf, M1T);
    k_cvec<<<1,256,0,stream>>>(b2arr[br], bfold, wfoldT, projT[br], proj_b[br], c1);
    if(br==0)
      k_gemm12<0><<<1024,256,0,stream>>>(bufA, M1T, c1, w2T[0], b2arr[0], nullptr, bufC);
    else
      k_gemm12<1><<<1024,256,0,stream>>>(bufA, M1T, c1, w2T[1], b2arr[1], bufC, bufC);
  }
  // fc tail: bufC = f
  k_gemm_mfma<1,0><<<1024,256,0,stream>>>(bufC, fc1w1T, fc1_b1, nullptr,nullptr, bufA, 65536,256,256, 256);
  k_gemm_mfma<1,1><<<1024,256,0,stream>>>(bufA, fc1w2T, fc1_b2, bufC, nullptr, bufB, 65536,256,256, 256);
  k_gemmF<<<1024,256,0,stream>>>(bufB, fc2w1T, fc2_b1, fc2_w2, part);
  k_combine<<<768,256,0,stream>>>(part, fc2_b2, bil, (float*)d_out);
}

// Round 16
// 553.411 us; speedup vs baseline: 1.0842x; 1.0842x over previous
//
#include <hip/hip_runtime.h>
#include <hip/hip_bf16.h>

#define DI __device__ __forceinline__

DI float gelu_f(float x){ return 0.5f*x*(1.0f + erff(x*0.7071067811865476f)); }
DI float bf2f(__hip_bfloat16 b){ return __bfloat162float(b); }
DI __hip_bfloat16 f2bf(float f){ return __float2bfloat16(f); }
DI float bflo(unsigned u){ return __uint_as_float(u<<16); }
DI float bfhi(unsigned u){ return __uint_as_float(u & 0xffff0000u); }
DI unsigned pack2bf(float a, float b){
  __hip_bfloat16 ha = f2bf(a), hb = f2bf(b);
  unsigned short ua = *reinterpret_cast<unsigned short*>(&ha);
  unsigned short ub = *reinterpret_cast<unsigned short*>(&hb);
  return (unsigned)ua | ((unsigned)ub<<16);
}

typedef __attribute__((ext_vector_type(8))) short bf16x8;
typedef __attribute__((ext_vector_type(4))) float f32x4;

template<typename T>
DI void load_lds16(const T* g, T* l){
  __builtin_amdgcn_global_load_lds((const __attribute__((address_space(1))) void*)g,
                                   (__attribute__((address_space(3))) void*)l, 16, 0, 0);
}

DI int kvmap(int j){ int h=j>>5, idx=j&31; return idx<16 ? h*16+idx : 256+h*16+(idx-16); }

// ---------------- conv1: inp -> featP (4096 pix, 64 ch) bf16 pixel-major ----------------
__global__ __launch_bounds__(256) void k_conv1(const float* __restrict__ inp, const float* __restrict__ w,
                                               const float* __restrict__ b, __hip_bfloat16* __restrict__ featP){
  int idx = blockIdx.x*256 + threadIdx.x;
  int o = idx & 63, p = idx >> 6, y = p >> 6, x = p & 63;
  float acc = b[o];
  #pragma unroll
  for(int c=0;c<3;c++){
    #pragma unroll
    for(int ky=0;ky<3;ky++){
      int yy = y+ky-1; if((unsigned)yy >= 64u) continue;
      #pragma unroll
      for(int kx=0;kx<3;kx++){
        int xx = x+kx-1; if((unsigned)xx >= 64u) continue;
        acc += inp[c*4096 + yy*64 + xx] * w[o*27 + c*9 + ky*3 + kx];
      }
    }
  }
  featP[p*64 + o] = f2bf(acc);
}

// ---------------- wfreq permute ----------------
__global__ __launch_bounds__(256) void k_wfreq(const float* __restrict__ fw, __hip_bfloat16* __restrict__ wt){
  int o = blockIdx.x, t = threadIdx.x;
  #pragma unroll
  for(int it=0; it<3; it++){
    int k = it*256 + t;
    if(k >= 640) break;
    float v = 0.0f;
    if(k < 576){
      int tap = k>>6, c = k&63;
      v = fw[o*576 + c*9 + tap];
    }
    wt[(size_t)o*640 + k] = f2bf(v);
  }
}

// ---------------- wblkT ----------------
__global__ __launch_bounds__(256) void k_wblk(const float* __restrict__ w0, const float* __restrict__ w1,
                                              __hip_bfloat16* __restrict__ wt){
  int j = blockIdx.x, kk = threadIdx.x;
  float v;
  if(j < 1024){
    int s = j>>8, n = j&255;
    v = w0[(8 + 256*s + kk)*256 + n];
  } else {
    v = w1[(2 + kk)*256 + (j-1024)];
  }
  wt[(size_t)j*256 + kk] = f2bf(v);
}

// ---------------- batched weight transpose / qkv head-permute ----------------
struct PrepDesc { const float* src; __hip_bfloat16* dst; int mode; int pad; };
struct PrepArgs { PrepDesc d[13]; };
__global__ __launch_bounds__(256) void k_prep(PrepArgs a){
  int u = blockIdx.x >> 8, b = blockIdx.x & 255, t = threadIdx.x;
  PrepDesc d = a.d[u];
  float v;
  if(d.mode == 0) v = d.src[t*256 + b];
  else { int col = 48*(b>>4) + (d.mode-1) + (b&15); v = d.src[t*768 + col]; }
  d.dst[b*256 + t] = f2bf(v);
}

// permuted qkv biases + reordered LN params + zero guard page
__global__ __launch_bounds__(256) void k_biasperm(const float* __restrict__ b0, const float* __restrict__ b1,
    const float* kw0, const float* kb0, const float* vw0, const float* vb0,
    const float* kw1, const float* kb1, const float* vw1, const float* vb1,
    float* __restrict__ dstB, float* __restrict__ lnw2, float* __restrict__ lnb2,
    __hip_bfloat16* __restrict__ zpage){
  int t = threadIdx.x;
  zpage[t] = f2bf(0.0f);
  #pragma unroll
  for(int br=0;br<2;br++){
    const float* s = br ? b1 : b0;
    #pragma unroll
    for(int part=0;part<3;part++)
      dstB[br*768 + part*256 + t] = s[48*(t>>4) + part*16 + (t&15)];
  }
  #pragma unroll
  for(int br=0;br<2;br++){
    #pragma unroll
    for(int half=0;half<2;half++){
      int j = half*256 + t;
      int h = j>>5, idx = j&31;
      bool isK = idx<16;
      int c = isK ? idx : idx-16;
      const float* w = isK ? (br?kw1:kw0) : (br?vw1:vw0);
      const float* bb= isK ? (br?kb1:kb0) : (br?vb1:vb0);
      lnw2[br*512 + j] = w[h*16+c];
      lnb2[br*512 + j] = bb[h*16+c];
    }
  }
}

// ---------------- small row-major matmul: C = (A[+I]) @ B ----------------
template<int ADDI>
__global__ __launch_bounds__(256) void k_smallmm(const __hip_bfloat16* __restrict__ A,
    const __hip_bfloat16* __restrict__ B, __hip_bfloat16* __restrict__ C){
  __shared__ float ar[256];
  int i = blockIdx.x, t = threadIdx.x;
  float a = bf2f(A[(size_t)i*256 + t]);
  if(ADDI && t==i) a += 1.0f;
  ar[t] = a;
  __syncthreads();
  float a0=0.f,a1=0.f,a2=0.f,a3=0.f;
  for(int l=0;l<256;l+=4){
    a0 += ar[l+0]*bf2f(B[(l+0)*256 + t]);
    a1 += ar[l+1]*bf2f(B[(l+1)*256 + t]);
    a2 += ar[l+2]*bf2f(B[(l+2)*256 + t]);
    a3 += ar[l+3]*bf2f(B[(l+3)*256 + t]);
  }
  C[(size_t)i*256 + t] = f2bf((a0+a1)+(a2+a3));
}

__global__ __launch_bounds__(256) void k_smallmmR(const __hip_bfloat16* __restrict__ A,
    const __hip_bfloat16* __restrict__ B, __hip_bfloat16* __restrict__ C){
  __shared__ float ar[256];
  int j = blockIdx.x, t = threadIdx.x;
  int src = kvmap(j);
  ar[t] = bf2f(A[(size_t)src*256 + t]);
  __syncthreads();
  float a0=0.f,a1=0.f,a2=0.f,a3=0.f;
  for(int l=0;l<256;l+=4){
    a0 += ar[l+0]*bf2f(B[(l+0)*256 + t]);
    a1 += ar[l+1]*bf2f(B[(l+1)*256 + t]);
    a2 += ar[l+2]*bf2f(B[(l+2)*256 + t]);
    a3 += ar[l+3]*bf2f(B[(l+3)*256 + t]);
  }
  C[(size_t)j*256 + t] = f2bf((a0+a1)+(a2+a3));
}

__global__ __launch_bounds__(256) void k_bkv2R(const float* __restrict__ b2, const float* __restrict__ biaskv,
    const __hip_bfloat16* __restrict__ kvT_, float* __restrict__ outb){
  __shared__ float s_b2[256];
  int t = threadIdx.x; int n = blockIdx.x*256 + t;
  int src = kvmap(n);
  s_b2[t] = b2[t];
  __syncthreads();
  float v = biaskv[src];
  for(int l=0;l<256;l++) v += s_b2[l]*bf2f(kvT_[(size_t)src*256 + l]);
  outb[n] = v;
}

// ---------------- c1 = ((b2@(Wfold+I)+bfold) @ Wp) + bp ----------------
__global__ __launch_bounds__(256) void k_cvec(const float* __restrict__ b2, const float* __restrict__ bfold,
    const __hip_bfloat16* __restrict__ WfoldT, const __hip_bfloat16* __restrict__ projT_,
    const float* __restrict__ bp, float* __restrict__ c1){
  __shared__ float s_b2[256], s_r[256];
  int t = threadIdx.x;
  s_b2[t] = b2[t];
  __syncthreads();
  float r = s_b2[t] + bfold[t];
  for(int l=0;l<256;l++) r += s_b2[l]*bf2f(WfoldT[(size_t)t*256 + l]);
  s_r[t] = r;
  __syncthreads();
  float c = bp[t];
  for(int l=0;l<256;l++) c += s_r[l]*bf2f(projT_[(size_t)t*256 + l]);
  c1[t] = c;
}

// ---------------- per-query sampling geometry + result_bil ----------------
__global__ __launch_bounds__(256) void k_sample(const float* __restrict__ coord, const float* __restrict__ inp,
    float* __restrict__ mf, int* __restrict__ mi, float* __restrict__ bil){
  int q = blockIdx.x*256 + threadIdx.x;
  float cy = coord[2*q], cx = coord[2*q+1];
  const float LO = (float)(-1.0 + 1e-6), HI = (float)(1.0 - 1e-6);
  const float ONEG = (float)(-1.0/64.0 + 1e-6), OPOS = (float)(1.0/64.0 + 1e-6);
  float areas[4];
  #pragma unroll
  for(int s=0;s<4;s++){
    float oy = (s<2)?ONEG:OPOS;
    float ox = (s&1)?OPOS:ONEG;
    float csy = fminf(fmaxf(cy+oy, LO), HI);
    float csx = fminf(fmaxf(cx+ox, LO), HI);
    float fy = ((csy+1.0f)*64.0f - 1.0f)*0.5f;
    float fx = ((csx+1.0f)*64.0f - 1.0f)*0.5f;
    int iy = (int)rintf(fy); iy = iy<0?0:(iy>63?63:iy);
    int ix = (int)rintf(fx); ix = ix<0?0:(ix>63?63:ix);
    float qcy = -1.0f + (float)(2*iy+1)*0.015625f;
    float qcx = -1.0f + (float)(2*ix+1)*0.015625f;
    float ry = (cy-qcy)*64.0f, rx = (cx-qcx)*64.0f;
    mf[q*16 + 4 + 2*s] = ry; mf[q*16 + 5 + 2*s] = rx;
    areas[s] = fabsf(ry*rx) + 1e-9f;
    mi[q*8 + s] = iy*64 + ix;
  }
  float tot = areas[0]+areas[1]+areas[2]+areas[3];
  #pragma unroll
  for(int s=0;s<4;s++) mf[q*16 + s] = areas[3-s] / tot;

  float fy = ((cy+1.0f)*64.0f - 1.0f)*0.5f;
  float fx = ((cx+1.0f)*64.0f - 1.0f)*0.5f;
  {
    float y0 = floorf(fy), x0 = floorf(fx);
    float wy = fy-y0, wx = fx-x0;
    int y0i = (int)y0, x0i = (int)x0;
    float cw[4] = {(1.0f-wy)*(1.0f-wx), (1.0f-wy)*wx, wy*(1.0f-wx), wy*wx};
    #pragma unroll
    for(int c2=0;c2<4;c2++){
      int yi = y0i + (c2>>1), xi = x0i + (c2&1);
      bool ok = (yi>=0 && yi<64 && xi>=0 && xi<64);
      int yc = yi<0?0:(yi>63?63:yi), xc = xi<0?0:(xi>63?63:xi);
      mf[q*16 + 12 + c2] = ok ? cw[c2] : 0.0f;
      mi[q*8 + 4 + c2] = yc*64 + xc;
    }
  }
  {
    float fyb = fminf(fmaxf(fy, 0.0f), 63.0f);
    float fxb = fminf(fmaxf(fx, 0.0f), 63.0f);
    float y0 = floorf(fyb), x0 = floorf(fxb);
    float wy = fyb-y0, wx = fxb-x0;
    int y0i = (int)y0, x0i = (int)x0;
    float cw[4] = {(1.0f-wy)*(1.0f-wx), (1.0f-wy)*wx, wy*(1.0f-wx), wy*wx};
    float a0=0,a1=0,a2=0;
    #pragma unroll
    for(int c2=0;c2<4;c2++){
      int yi = y0i + (c2>>1), xi = x0i + (c2&1);
      if(yi>=0 && yi<64 && xi>=0 && xi<64){
        int idx = yi*64+xi; float wgt = cw[c2];
        a0 += inp[idx]*wgt; a1 += inp[4096+idx]*wgt; a2 += inp[8192+idx]*wgt;
      }
    }
    bil[q*3+0]=a0; bil[q*3+1]=a1; bil[q*3+2]=a2;
  }
}

// ---------------- stage-1 MLP via P-gather ----------------
template<int BR>
__global__ __launch_bounds__(256) void k_stage1(const __hip_bfloat16* __restrict__ P, const float* __restrict__ mf,
    const int* __restrict__ mi, const float* __restrict__ coord, const float* __restrict__ cell,
    const float* __restrict__ W1, const float* __restrict__ b1, __hip_bfloat16* __restrict__ out){
  __shared__ float wsm[11][256];
  int j = threadIdx.x;
  if(BR==0){
    #pragma unroll
    for(int r=0;r<8;r++) wsm[r][j] = W1[r*256 + j];
    wsm[8][j] = W1[1032*256 + j];
    wsm[9][j] = W1[1033*256 + j];
    wsm[10][j] = b1[j];
  } else {
    wsm[0][j] = W1[0*256 + j];
    wsm[1][j] = W1[1*256 + j];
    wsm[2][j] = W1[258*256 + j];
    wsm[3][j] = W1[259*256 + j];
    wsm[4][j] = b1[j];
  }
  __syncthreads();
  int q0 = blockIdx.x*32;
  for(int qq=0;qq<32;qq++){
    int q = q0+qq;
    float acc;
    const float* m = mf + q*16;
    const int* ii = mi + q*8;
    if(BR==0){
      acc = wsm[10][j];
      #pragma unroll
      for(int r=0;r<8;r++) acc += m[4+r]*wsm[r][j];
      float cly = cell[2*q]*64.0f, clx = cell[2*q+1]*64.0f;
      acc += cly*wsm[8][j] + clx*wsm[9][j];
      #pragma unroll
      for(int s=0;s<4;s++) acc += m[s]*bf2f(P[(size_t)ii[s]*1280 + s*256 + j]);
    } else {
      acc = wsm[4][j];
      float cy = coord[2*q], cx = coord[2*q+1];
      float cly = cell[2*q]*64.0f, clx = cell[2*q+1]*64.0f;
      acc += cy*wsm[0][j] + cx*wsm[1][j] + cly*wsm[2][j] + clx*wsm[3][j];
      #pragma unroll
      for(int c2=0;c2<4;c2++) acc += m[12+c2]*bf2f(P[(size_t)ii[4+c2]*1280 + 1024 + j]);
    }
    out[(size_t)q*256 + j] = f2bf(gelu_f(acc));
  }
}

// ---------------- MFMA bf16 GEMM v3: 34 KB LDS, half-tile epilogue w/ bank rotation ----------------
template<int ACT,int NRES>
__global__ __launch_bounds__(256) void k_gemm_mfma(
    const __hip_bfloat16* __restrict__ A, const __hip_bfloat16* __restrict__ BT,
    const float* __restrict__ bias, const __hip_bfloat16* __restrict__ R1,
    const __hip_bfloat16* __restrict__ R2, __hip_bfloat16* __restrict__ C,
    int M, int N, int K, int ldc){
  __shared__ __align__(1024) char smem[64*133*4];
  const int t = threadIdx.x, wave = t>>6, lane = t&63;
  const int MT = M>>7, NT = N>>7;
  const int b = blockIdx.x, xcd = b&7, i = b>>3;
  const int nt = i % NT, mtl = i / NT;
  const int m0 = (xcd*(MT>>3) + mtl) << 7, n0 = nt << 7;
  const int wr = (wave>>1)*64, wc = (wave&1)*64;
  const int lr = lane&15, lh = lane>>4;

  f32x4 acc[4][4] = {};
  const int ntiles = K>>6;
  for(int kt=0; kt<ntiles; ++kt){
    __syncthreads();
    #pragma unroll
    for(int q2=0;q2<4;q2++){
      int c = (wave*4+q2)*64 + lane;
      int row = c>>3; int k8 = (c&7) ^ (row&7);
      __hip_bfloat16* la = (__hip_bfloat16*)smem + (size_t)(wave*4+q2)*512;
      __hip_bfloat16* lb = (__hip_bfloat16*)(smem + 16384) + (size_t)(wave*4+q2)*512;
      load_lds16(A  + (size_t)(m0+row)*K + (kt*64 + k8*8), la);
      load_lds16(BT + (size_t)(n0+row)*K + (kt*64 + k8*8), lb);
    }
    __syncthreads();
    const __hip_bfloat16* Ab = (const __hip_bfloat16*)smem;
    const __hip_bfloat16* Bb = (const __hip_bfloat16*)(smem + 16384);
    #pragma unroll
    for(int kk=0;kk<2;kk++){
      bf16x8 af[4], bfr[4];
      #pragma unroll
      for(int m=0;m<4;m++){
        int row = wr + m*16 + lr;
        int p = (kk*4 + lh) ^ (row&7);
        af[m] = *reinterpret_cast<const bf16x8*>(Ab + row*64 + p*8);
      }
      #pragma unroll
      for(int n=0;n<4;n++){
        int row = wc + n*16 + lr;
        int p = (kk*4 + lh) ^ (row&7);
        bfr[n] = *reinterpret_cast<const bf16x8*>(Bb + row*64 + p*8);
      }
      #pragma unroll
      for(int m=0;m<4;m++)
        #pragma unroll
        for(int n=0;n<4;n++)
          acc[m][n] = __builtin_amdgcn_mfma_f32_16x16x32_bf16(af[m], bfr[n], acc[m][n], 0,0,0);
    }
  }

  float* epi = (float*)smem;
  const int cg = t&3;
  #pragma unroll
  for(int hf=0; hf<2; ++hf){
    __syncthreads();
    if((wave>>1) == hf){
      #pragma unroll
      for(int m=0;m<4;m++)
        #pragma unroll
        for(int n=0;n<4;n++){
          int col = wc + n*16 + lr;
          #pragma unroll
          for(int j=0;j<4;j++)
            epi[(m*16 + lh*4 + j)*133 + col] = acc[m][n][j];
        }
    }
    __syncthreads();
    const int lrow = t>>2, c0 = cg*32;
    const size_t grow = (size_t)(m0 + hf*64 + lrow);
    const float* er = epi + lrow*133;
    #pragma unroll
    for(int g0=0; g0<4; g0++){
      int g = (g0 + cg) & 3;                 // bank-conflict rotation
      int cb = c0 + g*8;
      int gc = n0 + cb;
      float v[8];
      #pragma unroll
      for(int e=0;e<8;e++) v[e] = er[cb+e];
      if(bias){
        #pragma unroll
        for(int e=0;e<8;e++) v[e] += bias[gc+e];
      }
      if(ACT==1){
        #pragma unroll
        for(int e=0;e<8;e++) v[e] = gelu_f(v[e]);
      }
      if(NRES==1 || NRES==2){
        uint4 r = *reinterpret_cast<const uint4*>(R1 + grow*ldc + gc);
        unsigned rw[4] = {r.x,r.y,r.z,r.w};
        #pragma unroll
        for(int q2=0;q2<4;q2++){ v[2*q2] += bflo(rw[q2]); v[2*q2+1] += bfhi(rw[q2]); }
      }
      if(NRES==2){
        uint4 r = *reinterpret_cast<const uint4*>(R2 + grow*ldc + gc);
        unsigned rw[4] = {r.x,r.y,r.z,r.w};
        #pragma unroll
        for(int q2=0;q2<4;q2++){ v[2*q2] += bflo(rw[q2]); v[2*q2+1] += bfhi(rw[q2]); }
      }
      uint4 o;
      o.x = pack2bf(v[0],v[1]); o.y = pack2bf(v[2],v[3]);
      o.z = pack2bf(v[4],v[5]); o.w = pack2bf(v[6],v[7]);
      *reinterpret_cast<uint4*>(C + grow*ldc + gc) = o;
    }
  }
}

// ---------------- freq conv GEMM: A gathered from featP via tap-offset ----------------
__global__ __launch_bounds__(256) void k_gfreq(
    const __hip_bfloat16* __restrict__ featP, const __hip_bfloat16* __restrict__ zpage,
    const __hip_bfloat16* __restrict__ BT, const float* __restrict__ bias,
    __hip_bfloat16* __restrict__ C){
  __shared__ __align__(1024) char smem[64*133*4];
  const int t = threadIdx.x, wave = t>>6, lane = t&63;
  const int MT = 32, NT = 2;
  const int b = blockIdx.x, xcd = b&7, i = b>>3;
  const int nt = i % NT, mtl = i / NT;
  const int m0 = (xcd*(MT>>3) + mtl) << 7, n0 = nt << 7;
  const int wr = (wave>>1)*64, wc = (wave&1)*64;
  const int lr = lane&15, lh = lane>>4;

  f32x4 acc[4][4] = {};
  for(int kt=0; kt<9; ++kt){
    int ky = kt/3, kx = kt - ky*3;
    __syncthreads();
    #pragma unroll
    for(int q2=0;q2<4;q2++){
      int c = (wave*4+q2)*64 + lane;
      int row = c>>3; int k8 = (c&7) ^ (row&7);
      __hip_bfloat16* la = (__hip_bfloat16*)smem + (size_t)(wave*4+q2)*512;
      __hip_bfloat16* lb = (__hip_bfloat16*)(smem + 16384) + (size_t)(wave*4+q2)*512;
      int pix = m0+row, y = pix>>6, x = pix&63;
      int yy = y+ky-1, xx = x+kx-1;
      const __hip_bfloat16* src = ((unsigned)yy<64u && (unsigned)xx<64u) ?
          (featP + (size_t)(yy*64+xx)*64 + k8*8) : (zpage + k8*8);
      load_lds16(src, la);
      load_lds16(BT + (size_t)(n0+row)*640 + (kt*64 + k8*8), lb);
    }
    __syncthreads();
    const __hip_bfloat16* Ab = (const __hip_bfloat16*)smem;
    const __hip_bfloat16* Bb = (const __hip_bfloat16*)(smem + 16384);
    #pragma unroll
    for(int kk=0;kk<2;kk++){
      bf16x8 af[4], bfr[4];
      #pragma unroll
      for(int m=0;m<4;m++){
        int row = wr + m*16 + lr;
        int p = (kk*4 + lh) ^ (row&7);
        af[m] = *reinterpret_cast<const bf16x8*>(Ab + row*64 + p*8);
      }
      #pragma unroll
      for(int n=0;n<4;n++){
        int row = wc + n*16 + lr;
        int p = (kk*4 + lh) ^ (row&7);
        bfr[n] = *reinterpret_cast<const bf16x8*>(Bb + row*64 + p*8);
      }
      #pragma unroll
      for(int m=0;m<4;m++)
        #pragma unroll
        for(int n=0;n<4;n++)
          acc[m][n] = __builtin_amdgcn_mfma_f32_16x16x32_bf16(af[m], bfr[n], acc[m][n], 0,0,0);
    }
  }

  float* epi = (float*)smem;
  const int cg = t&3;
  #pragma unroll
  for(int hf=0; hf<2; ++hf){
    __syncthreads();
    if((wave>>1) == hf){
      #pragma unroll
      for(int m=0;m<4;m++)
        #pragma unroll
        for(int n=0;n<4;n++){
          int col = wc + n*16 + lr;
          #pragma unroll
          for(int j=0;j<4;j++)
            epi[(m*16 + lh*4 + j)*133 + col] = acc[m][n][j];
        }
    }
    __syncthreads();
    const int lrow = t>>2, c0 = cg*32;
    const size_t grow = (size_t)(m0 + hf*64 + lrow);
    const float* er = epi + lrow*133;
    #pragma unroll
    for(int g0=0; g0<4; g0++){
      int g = (g0 + cg) & 3;
      int cb = c0 + g*8;
      int gc = n0 + cb;
      float v[8];
      #pragma unroll
      for(int e=0;e<8;e++) v[e] = er[cb+e] + bias[gc+e];
      uint4 o;
      o.x = pack2bf(v[0],v[1]); o.y = pack2bf(v[2],v[3]);
      o.z = pack2bf(v[4],v[5]); o.w = pack2bf(v[6],v[7]);
      *reinterpret_cast<uint4*>(C + grow*256 + gc) = o;
    }
  }
}

// ---------------- fused kv: GEMM(N=512 reordered) + bias + LDS-transposed LN + per-head MFMA outer product ----
__global__ __launch_bounds__(256) void k_kvln(
    const __hip_bfloat16* __restrict__ A, const __hip_bfloat16* __restrict__ BT,
    const float* __restrict__ bias, const float* __restrict__ lnw, const float* __restrict__ lnb,
    float* __restrict__ kvpart){
  __shared__ __align__(1024) char smem[34816];
  const int t = threadIdx.x, wave = t>>6, lane = t&63;
  const int MT = 512, NT = 4;
  const int b = blockIdx.x, xcd = b&7, i = b>>3;
  const int nt = i % NT, mtl = i / NT;
  const int m0 = (xcd*(MT>>3) + mtl) << 7, n0 = nt << 7;
  const int wr = (wave>>1)*64, wc = (wave&1)*64;
  const int lr = lane&15, lh = lane>>4;

  f32x4 acc[4][4] = {};
  for(int kt=0; kt<4; ++kt){
    __syncthreads();
    #pragma unroll
    for(int q2=0;q2<4;q2++){
      int c = (wave*4+q2)*64 + lane;
      int row = c>>3; int k8 = (c&7) ^ (row&7);
      __hip_bfloat16* la = (__hip_bfloat16*)smem + (size_t)(wave*4+q2)*512;
      __hip_bfloat16* lb = (__hip_bfloat16*)(smem + 16384) + (size_t)(wave*4+q2)*512;
      load_lds16(A  + (size_t)(m0+row)*256 + (kt*64 + k8*8), la);
      load_lds16(BT + (size_t)(n0+row)*256 + (kt*64 + k8*8), lb);
    }
    __syncthreads();
    const __hip_bfloat16* Ab = (const __hip_bfloat16*)smem;
    const __hip_bfloat16* Bb = (const __hip_bfloat16*)(smem + 16384);
    #pragma unroll
    for(int kk=0;kk<2;kk++){
      bf16x8 af[4], bfr[4];
      #pragma unroll
      for(int m=0;m<4;m++){
        int row = wr + m*16 + lr;
        int p = (kk*4 + lh) ^ (row&7);
        af[m] = *reinterpret_cast<const bf16x8*>(Ab + row*64 + p*8);
      }
      #pragma unroll
      for(int n=0;n<4;n++){
        int row = wc + n*16 + lr;
        int p = (kk*4 + lh) ^ (row&7);
        bfr[n] = *reinterpret_cast<const bf16x8*>(Bb + row*64 + p*8);
      }
      #pragma unroll
      for(int m=0;m<4;m++)
        #pragma unroll
        for(int n=0;n<4;n++)
          acc[m][n] = __builtin_amdgcn_mfma_f32_16x16x32_bf16(af[m], bfr[n], acc[m][n], 0,0,0);
    }
  }
  __syncthreads();

  __hip_bfloat16* knT = (__hip_bfloat16*)smem;            // [4 heads][16 cols][136 rows]
  __hip_bfloat16* vnT = (__hip_bfloat16*)(smem + 17408);
  #pragma unroll
  for(int m=0;m<4;m++){
    #pragma unroll
    for(int n=0;n<4;n++){
      int cl = wc + n*16 + lr;
      int gcol = n0 + cl;
      float bs = bias[gcol];
      int h2 = cl>>5, isV = (cl>>4)&1;
      short4 pk;
      #pragma unroll
      for(int j=0;j<4;j++) ((__hip_bfloat16*)&pk)[j] = f2bf(acc[m][n][j] + bs);
      int r = wr + m*16 + lh*4;
      __hip_bfloat16* dst = (isV ? vnT : knT) + (h2*16 + lr)*136 + r;
      *reinterpret_cast<short4*>(dst) = pk;
    }
  }
  __syncthreads();
  #pragma unroll
  for(int i4=0; i4<4; ++i4){
    int task = i4*256 + t;
    int r = task & 127, hv = task >> 7;
    int h2 = hv >> 1, isV = hv & 1;
    __hip_bfloat16* base = (isV ? vnT : knT) + (h2*16)*136 + r;
    float xs[16];
    float s=0.0f, s2=0.0f;
    #pragma unroll
    for(int c=0;c<16;c++){ xs[c] = bf2f(base[c*136]); s += xs[c]; s2 += xs[c]*xs[c]; }
    float mean = s*0.0625f;
    float var = (s2 - 16.0f*mean*mean)*(1.0f/15.0f); var = var<0.0f?0.0f:var;
    float inv = 1.0f/(sqrtf(var) + 1e-5f);
    int gbase = n0 + h2*32 + isV*16;
    #pragma unroll
    for(int c=0;c<16;c++)
      base[c*136] = f2bf(lnw[gbase+c]*((xs[c]-mean)*inv) + lnb[gbase+c]);
  }
  __syncthreads();
  f32x4 kacc = {};
  #pragma unroll
  for(int kk=0;kk<4;kk++){
    bf16x8 af  = *reinterpret_cast<const bf16x8*>(knT + (wave*16 + lr)*136 + kk*32 + lh*8);
    bf16x8 bf_ = *reinterpret_cast<const bf16x8*>(vnT + (wave*16 + lr)*136 + kk*32 + lh*8);
    kacc = __builtin_amdgcn_mfma_f32_16x16x32_bf16(af, bf_, kacc, 0,0,0);
  }
  const int mt = m0>>7;
  const int hglob = nt*4 + wave;
  #pragma unroll
  for(int j=0;j<4;j++)
    kvpart[(size_t)mt*4096 + hglob*256 + (lh*4+j)*16 + lr] = kacc[j];
}

// ---------------- G12 fused (round-14 epilogue): C = gelu(A@B1^T + c1) + (A@B2^T + b2) [+R] ----------------
template<int NRES>
__global__ __launch_bounds__(256) void k_gemm12(
    const __hip_bfloat16* __restrict__ A, const __hip_bfloat16* __restrict__ B1T,
    const float* __restrict__ c1, const __hip_bfloat16* __restrict__ B2T,
    const float* __restrict__ b2, const __hip_bfloat16* __restrict__ R,
    __hip_bfloat16* __restrict__ C){
  __shared__ __align__(1024) char smem[49152];
  const int t = threadIdx.x, wave = t>>6, lane = t&63;
  const int MT = 512, NT = 2;
  const int b = blockIdx.x, xcd = b&7, i = b>>3;
  const int nt = i % NT, mtl = i / NT;
  const int m0 = (xcd*(MT>>3) + mtl) << 7, n0 = nt << 7;
  const int wr = (wave>>1)*64, wc = (wave&1)*64;
  const int lr = lane&15, lh = lane>>4;
  f32x4 acc1[4][4] = {}, acc2[4][4] = {};
  for(int k0=0;k0<256;k0+=64){
    __syncthreads();
    #pragma unroll
    for(int q2=0;q2<4;q2++){
      int c = (wave*4+q2)*64 + lane;
      int row = c>>3; int k8 = (c&7) ^ (row&7);
      __hip_bfloat16* base = (__hip_bfloat16*)smem + (size_t)(wave*4+q2)*512;
      load_lds16(A   + (size_t)(m0+row)*256 + (k0 + k8*8), base);
      load_lds16(B1T + (size_t)(n0+row)*256 + (k0 + k8*8), base + 8192);
      load_lds16(B2T + (size_t)(n0+row)*256 + (k0 + k8*8), base + 16384);
    }
    __syncthreads();
    const __hip_bfloat16* Ab = (const __hip_bfloat16*)smem;
    #pragma unroll
    for(int kk=0;kk<2;kk++){
      bf16x8 af[4], bfr[4];
      #pragma unroll
      for(int m=0;m<4;m++){
        int row = wr + m*16 + lr;
        int p = (kk*4 + lh) ^ (row&7);
        af[m] = *reinterpret_cast<const bf16x8*>(Ab + row*64 + p*8);
      }
      #pragma unroll
      for(int n=0;n<4;n++){
        int row = wc + n*16 + lr;
        int p = (kk*4 + lh) ^ (row&7);
        bfr[n] = *reinterpret_cast<const bf16x8*>(Ab + 8192 + row*64 + p*8);
      }
      #pragma unroll
      for(int m=0;m<4;m++)
        #pragma unroll
        for(int n=0;n<4;n++)
          acc1[m][n] = __builtin_amdgcn_mfma_f32_16x16x32_bf16(af[m], bfr[n], acc1[m][n], 0,0,0);
      #pragma unroll
      for(int n=0;n<4;n++){
        int row = wc + n*16 + lr;
        int p = (kk*4 + lh) ^ (row&7);
        bfr[n] = *reinterpret_cast<const bf16x8*>(Ab + 16384 + row*64 + p*8);
      }
      #pragma unroll
      for(int m=0;m<4;m++)
        #pragma unroll
        for(int n=0;n<4;n++)
          acc2[m][n] = __builtin_amdgcn_mfma_f32_16x16x32_bf16(af[m], bfr[n], acc2[m][n], 0,0,0);
    }
  }
  float* epi = (float*)smem;
  #pragma unroll
  for(int hf=0; hf<2; ++hf){
    const int lrow = t>>2, c0 = (t&3)*32;
    const size_t grow = (size_t)(m0 + hf*64 + lrow);
    float v1[32];
    __syncthreads();
    if((wave>>1) == hf){
      #pragma unroll
      for(int m=0;m<4;m++)
        #pragma unroll
        for(int n=0;n<4;n++){
          int col = wc + n*16 + lr;
          #pragma unroll
          for(int j=0;j<4;j++)
            epi[(m*16 + lh*4 + j)*133 + col] = acc1[m][n][j];
        }
    }
    __syncthreads();
    {
      const float* er = epi + lrow*133;
      #pragma unroll
      for(int g=0; g<4; g++){
        int cb = c0 + g*8;
        #pragma unroll
        for(int e=0;e<8;e++) v1[g*8+e] = gelu_f(er[cb+e] + c1[n0+cb+e]);
      }
    }
    __syncthreads();
    if((wave>>1) == hf){
      #pragma unroll
      for(int m=0;m<4;m++)
        #pragma unroll
        for(int n=0;n<4;n++){
          int col = wc + n*16 + lr;
          #pragma unroll
          for(int j=0;j<4;j++)
            epi[(m*16 + lh*4 + j)*133 + col] = acc2[m][n][j];
        }
    }
    __syncthreads();
    {
      const float* er = epi + lrow*133;
      #pragma unroll
      for(int g=0; g<4; g++){
        int cb = c0 + g*8;
        int gc = n0 + cb;
        float v[8];
        #pragma unroll
        for(int e=0;e<8;e++) v[e] = v1[g*8+e] + er[cb+e] + b2[gc+e];
        if(NRES==1){
          uint4 r = *reinterpret_cast<const uint4*>(R + grow*256 + gc);
          unsigned rw[4] = {r.x,r.y,r.z,r.w};
          #pragma unroll
          for(int q2=0;q2<4;q2++){ v[2*q2] += bflo(rw[q2]); v[2*q2+1] += bfhi(rw[q2]); }
        }
        uint4 o;
        o.x = pack2bf(v[0],v[1]); o.y = pack2bf(v[2],v[3]);
        o.z = pack2bf(v[4],v[5]); o.w = pack2bf(v[6],v[7]);
        *reinterpret_cast<uint4*>(C + grow*256 + gc) = o;
      }
    }
  }
}

// ---------------- fc3+final fused: part[nt][row][3] ----------------
__global__ __launch_bounds__(256) void k_gemmF(
    const __hip_bfloat16* __restrict__ A, const __hip_bfloat16* __restrict__ BT,
    const float* __restrict__ bias, const float* __restrict__ W4,
    float* __restrict__ part){
  __shared__ __align__(1024) char smem[64*133*4];
  __shared__ float w4s[768];
  const int t = threadIdx.x, wave = t>>6, lane = t&63;
  const int MT = 512, NT = 2;
  const int b = blockIdx.x, xcd = b&7, i = b>>3;
  const int nt = i % NT, mtl = i / NT;
  const int m0 = (xcd*(MT>>3) + mtl) << 7, n0 = nt << 7;
  const int wr = (wave>>1)*64, wc = (wave&1)*64;
  const int lr = lane&15, lh = lane>>4;
  for(int l=t;l<768;l+=256) w4s[l] = W4[l];

  f32x4 acc[4][4] = {};
  for(int kt=0; kt<4; ++kt){
    __syncthreads();
    #pragma unroll
    for(int q2=0;q2<4;q2++){
      int c = (wave*4+q2)*64 + lane;
      int row = c>>3; int k8 = (c&7) ^ (row&7);
      __hip_bfloat16* la = (__hip_bfloat16*)smem + (size_t)(wave*4+q2)*512;
      __hip_bfloat16* lb = (__hip_bfloat16*)(smem + 16384) + (size_t)(wave*4+q2)*512;
      load_lds16(A  + (size_t)(m0+row)*256 + (kt*64 + k8*8), la);
      load_lds16(BT + (size_t)(n0+row)*256 + (kt*64 + k8*8), lb);
    }
    __syncthreads();
    const __hip_bfloat16* Ab = (const __hip_bfloat16*)smem;
    const __hip_bfloat16* Bb = (const __hip_bfloat16*)(smem + 16384);
    #pragma unroll
    for(int kk=0;kk<2;kk++){
      bf16x8 af[4], bfr[4];
      #pragma unroll
      for(int m=0;m<4;m++){
        int row = wr + m*16 + lr;
        int p = (kk*4 + lh) ^ (row&7);
        af[m] = *reinterpret_cast<const bf16x8*>(Ab + row*64 + p*8);
      }
      #pragma unroll
      for(int n=0;n<4;n++){
        int row = wc + n*16 + lr;
        int p = (kk*4 + lh) ^ (row&7);
        bfr[n] = *reinterpret_cast<const bf16x8*>(Bb + row*64 + p*8);
      }
      #pragma unroll
      for(int m=0;m<4;m++)
        #pragma unroll
        for(int n=0;n<4;n++)
          acc[m][n] = __builtin_amdgcn_mfma_f32_16x16x32_bf16(af[m], bfr[n], acc[m][n], 0,0,0);
    }
  }

  float* epi = (float*)smem;
  const int cg = t&3;
  #pragma unroll
  for(int hf=0; hf<2; ++hf){
    __syncthreads();
    if((wave>>1) == hf){
      #pragma unroll
      for(int m=0;m<4;m++)
        #pragma unroll
        for(int n=0;n<4;n++){
          int col = wc + n*16 + lr;
          #pragma unroll
          for(int j=0;j<4;j++)
            epi[(m*16 + lh*4 + j)*133 + col] = acc[m][n][j];
        }
    }
    __syncthreads();
    {
      const int lrow = t>>2, c0 = cg*32;
      const float* er = epi + lrow*133;
      float s0=0.f, s1=0.f, s2=0.f;
      #pragma unroll
      for(int g0=0; g0<4; g0++){
        int g = (g0 + cg) & 3;
        int cb = c0 + g*8;
        int gc = n0 + cb;
        #pragma unroll
        for(int e=0;e<8;e++){
          float v = gelu_f(er[cb+e] + bias[gc+e]);
          s0 += v*w4s[(gc+e)*3+0];
          s1 += v*w4s[(gc+e)*3+1];
          s2 += v*w4s[(gc+e)*3+2];
        }
      }
      s0 += __shfl_xor(s0,1); s0 += __shfl_xor(s0,2);
      s1 += __shfl_xor(s1,1); s1 += __shfl_xor(s1,2);
      s2 += __shfl_xor(s2,1); s2 += __shfl_xor(s2,2);
      if((t&3)==0){
        float* pp = part + (size_t)nt*196608 + (size_t)(m0 + hf*64 + (t>>2))*3;
        pp[0]=s0; pp[1]=s1; pp[2]=s2;
      }
    }
  }
}

__global__ __launch_bounds__(256) void k_combine(const float* __restrict__ part, const float* __restrict__ b4,
    const float* __restrict__ bil, float* __restrict__ out){
  int i = blockIdx.x*256 + threadIdx.x;
  int j = i - (i/3)*3;
  out[i] = part[i] + part[196608 + i] + b4[j] + bil[i];
}

__global__ __launch_bounds__(256) void k_kvred(const float* __restrict__ kvpart, float* __restrict__ kv){
  __shared__ float sm[256];
  int b = blockIdx.x, t = threadIdx.x;
  int d = t & 15, seg = t >> 4;
  float s = 0.0f;
  for(int k=0;k<32;k++) s += kvpart[(size_t)(seg*32+k)*4096 + b*16 + d];
  sm[t] = s;
  __syncthreads();
  if(t < 16){
    float r = 0.0f;
    #pragma unroll
    for(int g=0; g<16; g++) r += sm[g*16 + t];
    kv[b*16 + t] = r * (1.0f/65536.0f);
  }
}

// ---------------- fold q-projection through kv ----------------
__global__ __launch_bounds__(256) void k_fold(const __hip_bfloat16* __restrict__ qT,
    const float* __restrict__ biasq, const float* __restrict__ kv,
    __hip_bfloat16* __restrict__ WfoldT, float* __restrict__ bfold){
  int n = blockIdx.x, t = threadIdx.x;
  int h = n>>4, d = n&15;
  float s = 0.0f;
  #pragma unroll
  for(int c=0;c<16;c++)
    s += bf2f(qT[(size_t)(h*16+c)*256 + t]) * kv[h*256 + c*16 + d];
  WfoldT[(size_t)n*256 + t] = f2bf(s);
  if(t==0){
    float b=0.0f;
    #pragma unroll
    for(int c=0;c<16;c++) b += biasq[h*16+c]*kv[h*256+c*16+d];
    bfold[n]=b;
  }
}

extern "C" void kernel_launch(void* const* d_in, const int* in_sizes, int n_in,
                              void* d_out, int out_size, void* d_ws, size_t ws_size,
                              hipStream_t stream){
  (void)in_sizes; (void)n_in; (void)out_size;
  const float* inp     = (const float*)d_in[0];
  const float* coord   = (const float*)d_in[1];
  const float* cell    = (const float*)d_in[2];
  const float* enc_w   = (const float*)d_in[3];
  const float* enc_b   = (const float*)d_in[4];
  const float* freq_w  = (const float*)d_in[5];
  const float* freq_b  = (const float*)d_in[6];
  const float* out0_w1 = (const float*)d_in[7];
  const float* out0_b1 = (const float*)d_in[8];
  const float* out0_w2 = (const float*)d_in[9];
  const float* out0_b2 = (const float*)d_in[10];
  const float* out1_w1 = (const float*)d_in[11];
  const float* out1_b1 = (const float*)d_in[12];
  const float* out1_w2 = (const float*)d_in[13];
  const float* out1_b2 = (const float*)d_in[14];
  const float* fc1_w1  = (const float*)d_in[15];
  const float* fc1_b1  = (const float*)d_in[16];
  const float* fc1_w2  = (const float*)d_in[17];
  const float* fc1_b2  = (const float*)d_in[18];
  const float* fc2_w1  = (const float*)d_in[19];
  const float* fc2_b1  = (const float*)d_in[20];
  const float* fc2_w2  = (const float*)d_in[21];
  const float* fc2_b2  = (const float*)d_in[22];
  const float* qkv_w[2] = {(const float*)d_in[23], (const float*)d_in[31]};
  const float* qkv_b[2] = {(const float*)d_in[24], (const float*)d_in[32]};
  const float* kln_w[2] = {(const float*)d_in[25], (const float*)d_in[33]};
  const float* kln_b[2] = {(const float*)d_in[26], (const float*)d_in[34]};
  const float* vln_w[2] = {(const float*)d_in[27], (const float*)d_in[35]};
  const float* vln_b[2] = {(const float*)d_in[28], (const float*)d_in[36]};
  const float* proj_w[2] = {(const float*)d_in[29], (const float*)d_in[37]};
  const float* proj_b[2] = {(const float*)d_in[30], (const float*)d_in[38]};
  const float* b2arr[2] = {out0_b2, out1_b2};

  char* wsp = (char*)d_ws; size_t off = 0;
  auto alloc = [&](size_t bytes)->void*{ void* p = wsp + off; off += (bytes + 255) & ~(size_t)255; return p; };
  __hip_bfloat16* featP = (__hip_bfloat16*)alloc(262144ull*2);
  __hip_bfloat16* zpage = (__hip_bfloat16*)alloc(256ull*2);
  __hip_bfloat16* wtb = (__hip_bfloat16*)alloc(2097152ull*2);
  __hip_bfloat16* P = (__hip_bfloat16*)alloc(5242880ull*2);
  float* mf     = (float*)alloc(65536ull*16*4);
  int*   mi     = (int*)alloc(65536ull*8*4);
  float* bil    = (float*)alloc(65536ull*3*4);
  float* kvpart = (float*)alloc(512ull*4096*4);
  float* kv0    = (float*)alloc(4096ull*4);
  float* kv1    = (float*)alloc(4096ull*4);
  float* biasbuf= (float*)alloc(1536ull*4);
  float* lnbuf  = (float*)alloc(2048ull*4);
  float* bfold  = (float*)alloc(256ull*4);
  float* c1     = (float*)alloc(256ull*4);
  float* bkvh   = (float*)alloc(1024ull*4);
  float* part   = (float*)alloc(2ull*196608*4);
  __hip_bfloat16* wfoldT = (__hip_bfloat16*)alloc(65536ull*2);
  __hip_bfloat16* bufA = (__hip_bfloat16*)alloc(65536ull*256*2);
  __hip_bfloat16* bufB = (__hip_bfloat16*)alloc(65536ull*256*2);
  __hip_bfloat16* bufC = (__hip_bfloat16*)alloc(65536ull*256*2);
  if(off > ws_size) return;

  __hip_bfloat16* w2T[2]   = {wtb,          wtb + 65536};
  __hip_bfloat16* projT[2] = {wtb + 131072, wtb + 196608};
  __hip_bfloat16* fc1w1T   =  wtb + 262144;
  __hip_bfloat16* fc1w2T   =  wtb + 327680;
  __hip_bfloat16* fc2w1T   =  wtb + 393216;
  __hip_bfloat16* qT[2]    = {wtb + 458752, wtb + 655360};
  __hip_bfloat16* kvT[2]   = {wtb + 524288, wtb + 720896};
  __hip_bfloat16* wfreqT   =  wtb + 851968;   // 256 x 640
  __hip_bfloat16* wblkT    =  wtb + 1015808;  // 1280 x 256
  __hip_bfloat16* kvh2T[2] = {wtb + 1343488, wtb + 1474560};
  __hip_bfloat16* Ubuf     =  wtb + 1605632;
  __hip_bfloat16* M1T      =  wtb + 1671168;
  __hip_bfloat16* freqB = bufB;               // 4096 x 256

  k_conv1<<<1024,256,0,stream>>>(inp, enc_w, enc_b, featP);
  k_wfreq<<<256,256,0,stream>>>(freq_w, wfreqT);
  k_wblk<<<1280,256,0,stream>>>(out0_w1, out1_w1, wblkT);

  PrepArgs pa;
  pa.d[0]  = {out0_w2,   w2T[0],   0, 0};
  pa.d[1]  = {out1_w2,   w2T[1],   0, 0};
  pa.d[2]  = {proj_w[0], projT[0], 0, 0};
  pa.d[3]  = {proj_w[1], projT[1], 0, 0};
  pa.d[4]  = {fc1_w1,    fc1w1T,   0, 0};
  pa.d[5]  = {fc1_w2,    fc1w2T,   0, 0};
  pa.d[6]  = {fc2_w1,    fc2w1T,   0, 0};
  pa.d[7]  = {qkv_w[0],  qT[0],    1, 0};
  pa.d[8]  = {qkv_w[0],  kvT[0],   17, 0};
  pa.d[9]  = {qkv_w[0],  kvT[0]+65536, 33, 0};
  pa.d[10] = {qkv_w[1],  qT[1],    1, 0};
  pa.d[11] = {qkv_w[1],  kvT[1],   17, 0};
  pa.d[12] = {qkv_w[1],  kvT[1]+65536, 33, 0};
  k_prep<<<13*256,256,0,stream>>>(pa);
  k_biasperm<<<1,256,0,stream>>>(qkv_b[0], qkv_b[1],
      kln_w[0], kln_b[0], vln_w[0], vln_b[0], kln_w[1], kln_b[1], vln_w[1], vln_b[1],
      biasbuf, lnbuf, lnbuf + 1024, zpage);

  for(int br=0;br<2;br++){
    k_smallmmR<<<512,256,0,stream>>>(kvT[br], w2T[br], kvh2T[br]);
    k_bkv2R<<<2,256,0,stream>>>(b2arr[br], biasbuf + br*768 + 256, kvT[br], bkvh + br*512);
  }

  k_gfreq<<<64,256,0,stream>>>(featP, zpage, wfreqT, freq_b, freqB);
  k_gemm_mfma<0,0><<<320,256,0,stream>>>(freqB, wblkT, nullptr, nullptr,nullptr, P, 4096,1280,256, 1280);

  k_sample<<<256,256,0,stream>>>(coord, inp, mf, mi, bil);

  for(int br=0;br<2;br++){
    if(br==0) k_stage1<0><<<2048,256,0,stream>>>(P, mf, mi, coord, cell, out0_w1, out0_b1, bufA);
    else      k_stage1<1><<<2048,256,0,stream>>>(P, mf, mi, coord, cell, out1_w1, out1_b1, bufA);
    k_kvln<<<2048,256,0,stream>>>(bufA, kvh2T[br], bkvh + br*512, lnbuf + br*512, lnbuf + 1024 + br*512, kvpart);
    float* kvf = br ? kv1 : kv0;
    k_kvred<<<256,256,0,stream>>>(kvpart, kvf);
    k_fold<<<256,256,0,stream>>>(qT[br], biasbuf + br*768, kvf, wfoldT, bfold);
    k_smallmm<1><<<256,256,0,stream>>>(wfoldT, w2T[br], Ubuf);
    k_smallmm<0><<<256,256,0,stream>>>(projT[br], Ubuf, M1T);
    k_cvec<<<1,256,0,stream>>>(b2arr[br], bfold, wfoldT, projT[br], proj_b[br], c1);
    if(br==0)
      k_gemm12<0><<<1024,256,0,stream>>>(bufA, M1T, c1, w2T[0], b2arr[0], nullptr, bufC);
    else
      k_gemm12<1><<<1024,256,0,stream>>>(bufA, M1T, c1, w2T[1], b2arr[1], bufC, bufC);
  }
  // fc tail: bufC = f
  k_gemm_mfma<1,0><<<1024,256,0,stream>>>(bufC, fc1w1T, fc1_b1, nullptr,nullptr, bufA, 65536,256,256, 256);
  k_gemm_mfma<1,1><<<1024,256,0,stream>>>(bufA, fc1w2T, fc1_b2, bufC, nullptr, bufB, 65536,256,256, 256);
  k_gemmF<<<1024,256,0,stream>>>(bufB, fc2w1T, fc2_b1, fc2_w2, part);
  k_combine<<<768,256,0,stream>>>(part, fc2_b2, bil, (float*)d_out);
}

// Round 17
// 483.998 us; speedup vs baseline: 1.2397x; 1.1434x over previous
//
#include <hip/hip_runtime.h>
#include <hip/hip_bf16.h>

#define DI __device__ __forceinline__

DI float gelu_f(float x){ return 0.5f*x*(1.0f + erff(x*0.7071067811865476f)); }
DI float bf2f(__hip_bfloat16 b){ return __bfloat162float(b); }
DI __hip_bfloat16 f2bf(float f){ return __float2bfloat16(f); }
DI float bflo(unsigned u){ return __uint_as_float(u<<16); }
DI float bfhi(unsigned u){ return __uint_as_float(u & 0xffff0000u); }
DI unsigned pack2bf(float a, float b){
  __hip_bfloat16 ha = f2bf(a), hb = f2bf(b);
  unsigned short ua = *reinterpret_cast<unsigned short*>(&ha);
  unsigned short ub = *reinterpret_cast<unsigned short*>(&hb);
  return (unsigned)ua | ((unsigned)ub<<16);
}

typedef __attribute__((ext_vector_type(8))) short bf16x8;
typedef __attribute__((ext_vector_type(4))) float f32x4;

template<typename T>
DI void load_lds16(const T* g, T* l){
  __builtin_amdgcn_global_load_lds((const __attribute__((address_space(1))) void*)g,
                                   (__attribute__((address_space(3))) void*)l, 16, 0, 0);
}

DI int kvmap(int j){ int h=j>>5, idx=j&31; return idx<16 ? h*16+idx : 256+h*16+(idx-16); }

// ---------------- conv1: inp -> featP (4096 pix, 64 ch) bf16 pixel-major ----------------
__global__ __launch_bounds__(256) void k_conv1(const float* __restrict__ inp, const float* __restrict__ w,
                                               const float* __restrict__ b, __hip_bfloat16* __restrict__ featP){
  int idx = blockIdx.x*256 + threadIdx.x;
  int o = idx & 63, p = idx >> 6, y = p >> 6, x = p & 63;
  float acc = b[o];
  #pragma unroll
  for(int c=0;c<3;c++){
    #pragma unroll
    for(int ky=0;ky<3;ky++){
      int yy = y+ky-1; if((unsigned)yy >= 64u) continue;
      #pragma unroll
      for(int kx=0;kx<3;kx++){
        int xx = x+kx-1; if((unsigned)xx >= 64u) continue;
        acc += inp[c*4096 + yy*64 + xx] * w[o*27 + c*9 + ky*3 + kx];
      }
    }
  }
  featP[p*64 + o] = f2bf(acc);
}

// ---------------- wfreq permute ----------------
__global__ __launch_bounds__(256) void k_wfreq(const float* __restrict__ fw, __hip_bfloat16* __restrict__ wt){
  int o = blockIdx.x, t = threadIdx.x;
  #pragma unroll
  for(int it=0; it<3; it++){
    int k = it*256 + t;
    if(k >= 640) break;
    float v = 0.0f;
    if(k < 576){
      int tap = k>>6, c = k&63;
      v = fw[o*576 + c*9 + tap];
    }
    wt[(size_t)o*640 + k] = f2bf(v);
  }
}

// ---------------- wblkT ----------------
__global__ __launch_bounds__(256) void k_wblk(const float* __restrict__ w0, const float* __restrict__ w1,
                                              __hip_bfloat16* __restrict__ wt){
  int j = blockIdx.x, kk = threadIdx.x;
  float v;
  if(j < 1024){
    int s = j>>8, n = j&255;
    v = w0[(8 + 256*s + kk)*256 + n];
  } else {
    v = w1[(2 + kk)*256 + (j-1024)];
  }
  wt[(size_t)j*256 + kk] = f2bf(v);
}

// ---------------- batched weight transpose / qkv head-permute ----------------
struct PrepDesc { const float* src; __hip_bfloat16* dst; int mode; int pad; };
struct PrepArgs { PrepDesc d[13]; };
__global__ __launch_bounds__(256) void k_prep(PrepArgs a){
  int u = blockIdx.x >> 8, b = blockIdx.x & 255, t = threadIdx.x;
  PrepDesc d = a.d[u];
  float v;
  if(d.mode == 0) v = d.src[t*256 + b];
  else { int col = 48*(b>>4) + (d.mode-1) + (b&15); v = d.src[t*768 + col]; }
  d.dst[b*256 + t] = f2bf(v);
}

// permuted qkv biases + reordered LN params + zero guard page
__global__ __launch_bounds__(256) void k_biasperm(const float* __restrict__ b0, const float* __restrict__ b1,
    const float* kw0, const float* kb0, const float* vw0, const float* vb0,
    const float* kw1, const float* kb1, const float* vw1, const float* vb1,
    float* __restrict__ dstB, float* __restrict__ lnw2, float* __restrict__ lnb2,
    __hip_bfloat16* __restrict__ zpage){
  int t = threadIdx.x;
  zpage[t] = f2bf(0.0f);
  #pragma unroll
  for(int br=0;br<2;br++){
    const float* s = br ? b1 : b0;
    #pragma unroll
    for(int part=0;part<3;part++)
      dstB[br*768 + part*256 + t] = s[48*(t>>4) + part*16 + (t&15)];
  }
  #pragma unroll
  for(int br=0;br<2;br++){
    #pragma unroll
    for(int half=0;half<2;half++){
      int j = half*256 + t;
      int h = j>>5, idx = j&31;
      bool isK = idx<16;
      int c = isK ? idx : idx-16;
      const float* w = isK ? (br?kw1:kw0) : (br?vw1:vw0);
      const float* bb= isK ? (br?kb1:kb0) : (br?vb1:vb0);
      lnw2[br*512 + j] = w[h*16+c];
      lnb2[br*512 + j] = bb[h*16+c];
    }
  }
}

// ---------------- small row-major matmul: C = (A[+I]) @ B ----------------
template<int ADDI>
__global__ __launch_bounds__(256) void k_smallmm(const __hip_bfloat16* __restrict__ A,
    const __hip_bfloat16* __restrict__ B, __hip_bfloat16* __restrict__ C){
  __shared__ float ar[256];
  int i = blockIdx.x, t = threadIdx.x;
  float a = bf2f(A[(size_t)i*256 + t]);
  if(ADDI && t==i) a += 1.0f;
  ar[t] = a;
  __syncthreads();
  float a0=0.f,a1=0.f,a2=0.f,a3=0.f;
  for(int l=0;l<256;l+=4){
    a0 += ar[l+0]*bf2f(B[(l+0)*256 + t]);
    a1 += ar[l+1]*bf2f(B[(l+1)*256 + t]);
    a2 += ar[l+2]*bf2f(B[(l+2)*256 + t]);
    a3 += ar[l+3]*bf2f(B[(l+3)*256 + t]);
  }
  C[(size_t)i*256 + t] = f2bf((a0+a1)+(a2+a3));
}

__global__ __launch_bounds__(256) void k_smallmmR(const __hip_bfloat16* __restrict__ A,
    const __hip_bfloat16* __restrict__ B, __hip_bfloat16* __restrict__ C){
  __shared__ float ar[256];
  int j = blockIdx.x, t = threadIdx.x;
  int src = kvmap(j);
  ar[t] = bf2f(A[(size_t)src*256 + t]);
  __syncthreads();
  float a0=0.f,a1=0.f,a2=0.f,a3=0.f;
  for(int l=0;l<256;l+=4){
    a0 += ar[l+0]*bf2f(B[(l+0)*256 + t]);
    a1 += ar[l+1]*bf2f(B[(l+1)*256 + t]);
    a2 += ar[l+2]*bf2f(B[(l+2)*256 + t]);
    a3 += ar[l+3]*bf2f(B[(l+3)*256 + t]);
  }
  C[(size_t)j*256 + t] = f2bf((a0+a1)+(a2+a3));
}

__global__ __launch_bounds__(256) void k_bkv2R(const float* __restrict__ b2, const float* __restrict__ biaskv,
    const __hip_bfloat16* __restrict__ kvT_, float* __restrict__ outb){
  __shared__ float s_b2[256];
  int t = threadIdx.x; int n = blockIdx.x*256 + t;
  int src = kvmap(n);
  s_b2[t] = b2[t];
  __syncthreads();
  float v = biaskv[src];
  for(int l=0;l<256;l++) v += s_b2[l]*bf2f(kvT_[(size_t)src*256 + l]);
  outb[n] = v;
}

// ---------------- c1 = ((b2@(Wfold+I)+bfold) @ Wp) + bp ----------------
__global__ __launch_bounds__(256) void k_cvec(const float* __restrict__ b2, const float* __restrict__ bfold,
    const __hip_bfloat16* __restrict__ WfoldT, const __hip_bfloat16* __restrict__ projT_,
    const float* __restrict__ bp, float* __restrict__ c1){
  __shared__ float s_b2[256], s_r[256];
  int t = threadIdx.x;
  s_b2[t] = b2[t];
  __syncthreads();
  float r = s_b2[t] + bfold[t];
  for(int l=0;l<256;l++) r += s_b2[l]*bf2f(WfoldT[(size_t)t*256 + l]);
  s_r[t] = r;
  __syncthreads();
  float c = bp[t];
  for(int l=0;l<256;l++) c += s_r[l]*bf2f(projT_[(size_t)t*256 + l]);
  c1[t] = c;
}

// ---------------- per-query sampling geometry + result_bil ----------------
__global__ __launch_bounds__(256) void k_sample(const float* __restrict__ coord, const float* __restrict__ inp,
    float* __restrict__ mf, int* __restrict__ mi, float* __restrict__ bil){
  int q = blockIdx.x*256 + threadIdx.x;
  float cy = coord[2*q], cx = coord[2*q+1];
  const float LO = (float)(-1.0 + 1e-6), HI = (float)(1.0 - 1e-6);
  const float ONEG = (float)(-1.0/64.0 + 1e-6), OPOS = (float)(1.0/64.0 + 1e-6);
  float areas[4];
  #pragma unroll
  for(int s=0;s<4;s++){
    float oy = (s<2)?ONEG:OPOS;
    float ox = (s&1)?OPOS:ONEG;
    float csy = fminf(fmaxf(cy+oy, LO), HI);
    float csx = fminf(fmaxf(cx+ox, LO), HI);
    float fy = ((csy+1.0f)*64.0f - 1.0f)*0.5f;
    float fx = ((csx+1.0f)*64.0f - 1.0f)*0.5f;
    int iy = (int)rintf(fy); iy = iy<0?0:(iy>63?63:iy);
    int ix = (int)rintf(fx); ix = ix<0?0:(ix>63?63:ix);
    float qcy = -1.0f + (float)(2*iy+1)*0.015625f;
    float qcx = -1.0f + (float)(2*ix+1)*0.015625f;
    float ry = (cy-qcy)*64.0f, rx = (cx-qcx)*64.0f;
    mf[q*16 + 4 + 2*s] = ry; mf[q*16 + 5 + 2*s] = rx;
    areas[s] = fabsf(ry*rx) + 1e-9f;
    mi[q*8 + s] = iy*64 + ix;
  }
  float tot = areas[0]+areas[1]+areas[2]+areas[3];
  #pragma unroll
  for(int s=0;s<4;s++) mf[q*16 + s] = areas[3-s] / tot;

  float fy = ((cy+1.0f)*64.0f - 1.0f)*0.5f;
  float fx = ((cx+1.0f)*64.0f - 1.0f)*0.5f;
  {
    float y0 = floorf(fy), x0 = floorf(fx);
    float wy = fy-y0, wx = fx-x0;
    int y0i = (int)y0, x0i = (int)x0;
    float cw[4] = {(1.0f-wy)*(1.0f-wx), (1.0f-wy)*wx, wy*(1.0f-wx), wy*wx};
    #pragma unroll
    for(int c2=0;c2<4;c2++){
      int yi = y0i + (c2>>1), xi = x0i + (c2&1);
      bool ok = (yi>=0 && yi<64 && xi>=0 && xi<64);
      int yc = yi<0?0:(yi>63?63:yi), xc = xi<0?0:(xi>63?63:xi);
      mf[q*16 + 12 + c2] = ok ? cw[c2] : 0.0f;
      mi[q*8 + 4 + c2] = yc*64 + xc;
    }
  }
  {
    float fyb = fminf(fmaxf(fy, 0.0f), 63.0f);
    float fxb = fminf(fmaxf(fx, 0.0f), 63.0f);
    float y0 = floorf(fyb), x0 = floorf(fxb);
    float wy = fyb-y0, wx = fxb-x0;
    int y0i = (int)y0, x0i = (int)x0;
    float cw[4] = {(1.0f-wy)*(1.0f-wx), (1.0f-wy)*wx, wy*(1.0f-wx), wy*wx};
    float a0=0,a1=0,a2=0;
    #pragma unroll
    for(int c2=0;c2<4;c2++){
      int yi = y0i + (c2>>1), xi = x0i + (c2&1);
      if(yi>=0 && yi<64 && xi>=0 && xi<64){
        int idx = yi*64+xi; float wgt = cw[c2];
        a0 += inp[idx]*wgt; a1 += inp[4096+idx]*wgt; a2 += inp[8192+idx]*wgt;
      }
    }
    bil[q*3+0]=a0; bil[q*3+1]=a1; bil[q*3+2]=a2;
  }
}

// ---------------- stage-1 MLP via P-gather ----------------
template<int BR>
__global__ __launch_bounds__(256) void k_stage1(const __hip_bfloat16* __restrict__ P, const float* __restrict__ mf,
    const int* __restrict__ mi, const float* __restrict__ coord, const float* __restrict__ cell,
    const float* __restrict__ W1, const float* __restrict__ b1, __hip_bfloat16* __restrict__ out){
  __shared__ float wsm[11][256];
  int j = threadIdx.x;
  if(BR==0){
    #pragma unroll
    for(int r=0;r<8;r++) wsm[r][j] = W1[r*256 + j];
    wsm[8][j] = W1[1032*256 + j];
    wsm[9][j] = W1[1033*256 + j];
    wsm[10][j] = b1[j];
  } else {
    wsm[0][j] = W1[0*256 + j];
    wsm[1][j] = W1[1*256 + j];
    wsm[2][j] = W1[258*256 + j];
    wsm[3][j] = W1[259*256 + j];
    wsm[4][j] = b1[j];
  }
  __syncthreads();
  int q0 = blockIdx.x*32;
  for(int qq=0;qq<32;qq++){
    int q = q0+qq;
    float acc;
    const float* m = mf + q*16;
    const int* ii = mi + q*8;
    if(BR==0){
      acc = wsm[10][j];
      #pragma unroll
      for(int r=0;r<8;r++) acc += m[4+r]*wsm[r][j];
      float cly = cell[2*q]*64.0f, clx = cell[2*q+1]*64.0f;
      acc += cly*wsm[8][j] + clx*wsm[9][j];
      #pragma unroll
      for(int s=0;s<4;s++) acc += m[s]*bf2f(P[(size_t)ii[s]*1280 + s*256 + j]);
    } else {
      acc = wsm[4][j];
      float cy = coord[2*q], cx = coord[2*q+1];
      float cly = cell[2*q]*64.0f, clx = cell[2*q+1]*64.0f;
      acc += cy*wsm[0][j] + cx*wsm[1][j] + cly*wsm[2][j] + clx*wsm[3][j];
      #pragma unroll
      for(int c2=0;c2<4;c2++) acc += m[12+c2]*bf2f(P[(size_t)ii[4+c2]*1280 + 1024 + j]);
    }
    out[(size_t)q*256 + j] = f2bf(gelu_f(acc));
  }
}

// ---------------- MFMA bf16 GEMM v3: 34 KB LDS, half-tile epilogue w/ bank rotation ----------------
template<int ACT,int NRES>
__global__ __launch_bounds__(256) void k_gemm_mfma(
    const __hip_bfloat16* __restrict__ A, const __hip_bfloat16* __restrict__ BT,
    const float* __restrict__ bias, const __hip_bfloat16* __restrict__ R1,
    const __hip_bfloat16* __restrict__ R2, __hip_bfloat16* __restrict__ C,
    int M, int N, int K, int ldc){
  __shared__ __align__(1024) char smem[64*133*4];
  const int t = threadIdx.x, wave = t>>6, lane = t&63;
  const int MT = M>>7, NT = N>>7;
  const int b = blockIdx.x, xcd = b&7, i = b>>3;
  const int nt = i % NT, mtl = i / NT;
  const int m0 = (xcd*(MT>>3) + mtl) << 7, n0 = nt << 7;
  const int wr = (wave>>1)*64, wc = (wave&1)*64;
  const int lr = lane&15, lh = lane>>4;

  f32x4 acc[4][4] = {};
  const int ntiles = K>>6;
  for(int kt=0; kt<ntiles; ++kt){
    __syncthreads();
    #pragma unroll
    for(int q2=0;q2<4;q2++){
      int c = (wave*4+q2)*64 + lane;
      int row = c>>3; int k8 = (c&7) ^ (row&7);
      __hip_bfloat16* la = (__hip_bfloat16*)smem + (size_t)(wave*4+q2)*512;
      __hip_bfloat16* lb = (__hip_bfloat16*)(smem + 16384) + (size_t)(wave*4+q2)*512;
      load_lds16(A  + (size_t)(m0+row)*K + (kt*64 + k8*8), la);
      load_lds16(BT + (size_t)(n0+row)*K + (kt*64 + k8*8), lb);
    }
    __syncthreads();
    const __hip_bfloat16* Ab = (const __hip_bfloat16*)smem;
    const __hip_bfloat16* Bb = (const __hip_bfloat16*)(smem + 16384);
    #pragma unroll
    for(int kk=0;kk<2;kk++){
      bf16x8 af[4], bfr[4];
      #pragma unroll
      for(int m=0;m<4;m++){
        int row = wr + m*16 + lr;
        int p = (kk*4 + lh) ^ (row&7);
        af[m] = *reinterpret_cast<const bf16x8*>(Ab + row*64 + p*8);
      }
      #pragma unroll
      for(int n=0;n<4;n++){
        int row = wc + n*16 + lr;
        int p = (kk*4 + lh) ^ (row&7);
        bfr[n] = *reinterpret_cast<const bf16x8*>(Bb + row*64 + p*8);
      }
      #pragma unroll
      for(int m=0;m<4;m++)
        #pragma unroll
        for(int n=0;n<4;n++)
          acc[m][n] = __builtin_amdgcn_mfma_f32_16x16x32_bf16(af[m], bfr[n], acc[m][n], 0,0,0);
    }
  }

  float* epi = (float*)smem;
  const int cg = t&3;
  #pragma unroll
  for(int hf=0; hf<2; ++hf){
    __syncthreads();
    if((wave>>1) == hf){
      #pragma unroll
      for(int m=0;m<4;m++)
        #pragma unroll
        for(int n=0;n<4;n++){
          int col = wc + n*16 + lr;
          #pragma unroll
          for(int j=0;j<4;j++)
            epi[(m*16 + lh*4 + j)*133 + col] = acc[m][n][j];
        }
    }
    __syncthreads();
    const int lrow = t>>2, c0 = cg*32;
    const size_t grow = (size_t)(m0 + hf*64 + lrow);
    const float* er = epi + lrow*133;
    #pragma unroll
    for(int g0=0; g0<4; g0++){
      int g = (g0 + cg) & 3;                 // bank-conflict rotation
      int cb = c0 + g*8;
      int gc = n0 + cb;
      float v[8];
      #pragma unroll
      for(int e=0;e<8;e++) v[e] = er[cb+e];
      if(bias){
        #pragma unroll
        for(int e=0;e<8;e++) v[e] += bias[gc+e];
      }
      if(ACT==1){
        #pragma unroll
        for(int e=0;e<8;e++) v[e] = gelu_f(v[e]);
      }
      if(NRES==1 || NRES==2){
        uint4 r = *reinterpret_cast<const uint4*>(R1 + grow*ldc + gc);
        unsigned rw[4] = {r.x,r.y,r.z,r.w};
        #pragma unroll
        for(int q2=0;q2<4;q2++){ v[2*q2] += bflo(rw[q2]); v[2*q2+1] += bfhi(rw[q2]); }
      }
      if(NRES==2){
        uint4 r = *reinterpret_cast<const uint4*>(R2 + grow*ldc + gc);
        unsigned rw[4] = {r.x,r.y,r.z,r.w};
        #pragma unroll
        for(int q2=0;q2<4;q2++){ v[2*q2] += bflo(rw[q2]); v[2*q2+1] += bfhi(rw[q2]); }
      }
      uint4 o;
      o.x = pack2bf(v[0],v[1]); o.y = pack2bf(v[2],v[3]);
      o.z = pack2bf(v[4],v[5]); o.w = pack2bf(v[6],v[7]);
      *reinterpret_cast<uint4*>(C + grow*ldc + gc) = o;
    }
  }
}

// ---------------- freq conv GEMM: A gathered from featP via tap-offset ----------------
__global__ __launch_bounds__(256) void k_gfreq(
    const __hip_bfloat16* __restrict__ featP, const __hip_bfloat16* __restrict__ zpage,
    const __hip_bfloat16* __restrict__ BT, const float* __restrict__ bias,
    __hip_bfloat16* __restrict__ C){
  __shared__ __align__(1024) char smem[64*133*4];
  const int t = threadIdx.x, wave = t>>6, lane = t&63;
  const int MT = 32, NT = 2;
  const int b = blockIdx.x, xcd = b&7, i = b>>3;
  const int nt = i % NT, mtl = i / NT;
  const int m0 = (xcd*(MT>>3) + mtl) << 7, n0 = nt << 7;
  const int wr = (wave>>1)*64, wc = (wave&1)*64;
  const int lr = lane&15, lh = lane>>4;

  f32x4 acc[4][4] = {};
  for(int kt=0; kt<9; ++kt){
    int ky = kt/3, kx = kt - ky*3;
    __syncthreads();
    #pragma unroll
    for(int q2=0;q2<4;q2++){
      int c = (wave*4+q2)*64 + lane;
      int row = c>>3; int k8 = (c&7) ^ (row&7);
      __hip_bfloat16* la = (__hip_bfloat16*)smem + (size_t)(wave*4+q2)*512;
      __hip_bfloat16* lb = (__hip_bfloat16*)(smem + 16384) + (size_t)(wave*4+q2)*512;
      int pix = m0+row, y = pix>>6, x = pix&63;
      int yy = y+ky-1, xx = x+kx-1;
      const __hip_bfloat16* src = ((unsigned)yy<64u && (unsigned)xx<64u) ?
          (featP + (size_t)(yy*64+xx)*64 + k8*8) : (zpage + k8*8);
      load_lds16(src, la);
      load_lds16(BT + (size_t)(n0+row)*640 + (kt*64 + k8*8), lb);
    }
    __syncthreads();
    const __hip_bfloat16* Ab = (const __hip_bfloat16*)smem;
    const __hip_bfloat16* Bb = (const __hip_bfloat16*)(smem + 16384);
    #pragma unroll
    for(int kk=0;kk<2;kk++){
      bf16x8 af[4], bfr[4];
      #pragma unroll
      for(int m=0;m<4;m++){
        int row = wr + m*16 + lr;
        int p = (kk*4 + lh) ^ (row&7);
        af[m] = *reinterpret_cast<const bf16x8*>(Ab + row*64 + p*8);
      }
      #pragma unroll
      for(int n=0;n<4;n++){
        int row = wc + n*16 + lr;
        int p = (kk*4 + lh) ^ (row&7);
        bfr[n] = *reinterpret_cast<const bf16x8*>(Bb + row*64 + p*8);
      }
      #pragma unroll
      for(int m=0;m<4;m++)
        #pragma unroll
        for(int n=0;n<4;n++)
          acc[m][n] = __builtin_amdgcn_mfma_f32_16x16x32_bf16(af[m], bfr[n], acc[m][n], 0,0,0);
    }
  }

  float* epi = (float*)smem;
  const int cg = t&3;
  #pragma unroll
  for(int hf=0; hf<2; ++hf){
    __syncthreads();
    if((wave>>1) == hf){
      #pragma unroll
      for(int m=0;m<4;m++)
        #pragma unroll
        for(int n=0;n<4;n++){
          int col = wc + n*16 + lr;
          #pragma unroll
          for(int j=0;j<4;j++)
            epi[(m*16 + lh*4 + j)*133 + col] = acc[m][n][j];
        }
    }
    __syncthreads();
    const int lrow = t>>2, c0 = cg*32;
    const size_t grow = (size_t)(m0 + hf*64 + lrow);
    const float* er = epi + lrow*133;
    #pragma unroll
    for(int g0=0; g0<4; g0++){
      int g = (g0 + cg) & 3;
      int cb = c0 + g*8;
      int gc = n0 + cb;
      float v[8];
      #pragma unroll
      for(int e=0;e<8;e++) v[e] = er[cb+e] + bias[gc+e];
      uint4 o;
      o.x = pack2bf(v[0],v[1]); o.y = pack2bf(v[2],v[3]);
      o.z = pack2bf(v[4],v[5]); o.w = pack2bf(v[6],v[7]);
      *reinterpret_cast<uint4*>(C + grow*256 + gc) = o;
    }
  }
}

// ---------------- fused kv: GEMM(N=512 reordered) + bias + LDS-transposed LN + per-head MFMA outer product ----
__global__ __launch_bounds__(256) void k_kvln(
    const __hip_bfloat16* __restrict__ A, const __hip_bfloat16* __restrict__ BT,
    const float* __restrict__ bias, const float* __restrict__ lnw, const float* __restrict__ lnb,
    float* __restrict__ kvpart){
  __shared__ __align__(1024) char smem[34816];
  const int t = threadIdx.x, wave = t>>6, lane = t&63;
  const int MT = 512, NT = 4;
  const int b = blockIdx.x, xcd = b&7, i = b>>3;
  const int nt = i % NT, mtl = i / NT;
  const int m0 = (xcd*(MT>>3) + mtl) << 7, n0 = nt << 7;
  const int wr = (wave>>1)*64, wc = (wave&1)*64;
  const int lr = lane&15, lh = lane>>4;

  f32x4 acc[4][4] = {};
  for(int kt=0; kt<4; ++kt){
    __syncthreads();
    #pragma unroll
    for(int q2=0;q2<4;q2++){
      int c = (wave*4+q2)*64 + lane;
      int row = c>>3; int k8 = (c&7) ^ (row&7);
      __hip_bfloat16* la = (__hip_bfloat16*)smem + (size_t)(wave*4+q2)*512;
      __hip_bfloat16* lb = (__hip_bfloat16*)(smem + 16384) + (size_t)(wave*4+q2)*512;
      load_lds16(A  + (size_t)(m0+row)*256 + (kt*64 + k8*8), la);
      load_lds16(BT + (size_t)(n0+row)*256 + (kt*64 + k8*8), lb);
    }
    __syncthreads();
    const __hip_bfloat16* Ab = (const __hip_bfloat16*)smem;
    const __hip_bfloat16* Bb = (const __hip_bfloat16*)(smem + 16384);
    #pragma unroll
    for(int kk=0;kk<2;kk++){
      bf16x8 af[4], bfr[4];
      #pragma unroll
      for(int m=0;m<4;m++){
        int row = wr + m*16 + lr;
        int p = (kk*4 + lh) ^ (row&7);
        af[m] = *reinterpret_cast<const bf16x8*>(Ab + row*64 + p*8);
      }
      #pragma unroll
      for(int n=0;n<4;n++){
        int row = wc + n*16 + lr;
        int p = (kk*4 + lh) ^ (row&7);
        bfr[n] = *reinterpret_cast<const bf16x8*>(Bb + row*64 + p*8);
      }
      #pragma unroll
      for(int m=0;m<4;m++)
        #pragma unroll
        for(int n=0;n<4;n++)
          acc[m][n] = __builtin_amdgcn_mfma_f32_16x16x32_bf16(af[m], bfr[n], acc[m][n], 0,0,0);
    }
  }
  __syncthreads();

  __hip_bfloat16* knT = (__hip_bfloat16*)smem;            // [4 heads][16 cols][136 rows]
  __hip_bfloat16* vnT = (__hip_bfloat16*)(smem + 17408);
  #pragma unroll
  for(int m=0;m<4;m++){
    #pragma unroll
    for(int n=0;n<4;n++){
      int cl = wc + n*16 + lr;
      int gcol = n0 + cl;
      float bs = bias[gcol];
      int h2 = cl>>5, isV = (cl>>4)&1;
      short4 pk;
      #pragma unroll
      for(int j=0;j<4;j++) ((__hip_bfloat16*)&pk)[j] = f2bf(acc[m][n][j] + bs);
      int r = wr + m*16 + lh*4;
      __hip_bfloat16* dst = (isV ? vnT : knT) + (h2*16 + lr)*136 + r;
      *reinterpret_cast<short4*>(dst) = pk;
    }
  }
  __syncthreads();
  #pragma unroll
  for(int i4=0; i4<4; ++i4){
    int task = i4*256 + t;
    int r = task & 127, hv = task >> 7;
    int h2 = hv >> 1, isV = hv & 1;
    __hip_bfloat16* base = (isV ? vnT : knT) + (h2*16)*136 + r;
    float xs[16];
    float s=0.0f, s2=0.0f;
    #pragma unroll
    for(int c=0;c<16;c++){ xs[c] = bf2f(base[c*136]); s += xs[c]; s2 += xs[c]*xs[c]; }
    float mean = s*0.0625f;
    float var = (s2 - 16.0f*mean*mean)*(1.0f/15.0f); var = var<0.0f?0.0f:var;
    float inv = 1.0f/(sqrtf(var) + 1e-5f);
    int gbase = n0 + h2*32 + isV*16;
    #pragma unroll
    for(int c=0;c<16;c++)
      base[c*136] = f2bf(lnw[gbase+c]*((xs[c]-mean)*inv) + lnb[gbase+c]);
  }
  __syncthreads();
  f32x4 kacc = {};
  #pragma unroll
  for(int kk=0;kk<4;kk++){
    bf16x8 af  = *reinterpret_cast<const bf16x8*>(knT + (wave*16 + lr)*136 + kk*32 + lh*8);
    bf16x8 bf_ = *reinterpret_cast<const bf16x8*>(vnT + (wave*16 + lr)*136 + kk*32 + lh*8);
    kacc = __builtin_amdgcn_mfma_f32_16x16x32_bf16(af, bf_, kacc, 0,0,0);
  }
  const int mt = m0>>7;
  const int hglob = nt*4 + wave;
  #pragma unroll
  for(int j=0;j<4;j++)
    kvpart[(size_t)mt*4096 + hglob*256 + (lh*4+j)*16 + lr] = kacc[j];
}

// ---------------- G12 fused v3 (8 waves): C = gelu(A@B1^T + c1) + (A@B2^T + b2) [+R] ----------------
template<int NRES>
__global__ __launch_bounds__(512) void k_gemm12(
    const __hip_bfloat16* __restrict__ A, const __hip_bfloat16* __restrict__ B1T,
    const float* __restrict__ c1, const __hip_bfloat16* __restrict__ B2T,
    const float* __restrict__ b2, const __hip_bfloat16* __restrict__ R,
    __hip_bfloat16* __restrict__ C){
  __shared__ __align__(1024) char smem[49152];
  const int t = threadIdx.x, wave = t>>6, lane = t&63;
  const int MT = 512, NT = 2;
  const int b = blockIdx.x, xcd = b&7, i = b>>3;
  const int nt = i % NT, mtl = i / NT;
  const int m0 = (xcd*(MT>>3) + mtl) << 7, n0 = nt << 7;
  const int wr = (wave>>2)*64, wc = (wave&3)*32;     // 8 waves: 2M x 4N sub-slices
  const int lr = lane&15, lh = lane>>4;
  f32x4 acc1[4][2] = {}, acc2[4][2] = {};
  for(int k0=0;k0<256;k0+=64){
    __syncthreads();
    #pragma unroll
    for(int q2=0;q2<2;q2++){
      int c = (wave*2+q2)*64 + lane;
      int row = c>>3; int k8 = (c&7) ^ (row&7);
      __hip_bfloat16* base = (__hip_bfloat16*)smem + (size_t)(wave*2+q2)*512;
      load_lds16(A   + (size_t)(m0+row)*256 + (k0 + k8*8), base);
      load_lds16(B1T + (size_t)(n0+row)*256 + (k0 + k8*8), base + 8192);
      load_lds16(B2T + (size_t)(n0+row)*256 + (k0 + k8*8), base + 16384);
    }
    __syncthreads();
    const __hip_bfloat16* Ab = (const __hip_bfloat16*)smem;
    #pragma unroll
    for(int kk=0;kk<2;kk++){
      bf16x8 af[4], bfr[2];
      #pragma unroll
      for(int m=0;m<4;m++){
        int row = wr + m*16 + lr;
        int p = (kk*4 + lh) ^ (row&7);
        af[m] = *reinterpret_cast<const bf16x8*>(Ab + row*64 + p*8);
      }
      #pragma unroll
      for(int n=0;n<2;n++){
        int row = wc + n*16 + lr;
        int p = (kk*4 + lh) ^ (row&7);
        bfr[n] = *reinterpret_cast<const bf16x8*>(Ab + 8192 + row*64 + p*8);
      }
      #pragma unroll
      for(int m=0;m<4;m++)
        #pragma unroll
        for(int n=0;n<2;n++)
          acc1[m][n] = __builtin_amdgcn_mfma_f32_16x16x32_bf16(af[m], bfr[n], acc1[m][n], 0,0,0);
      #pragma unroll
      for(int n=0;n<2;n++){
        int row = wc + n*16 + lr;
        int p = (kk*4 + lh) ^ (row&7);
        bfr[n] = *reinterpret_cast<const bf16x8*>(Ab + 16384 + row*64 + p*8);
      }
      #pragma unroll
      for(int m=0;m<4;m++)
        #pragma unroll
        for(int n=0;n<2;n++)
          acc2[m][n] = __builtin_amdgcn_mfma_f32_16x16x32_bf16(af[m], bfr[n], acc2[m][n], 0,0,0);
    }
  }
  float* epi = (float*)smem;
  #pragma unroll
  for(int hf=0; hf<2; ++hf){
    const int lrow = t>>3, c0 = (t&7)*16;
    const size_t grow = (size_t)(m0 + hf*64 + lrow);
    float v1[16];
    __syncthreads();
    if((wave>>2) == hf){
      #pragma unroll
      for(int m=0;m<4;m++)
        #pragma unroll
        for(int n=0;n<2;n++){
          int col = wc + n*16 + lr;
          #pragma unroll
          for(int j=0;j<4;j++)
            epi[(m*16 + lh*4 + j)*133 + col] = acc1[m][n][j];
        }
    }
    __syncthreads();
    {
      const float* er = epi + lrow*133;
      #pragma unroll
      for(int e=0;e<16;e++) v1[e] = gelu_f(er[c0+e] + c1[n0+c0+e]);
    }
    __syncthreads();
    if((wave>>2) == hf){
      #pragma unroll
      for(int m=0;m<4;m++)
        #pragma unroll
        for(int n=0;n<2;n++){
          int col = wc + n*16 + lr;
          #pragma unroll
          for(int j=0;j<4;j++)
            epi[(m*16 + lh*4 + j)*133 + col] = acc2[m][n][j];
        }
    }
    __syncthreads();
    {
      const float* er = epi + lrow*133;
      #pragma unroll
      for(int half=0; half<2; half++){
        int cb = c0 + half*8;
        int gc = n0 + cb;
        float v[8];
        #pragma unroll
        for(int e=0;e<8;e++) v[e] = v1[half*8+e] + er[cb+e] + b2[gc+e];
        if(NRES==1){
          uint4 r = *reinterpret_cast<const uint4*>(R + grow*256 + gc);
          unsigned rw[4] = {r.x,r.y,r.z,r.w};
          #pragma unroll
          for(int q2=0;q2<4;q2++){ v[2*q2] += bflo(rw[q2]); v[2*q2+1] += bfhi(rw[q2]); }
        }
        uint4 o;
        o.x = pack2bf(v[0],v[1]); o.y = pack2bf(v[2],v[3]);
        o.z = pack2bf(v[4],v[5]); o.w = pack2bf(v[6],v[7]);
        *reinterpret_cast<uint4*>(C + grow*256 + gc) = o;
      }
    }
  }
}

// ---------------- fc3+final fused: part[nt][row][3] ----------------
__global__ __launch_bounds__(256) void k_gemmF(
    const __hip_bfloat16* __restrict__ A, const __hip_bfloat16* __restrict__ BT,
    const float* __restrict__ bias, const float* __restrict__ W4,
    float* __restrict__ part){
  __shared__ __align__(1024) char smem[64*133*4];
  __shared__ float w4s[768];
  const int t = threadIdx.x, wave = t>>6, lane = t&63;
  const int MT = 512, NT = 2;
  const int b = blockIdx.x, xcd = b&7, i = b>>3;
  const int nt = i % NT, mtl = i / NT;
  const int m0 = (xcd*(MT>>3) + mtl) << 7, n0 = nt << 7;
  const int wr = (wave>>1)*64, wc = (wave&1)*64;
  const int lr = lane&15, lh = lane>>4;
  for(int l=t;l<768;l+=256) w4s[l] = W4[l];

  f32x4 acc[4][4] = {};
  for(int kt=0; kt<4; ++kt){
    __syncthreads();
    #pragma unroll
    for(int q2=0;q2<4;q2++){
      int c = (wave*4+q2)*64 + lane;
      int row = c>>3; int k8 = (c&7) ^ (row&7);
      __hip_bfloat16* la = (__hip_bfloat16*)smem + (size_t)(wave*4+q2)*512;
      __hip_bfloat16* lb = (__hip_bfloat16*)(smem + 16384) + (size_t)(wave*4+q2)*512;
      load_lds16(A  + (size_t)(m0+row)*256 + (kt*64 + k8*8), la);
      load_lds16(BT + (size_t)(n0+row)*256 + (kt*64 + k8*8), lb);
    }
    __syncthreads();
    const __hip_bfloat16* Ab = (const __hip_bfloat16*)smem;
    const __hip_bfloat16* Bb = (const __hip_bfloat16*)(smem + 16384);
    #pragma unroll
    for(int kk=0;kk<2;kk++){
      bf16x8 af[4], bfr[4];
      #pragma unroll
      for(int m=0;m<4;m++){
        int row = wr + m*16 + lr;
        int p = (kk*4 + lh) ^ (row&7);
        af[m] = *reinterpret_cast<const bf16x8*>(Ab + row*64 + p*8);
      }
      #pragma unroll
      for(int n=0;n<4;n++){
        int row = wc + n*16 + lr;
        int p = (kk*4 + lh) ^ (row&7);
        bfr[n] = *reinterpret_cast<const bf16x8*>(Bb + row*64 + p*8);
      }
      #pragma unroll
      for(int m=0;m<4;m++)
        #pragma unroll
        for(int n=0;n<4;n++)
          acc[m][n] = __builtin_amdgcn_mfma_f32_16x16x32_bf16(af[m], bfr[n], acc[m][n], 0,0,0);
    }
  }

  float* epi = (float*)smem;
  const int cg = t&3;
  #pragma unroll
  for(int hf=0; hf<2; ++hf){
    __syncthreads();
    if((wave>>1) == hf){
      #pragma unroll
      for(int m=0;m<4;m++)
        #pragma unroll
        for(int n=0;n<4;n++){
          int col = wc + n*16 + lr;
          #pragma unroll
          for(int j=0;j<4;j++)
            epi[(m*16 + lh*4 + j)*133 + col] = acc[m][n][j];
        }
    }
    __syncthreads();
    {
      const int lrow = t>>2, c0 = cg*32;
      const float* er = epi + lrow*133;
      float s0=0.f, s1=0.f, s2=0.f;
      #pragma unroll
      for(int g0=0; g0<4; g0++){
        int g = (g0 + cg) & 3;
        int cb = c0 + g*8;
        int gc = n0 + cb;
        #pragma unroll
        for(int e=0;e<8;e++){
          float v = gelu_f(er[cb+e] + bias[gc+e]);
          s0 += v*w4s[(gc+e)*3+0];
          s1 += v*w4s[(gc+e)*3+1];
          s2 += v*w4s[(gc+e)*3+2];
        }
      }
      s0 += __shfl_xor(s0,1); s0 += __shfl_xor(s0,2);
      s1 += __shfl_xor(s1,1); s1 += __shfl_xor(s1,2);
      s2 += __shfl_xor(s2,1); s2 += __shfl_xor(s2,2);
      if((t&3)==0){
        float* pp = part + (size_t)nt*196608 + (size_t)(m0 + hf*64 + (t>>2))*3;
        pp[0]=s0; pp[1]=s1; pp[2]=s2;
      }
    }
  }
}

__global__ __launch_bounds__(256) void k_combine(const float* __restrict__ part, const float* __restrict__ b4,
    const float* __restrict__ bil, float* __restrict__ out){
  int i = blockIdx.x*256 + threadIdx.x;
  int j = i - (i/3)*3;
  out[i] = part[i] + part[196608 + i] + b4[j] + bil[i];
}

__global__ __launch_bounds__(256) void k_kvred(const float* __restrict__ kvpart, float* __restrict__ kv){
  __shared__ float sm[256];
  int b = blockIdx.x, t = threadIdx.x;
  int d = t & 15, seg = t >> 4;
  float s = 0.0f;
  for(int k=0;k<32;k++) s += kvpart[(size_t)(seg*32+k)*4096 + b*16 + d];
  sm[t] = s;
  __syncthreads();
  if(t < 16){
    float r = 0.0f;
    #pragma unroll
    for(int g=0; g<16; g++) r += sm[g*16 + t];
    kv[b*16 + t] = r * (1.0f/65536.0f);
  }
}

// ---------------- fold q-projection through kv ----------------
__global__ __launch_bounds__(256) void k_fold(const __hip_bfloat16* __restrict__ qT,
    const float* __restrict__ biasq, const float* __restrict__ kv,
    __hip_bfloat16* __restrict__ WfoldT, float* __restrict__ bfold){
  int n = blockIdx.x, t = threadIdx.x;
  int h = n>>4, d = n&15;
  float s = 0.0f;
  #pragma unroll
  for(int c=0;c<16;c++)
    s += bf2f(qT[(size_t)(h*16+c)*256 + t]) * kv[h*256 + c*16 + d];
  WfoldT[(size_t)n*256 + t] = f2bf(s);
  if(t==0){
    float b=0.0f;
    #pragma unroll
    for(int c=0;c<16;c++) b += biasq[h*16+c]*kv[h*256+c*16+d];
    bfold[n]=b;
  }
}

extern "C" void kernel_launch(void* const* d_in, const int* in_sizes, int n_in,
                              void* d_out, int out_size, void* d_ws, size_t ws_size,
                              hipStream_t stream){
  (void)in_sizes; (void)n_in; (void)out_size;
  const float* inp     = (const float*)d_in[0];
  const float* coord   = (const float*)d_in[1];
  const float* cell    = (const float*)d_in[2];
  const float* enc_w   = (const float*)d_in[3];
  const float* enc_b   = (const float*)d_in[4];
  const float* freq_w  = (const float*)d_in[5];
  const float* freq_b  = (const float*)d_in[6];
  const float* out0_w1 = (const float*)d_in[7];
  const float* out0_b1 = (const float*)d_in[8];
  const float* out0_w2 = (const float*)d_in[9];
  const float* out0_b2 = (const float*)d_in[10];
  const float* out1_w1 = (const float*)d_in[11];
  const float* out1_b1 = (const float*)d_in[12];
  const float* out1_w2 = (const float*)d_in[13];
  const float* out1_b2 = (const float*)d_in[14];
  const float* fc1_w1  = (const float*)d_in[15];
  const float* fc1_b1  = (const float*)d_in[16];
  const float* fc1_w2  = (const float*)d_in[17];
  const float* fc1_b2  = (const float*)d_in[18];
  const float* fc2_w1  = (const float*)d_in[19];
  const float* fc2_b1  = (const float*)d_in[20];
  const float* fc2_w2  = (const float*)d_in[21];
  const float* fc2_b2  = (const float*)d_in[22];
  const float* qkv_w[2] = {(const float*)d_in[23], (const float*)d_in[31]};
  const float* qkv_b[2] = {(const float*)d_in[24], (const float*)d_in[32]};
  const float* kln_w[2] = {(const float*)d_in[25], (const float*)d_in[33]};
  const float* kln_b[2] = {(const float*)d_in[26], (const float*)d_in[34]};
  const float* vln_w[2] = {(const float*)d_in[27], (const float*)d_in[35]};
  const float* vln_b[2] = {(const float*)d_in[28], (const float*)d_in[36]};
  const float* proj_w[2] = {(const float*)d_in[29], (const float*)d_in[37]};
  const float* proj_b[2] = {(const float*)d_in[30], (const float*)d_in[38]};
  const float* b2arr[2] = {out0_b2, out1_b2};

  char* wsp = (char*)d_ws; size_t off = 0;
  auto alloc = [&](size_t bytes)->void*{ void* p = wsp + off; off += (bytes + 255) & ~(size_t)255; return p; };
  __hip_bfloat16* featP = (__hip_bfloat16*)alloc(262144ull*2);
  __hip_bfloat16* zpage = (__hip_bfloat16*)alloc(256ull*2);
  __hip_bfloat16* wtb = (__hip_bfloat16*)alloc(2097152ull*2);
  __hip_bfloat16* P = (__hip_bfloat16*)alloc(5242880ull*2);
  float* mf     = (float*)alloc(65536ull*16*4);
  int*   mi     = (int*)alloc(65536ull*8*4);
  float* bil    = (float*)alloc(65536ull*3*4);
  float* kvpart = (float*)alloc(512ull*4096*4);
  float* kv0    = (float*)alloc(4096ull*4);
  float* kv1    = (float*)alloc(4096ull*4);
  float* biasbuf= (float*)alloc(1536ull*4);
  float* lnbuf  = (float*)alloc(2048ull*4);
  float* bfold  = (float*)alloc(256ull*4);
  float* c1     = (float*)alloc(256ull*4);
  float* bkvh   = (float*)alloc(1024ull*4);
  float* part   = (float*)alloc(2ull*196608*4);
  __hip_bfloat16* wfoldT = (__hip_bfloat16*)alloc(65536ull*2);
  __hip_bfloat16* bufA = (__hip_bfloat16*)alloc(65536ull*256*2);
  __hip_bfloat16* bufB = (__hip_bfloat16*)alloc(65536ull*256*2);
  __hip_bfloat16* bufC = (__hip_bfloat16*)alloc(65536ull*256*2);
  if(off > ws_size) return;

  __hip_bfloat16* w2T[2]   = {wtb,          wtb + 65536};
  __hip_bfloat16* projT[2] = {wtb + 131072, wtb + 196608};
  __hip_bfloat16* fc1w1T   =  wtb + 262144;
  __hip_bfloat16* fc1w2T   =  wtb + 327680;
  __hip_bfloat16* fc2w1T   =  wtb + 393216;
  __hip_bfloat16* qT[2]    = {wtb + 458752, wtb + 655360};
  __hip_bfloat16* kvT[2]   = {wtb + 524288, wtb + 720896};
  __hip_bfloat16* wfreqT   =  wtb + 851968;   // 256 x 640
  __hip_bfloat16* wblkT    =  wtb + 1015808;  // 1280 x 256
  __hip_bfloat16* kvh2T[2] = {wtb + 1343488, wtb + 1474560};
  __hip_bfloat16* Ubuf     =  wtb + 1605632;
  __hip_bfloat16* M1T      =  wtb + 1671168;
  __hip_bfloat16* freqB = bufB;               // 4096 x 256

  k_conv1<<<1024,256,0,stream>>>(inp, enc_w, enc_b, featP);
  k_wfreq<<<256,256,0,stream>>>(freq_w, wfreqT);
  k_wblk<<<1280,256,0,stream>>>(out0_w1, out1_w1, wblkT);

  PrepArgs pa;
  pa.d[0]  = {out0_w2,   w2T[0],   0, 0};
  pa.d[1]  = {out1_w2,   w2T[1],   0, 0};
  pa.d[2]  = {proj_w[0], projT[0], 0, 0};
  pa.d[3]  = {proj_w[1], projT[1], 0, 0};
  pa.d[4]  = {fc1_w1,    fc1w1T,   0, 0};
  pa.d[5]  = {fc1_w2,    fc1w2T,   0, 0};
  pa.d[6]  = {fc2_w1,    fc2w1T,   0, 0};
  pa.d[7]  = {qkv_w[0],  qT[0],    1, 0};
  pa.d[8]  = {qkv_w[0],  kvT[0],   17, 0};
  pa.d[9]  = {qkv_w[0],  kvT[0]+65536, 33, 0};
  pa.d[10] = {qkv_w[1],  qT[1],    1, 0};
  pa.d[11] = {qkv_w[1],  kvT[1],   17, 0};
  pa.d[12] = {qkv_w[1],  kvT[1]+65536, 33, 0};
  k_prep<<<13*256,256,0,stream>>>(pa);
  k_biasperm<<<1,256,0,stream>>>(qkv_b[0], qkv_b[1],
      kln_w[0], kln_b[0], vln_w[0], vln_b[0], kln_w[1], kln_b[1], vln_w[1], vln_b[1],
      biasbuf, lnbuf, lnbuf + 1024, zpage);

  for(int br=0;br<2;br++){
    k_smallmmR<<<512,256,0,stream>>>(kvT[br], w2T[br], kvh2T[br]);
    k_bkv2R<<<2,256,0,stream>>>(b2arr[br], biasbuf + br*768 + 256, kvT[br], bkvh + br*512);
  }

  k_gfreq<<<64,256,0,stream>>>(featP, zpage, wfreqT, freq_b, freqB);
  k_gemm_mfma<0,0><<<320,256,0,stream>>>(freqB, wblkT, nullptr, nullptr,nullptr, P, 4096,1280,256, 1280);

  k_sample<<<256,256,0,stream>>>(coord, inp, mf, mi, bil);

  for(int br=0;br<2;br++){
    if(br==0) k_stage1<0><<<2048,256,0,stream>>>(P, mf, mi, coord, cell, out0_w1, out0_b1, bufA);
    else      k_stage1<1><<<2048,256,0,stream>>>(P, mf, mi, coord, cell, out1_w1, out1_b1, bufA);
    k_kvln<<<2048,256,0,stream>>>(bufA, kvh2T[br], bkvh + br*512, lnbuf + br*512, lnbuf + 1024 + br*512, kvpart);
    float* kvf = br ? kv1 : kv0;
    k_kvred<<<256,256,0,stream>>>(kvpart, kvf);
    k_fold<<<256,256,0,stream>>>(qT[br], biasbuf + br*768, kvf, wfoldT, bfold);
    k_smallmm<1><<<256,256,0,stream>>>(wfoldT, w2T[br], Ubuf);
    k_smallmm<0><<<256,256,0,stream>>>(projT[br], Ubuf, M1T);
    k_cvec<<<1,256,0,stream>>>(b2arr[br], bfold, wfoldT, projT[br], proj_b[br], c1);
    if(br==0)
      k_gemm12<0><<<1024,512,0,stream>>>(bufA, M1T, c1, w2T[0], b2arr[0], nullptr, bufC);
    else
      k_gemm12<1><<<1024,512,0,stream>>>(bufA, M1T, c1, w2T[1], b2arr[1], bufC, bufC);
  }
  // fc tail: bufC = f
  k_gemm_mfma<1,0><<<1024,256,0,stream>>>(bufC, fc1w1T, fc1_b1, nullptr,nullptr, bufA, 65536,256,256, 256);
  k_gemm_mfma<1,1><<<1024,256,0,stream>>>(bufA, fc1w2T, fc1_b2, bufC, nullptr, bufB, 65536,256,256, 256);
  k_gemmF<<<1024,256,0,stream>>>(bufB, fc2w1T, fc2_b1, fc2_w2, part);
  k_combine<<<768,256,0,stream>>>(part, fc2_b2, bil, (float*)d_out);
}

// Round 18
// 475.877 us; speedup vs baseline: 1.2609x; 1.0171x over previous
//
#include <hip/hip_runtime.h>
#include <hip/hip_bf16.h>

#define DI __device__ __forceinline__

DI float gelu_f(float x){ return 0.5f*x*(1.0f + erff(x*0.7071067811865476f)); }
DI float bf2f(__hip_bfloat16 b){ return __bfloat162float(b); }
DI __hip_bfloat16 f2bf(float f){ return __float2bfloat16(f); }
DI float bflo(unsigned u){ return __uint_as_float(u<<16); }
DI float bfhi(unsigned u){ return __uint_as_float(u & 0xffff0000u); }
DI unsigned pack2bf(float a, float b){
  __hip_bfloat16 ha = f2bf(a), hb = f2bf(b);
  unsigned short ua = *reinterpret_cast<unsigned short*>(&ha);
  unsigned short ub = *reinterpret_cast<unsigned short*>(&hb);
  return (unsigned)ua | ((unsigned)ub<<16);
}

typedef __attribute__((ext_vector_type(8))) short bf16x8;
typedef __attribute__((ext_vector_type(4))) float f32x4;

template<typename T>
DI void load_lds16(const T* g, T* l){
  __builtin_amdgcn_global_load_lds((const __attribute__((address_space(1))) void*)g,
                                   (__attribute__((address_space(3))) void*)l, 16, 0, 0);
}

DI int kvmap(int j){ int h=j>>5, idx=j&31; return idx<16 ? h*16+idx : 256+h*16+(idx-16); }

// ---------------- conv1: inp -> featP (4096 pix, 64 ch) bf16 pixel-major ----------------
__global__ __launch_bounds__(256) void k_conv1(const float* __restrict__ inp, const float* __restrict__ w,
                                               const float* __restrict__ b, __hip_bfloat16* __restrict__ featP){
  int idx = blockIdx.x*256 + threadIdx.x;
  int o = idx & 63, p = idx >> 6, y = p >> 6, x = p & 63;
  float acc = b[o];
  #pragma unroll
  for(int c=0;c<3;c++){
    #pragma unroll
    for(int ky=0;ky<3;ky++){
      int yy = y+ky-1; if((unsigned)yy >= 64u) continue;
      #pragma unroll
      for(int kx=0;kx<3;kx++){
        int xx = x+kx-1; if((unsigned)xx >= 64u) continue;
        acc += inp[c*4096 + yy*64 + xx] * w[o*27 + c*9 + ky*3 + kx];
      }
    }
  }
  featP[p*64 + o] = f2bf(acc);
}

// ---------------- wfreq permute ----------------
__global__ __launch_bounds__(256) void k_wfreq(const float* __restrict__ fw, __hip_bfloat16* __restrict__ wt){
  int o = blockIdx.x, t = threadIdx.x;
  #pragma unroll
  for(int it=0; it<3; it++){
    int k = it*256 + t;
    if(k >= 640) break;
    float v = 0.0f;
    if(k < 576){
      int tap = k>>6, c = k&63;
      v = fw[o*576 + c*9 + tap];
    }
    wt[(size_t)o*640 + k] = f2bf(v);
  }
}

// ---------------- wblkT ----------------
__global__ __launch_bounds__(256) void k_wblk(const float* __restrict__ w0, const float* __restrict__ w1,
                                              __hip_bfloat16* __restrict__ wt){
  int j = blockIdx.x, kk = threadIdx.x;
  float v;
  if(j < 1024){
    int s = j>>8, n = j&255;
    v = w0[(8 + 256*s + kk)*256 + n];
  } else {
    v = w1[(2 + kk)*256 + (j-1024)];
  }
  wt[(size_t)j*256 + kk] = f2bf(v);
}

// ---------------- batched weight transpose / qkv head-permute ----------------
struct PrepDesc { const float* src; __hip_bfloat16* dst; int mode; int pad; };
struct PrepArgs { PrepDesc d[13]; };
__global__ __launch_bounds__(256) void k_prep(PrepArgs a){
  int u = blockIdx.x >> 8, b = blockIdx.x & 255, t = threadIdx.x;
  PrepDesc d = a.d[u];
  float v;
  if(d.mode == 0) v = d.src[t*256 + b];
  else { int col = 48*(b>>4) + (d.mode-1) + (b&15); v = d.src[t*768 + col]; }
  d.dst[b*256 + t] = f2bf(v);
}

// permuted qkv biases + reordered LN params + zero guard page
__global__ __launch_bounds__(256) void k_biasperm(const float* __restrict__ b0, const float* __restrict__ b1,
    const float* kw0, const float* kb0, const float* vw0, const float* vb0,
    const float* kw1, const float* kb1, const float* vw1, const float* vb1,
    float* __restrict__ dstB, float* __restrict__ lnw2, float* __restrict__ lnb2,
    __hip_bfloat16* __restrict__ zpage){
  int t = threadIdx.x;
  zpage[t] = f2bf(0.0f);
  #pragma unroll
  for(int br=0;br<2;br++){
    const float* s = br ? b1 : b0;
    #pragma unroll
    for(int part=0;part<3;part++)
      dstB[br*768 + part*256 + t] = s[48*(t>>4) + part*16 + (t&15)];
  }
  #pragma unroll
  for(int br=0;br<2;br++){
    #pragma unroll
    for(int half=0;half<2;half++){
      int j = half*256 + t;
      int h = j>>5, idx = j&31;
      bool isK = idx<16;
      int c = isK ? idx : idx-16;
      const float* w = isK ? (br?kw1:kw0) : (br?vw1:vw0);
      const float* bb= isK ? (br?kb1:kb0) : (br?vb1:vb0);
      lnw2[br*512 + j] = w[h*16+c];
      lnb2[br*512 + j] = bb[h*16+c];
    }
  }
}

// ---------------- small row-major matmul: C = (A[+I]) @ B ----------------
template<int ADDI>
__global__ __launch_bounds__(256) void k_smallmm(const __hip_bfloat16* __restrict__ A,
    const __hip_bfloat16* __restrict__ B, __hip_bfloat16* __restrict__ C){
  __shared__ float ar[256];
  int i = blockIdx.x, t = threadIdx.x;
  float a = bf2f(A[(size_t)i*256 + t]);
  if(ADDI && t==i) a += 1.0f;
  ar[t] = a;
  __syncthreads();
  float a0=0.f,a1=0.f,a2=0.f,a3=0.f;
  for(int l=0;l<256;l+=4){
    a0 += ar[l+0]*bf2f(B[(l+0)*256 + t]);
    a1 += ar[l+1]*bf2f(B[(l+1)*256 + t]);
    a2 += ar[l+2]*bf2f(B[(l+2)*256 + t]);
    a3 += ar[l+3]*bf2f(B[(l+3)*256 + t]);
  }
  C[(size_t)i*256 + t] = f2bf((a0+a1)+(a2+a3));
}

__global__ __launch_bounds__(256) void k_smallmmR(const __hip_bfloat16* __restrict__ A,
    const __hip_bfloat16* __restrict__ B, __hip_bfloat16* __restrict__ C){
  __shared__ float ar[256];
  int j = blockIdx.x, t = threadIdx.x;
  int src = kvmap(j);
  ar[t] = bf2f(A[(size_t)src*256 + t]);
  __syncthreads();
  float a0=0.f,a1=0.f,a2=0.f,a3=0.f;
  for(int l=0;l<256;l+=4){
    a0 += ar[l+0]*bf2f(B[(l+0)*256 + t]);
    a1 += ar[l+1]*bf2f(B[(l+1)*256 + t]);
    a2 += ar[l+2]*bf2f(B[(l+2)*256 + t]);
    a3 += ar[l+3]*bf2f(B[(l+3)*256 + t]);
  }
  C[(size_t)j*256 + t] = f2bf((a0+a1)+(a2+a3));
}

__global__ __launch_bounds__(256) void k_bkv2R(const float* __restrict__ b2, const float* __restrict__ biaskv,
    const __hip_bfloat16* __restrict__ kvT_, float* __restrict__ outb){
  __shared__ float s_b2[256];
  int t = threadIdx.x; int n = blockIdx.x*256 + t;
  int src = kvmap(n);
  s_b2[t] = b2[t];
  __syncthreads();
  float v = biaskv[src];
  for(int l=0;l<256;l++) v += s_b2[l]*bf2f(kvT_[(size_t)src*256 + l]);
  outb[n] = v;
}

// ---------------- c1 = ((b2@(Wfold+I)+bfold) @ Wp) + bp ----------------
__global__ __launch_bounds__(256) void k_cvec(const float* __restrict__ b2, const float* __restrict__ bfold,
    const __hip_bfloat16* __restrict__ WfoldT, const __hip_bfloat16* __restrict__ projT_,
    const float* __restrict__ bp, float* __restrict__ c1){
  __shared__ float s_b2[256], s_r[256];
  int t = threadIdx.x;
  s_b2[t] = b2[t];
  __syncthreads();
  float r = s_b2[t] + bfold[t];
  for(int l=0;l<256;l++) r += s_b2[l]*bf2f(WfoldT[(size_t)t*256 + l]);
  s_r[t] = r;
  __syncthreads();
  float c = bp[t];
  for(int l=0;l<256;l++) c += s_r[l]*bf2f(projT_[(size_t)t*256 + l]);
  c1[t] = c;
}

// ---------------- per-query sampling geometry + result_bil ----------------
__global__ __launch_bounds__(256) void k_sample(const float* __restrict__ coord, const float* __restrict__ inp,
    float* __restrict__ mf, int* __restrict__ mi, float* __restrict__ bil){
  int q = blockIdx.x*256 + threadIdx.x;
  float cy = coord[2*q], cx = coord[2*q+1];
  const float LO = (float)(-1.0 + 1e-6), HI = (float)(1.0 - 1e-6);
  const float ONEG = (float)(-1.0/64.0 + 1e-6), OPOS = (float)(1.0/64.0 + 1e-6);
  float areas[4];
  #pragma unroll
  for(int s=0;s<4;s++){
    float oy = (s<2)?ONEG:OPOS;
    float ox = (s&1)?OPOS:ONEG;
    float csy = fminf(fmaxf(cy+oy, LO), HI);
    float csx = fminf(fmaxf(cx+ox, LO), HI);
    float fy = ((csy+1.0f)*64.0f - 1.0f)*0.5f;
    float fx = ((csx+1.0f)*64.0f - 1.0f)*0.5f;
    int iy = (int)rintf(fy); iy = iy<0?0:(iy>63?63:iy);
    int ix = (int)rintf(fx); ix = ix<0?0:(ix>63?63:ix);
    float qcy = -1.0f + (float)(2*iy+1)*0.015625f;
    float qcx = -1.0f + (float)(2*ix+1)*0.015625f;
    float ry = (cy-qcy)*64.0f, rx = (cx-qcx)*64.0f;
    mf[q*16 + 4 + 2*s] = ry; mf[q*16 + 5 + 2*s] = rx;
    areas[s] = fabsf(ry*rx) + 1e-9f;
    mi[q*8 + s] = iy*64 + ix;
  }
  float tot = areas[0]+areas[1]+areas[2]+areas[3];
  #pragma unroll
  for(int s=0;s<4;s++) mf[q*16 + s] = areas[3-s] / tot;

  float fy = ((cy+1.0f)*64.0f - 1.0f)*0.5f;
  float fx = ((cx+1.0f)*64.0f - 1.0f)*0.5f;
  {
    float y0 = floorf(fy), x0 = floorf(fx);
    float wy = fy-y0, wx = fx-x0;
    int y0i = (int)y0, x0i = (int)x0;
    float cw[4] = {(1.0f-wy)*(1.0f-wx), (1.0f-wy)*wx, wy*(1.0f-wx), wy*wx};
    #pragma unroll
    for(int c2=0;c2<4;c2++){
      int yi = y0i + (c2>>1), xi = x0i + (c2&1);
      bool ok = (yi>=0 && yi<64 && xi>=0 && xi<64);
      int yc = yi<0?0:(yi>63?63:yi), xc = xi<0?0:(xi>63?63:xi);
      mf[q*16 + 12 + c2] = ok ? cw[c2] : 0.0f;
      mi[q*8 + 4 + c2] = yc*64 + xc;
    }
  }
  {
    float fyb = fminf(fmaxf(fy, 0.0f), 63.0f);
    float fxb = fminf(fmaxf(fx, 0.0f), 63.0f);
    float y0 = floorf(fyb), x0 = floorf(fxb);
    float wy = fyb-y0, wx = fxb-x0;
    int y0i = (int)y0, x0i = (int)x0;
    float cw[4] = {(1.0f-wy)*(1.0f-wx), (1.0f-wy)*wx, wy*(1.0f-wx), wy*wx};
    float a0=0,a1=0,a2=0;
    #pragma unroll
    for(int c2=0;c2<4;c2++){
      int yi = y0i + (c2>>1), xi = x0i + (c2&1);
      if(yi>=0 && yi<64 && xi>=0 && xi<64){
        int idx = yi*64+xi; float wgt = cw[c2];
        a0 += inp[idx]*wgt; a1 += inp[4096+idx]*wgt; a2 += inp[8192+idx]*wgt;
      }
    }
    bil[q*3+0]=a0; bil[q*3+1]=a1; bil[q*3+2]=a2;
  }
}

// ---------------- stage-1 MLP via P-gather ----------------
template<int BR>
__global__ __launch_bounds__(256) void k_stage1(const __hip_bfloat16* __restrict__ P, const float* __restrict__ mf,
    const int* __restrict__ mi, const float* __restrict__ coord, const float* __restrict__ cell,
    const float* __restrict__ W1, const float* __restrict__ b1, __hip_bfloat16* __restrict__ out){
  __shared__ float wsm[11][256];
  int j = threadIdx.x;
  if(BR==0){
    #pragma unroll
    for(int r=0;r<8;r++) wsm[r][j] = W1[r*256 + j];
    wsm[8][j] = W1[1032*256 + j];
    wsm[9][j] = W1[1033*256 + j];
    wsm[10][j] = b1[j];
  } else {
    wsm[0][j] = W1[0*256 + j];
    wsm[1][j] = W1[1*256 + j];
    wsm[2][j] = W1[258*256 + j];
    wsm[3][j] = W1[259*256 + j];
    wsm[4][j] = b1[j];
  }
  __syncthreads();
  int q0 = blockIdx.x*32;
  for(int qq=0;qq<32;qq++){
    int q = q0+qq;
    float acc;
    const float* m = mf + q*16;
    const int* ii = mi + q*8;
    if(BR==0){
      acc = wsm[10][j];
      #pragma unroll
      for(int r=0;r<8;r++) acc += m[4+r]*wsm[r][j];
      float cly = cell[2*q]*64.0f, clx = cell[2*q+1]*64.0f;
      acc += cly*wsm[8][j] + clx*wsm[9][j];
      #pragma unroll
      for(int s=0;s<4;s++) acc += m[s]*bf2f(P[(size_t)ii[s]*1280 + s*256 + j]);
    } else {
      acc = wsm[4][j];
      float cy = coord[2*q], cx = coord[2*q+1];
      float cly = cell[2*q]*64.0f, clx = cell[2*q+1]*64.0f;
      acc += cy*wsm[0][j] + cx*wsm[1][j] + cly*wsm[2][j] + clx*wsm[3][j];
      #pragma unroll
      for(int c2=0;c2<4;c2++) acc += m[12+c2]*bf2f(P[(size_t)ii[4+c2]*1280 + 1024 + j]);
    }
    out[(size_t)q*256 + j] = f2bf(gelu_f(acc));
  }
}

// ---------------- MFMA bf16 GEMM v4: 8 waves, 34 KB LDS, half-tile epilogue ----------------
template<int ACT,int NRES>
__global__ __launch_bounds__(512) void k_gemm_mfma(
    const __hip_bfloat16* __restrict__ A, const __hip_bfloat16* __restrict__ BT,
    const float* __restrict__ bias, const __hip_bfloat16* __restrict__ R1,
    const __hip_bfloat16* __restrict__ R2, __hip_bfloat16* __restrict__ C,
    int M, int N, int K, int ldc){
  __shared__ __align__(1024) char smem[64*133*4];
  const int t = threadIdx.x, wave = t>>6, lane = t&63;
  const int MT = M>>7, NT = N>>7;
  const int b = blockIdx.x, xcd = b&7, i = b>>3;
  const int nt = i % NT, mtl = i / NT;
  const int m0 = (xcd*(MT>>3) + mtl) << 7, n0 = nt << 7;
  const int wr = (wave>>2)*64, wc = (wave&3)*32;
  const int lr = lane&15, lh = lane>>4;

  f32x4 acc[4][2] = {};
  const int ntiles = K>>6;
  for(int kt=0; kt<ntiles; ++kt){
    __syncthreads();
    #pragma unroll
    for(int q2=0;q2<2;q2++){
      int c = (wave*2+q2)*64 + lane;
      int row = c>>3; int k8 = (c&7) ^ (row&7);
      __hip_bfloat16* la = (__hip_bfloat16*)smem + (size_t)(wave*2+q2)*512;
      __hip_bfloat16* lb = (__hip_bfloat16*)(smem + 16384) + (size_t)(wave*2+q2)*512;
      load_lds16(A  + (size_t)(m0+row)*K + (kt*64 + k8*8), la);
      load_lds16(BT + (size_t)(n0+row)*K + (kt*64 + k8*8), lb);
    }
    __syncthreads();
    const __hip_bfloat16* Ab = (const __hip_bfloat16*)smem;
    const __hip_bfloat16* Bb = (const __hip_bfloat16*)(smem + 16384);
    #pragma unroll
    for(int kk=0;kk<2;kk++){
      bf16x8 af[4], bfr[2];
      #pragma unroll
      for(int m=0;m<4;m++){
        int row = wr + m*16 + lr;
        int p = (kk*4 + lh) ^ (row&7);
        af[m] = *reinterpret_cast<const bf16x8*>(Ab + row*64 + p*8);
      }
      #pragma unroll
      for(int n=0;n<2;n++){
        int row = wc + n*16 + lr;
        int p = (kk*4 + lh) ^ (row&7);
        bfr[n] = *reinterpret_cast<const bf16x8*>(Bb + row*64 + p*8);
      }
      #pragma unroll
      for(int m=0;m<4;m++)
        #pragma unroll
        for(int n=0;n<2;n++)
          acc[m][n] = __builtin_amdgcn_mfma_f32_16x16x32_bf16(af[m], bfr[n], acc[m][n], 0,0,0);
    }
  }

  float* epi = (float*)smem;
  #pragma unroll
  for(int hf=0; hf<2; ++hf){
    __syncthreads();
    if((wave>>2) == hf){
      #pragma unroll
      for(int m=0;m<4;m++)
        #pragma unroll
        for(int n=0;n<2;n++){
          int col = wc + n*16 + lr;
          #pragma unroll
          for(int j=0;j<4;j++)
            epi[(m*16 + lh*4 + j)*133 + col] = acc[m][n][j];
        }
    }
    __syncthreads();
    const int lrow = t>>3, c0 = (t&7)*16;
    const size_t grow = (size_t)(m0 + hf*64 + lrow);
    const float* er = epi + lrow*133;
    #pragma unroll
    for(int half=0; half<2; half++){
      int cb = c0 + half*8;
      int gc = n0 + cb;
      float v[8];
      #pragma unroll
      for(int e=0;e<8;e++) v[e] = er[cb+e];
      if(bias){
        #pragma unroll
        for(int e=0;e<8;e++) v[e] += bias[gc+e];
      }
      if(ACT==1){
        #pragma unroll
        for(int e=0;e<8;e++) v[e] = gelu_f(v[e]);
      }
      if(NRES==1 || NRES==2){
        uint4 r = *reinterpret_cast<const uint4*>(R1 + grow*ldc + gc);
        unsigned rw[4] = {r.x,r.y,r.z,r.w};
        #pragma unroll
        for(int q2=0;q2<4;q2++){ v[2*q2] += bflo(rw[q2]); v[2*q2+1] += bfhi(rw[q2]); }
      }
      if(NRES==2){
        uint4 r = *reinterpret_cast<const uint4*>(R2 + grow*ldc + gc);
        unsigned rw[4] = {r.x,r.y,r.z,r.w};
        #pragma unroll
        for(int q2=0;q2<4;q2++){ v[2*q2] += bflo(rw[q2]); v[2*q2+1] += bfhi(rw[q2]); }
      }
      uint4 o;
      o.x = pack2bf(v[0],v[1]); o.y = pack2bf(v[2],v[3]);
      o.z = pack2bf(v[4],v[5]); o.w = pack2bf(v[6],v[7]);
      *reinterpret_cast<uint4*>(C + grow*ldc + gc) = o;
    }
  }
}

// ---------------- freq conv GEMM: A gathered from featP via tap-offset (4-wave, unchanged) ----------------
__global__ __launch_bounds__(256) void k_gfreq(
    const __hip_bfloat16* __restrict__ featP, const __hip_bfloat16* __restrict__ zpage,
    const __hip_bfloat16* __restrict__ BT, const float* __restrict__ bias,
    __hip_bfloat16* __restrict__ C){
  __shared__ __align__(1024) char smem[64*133*4];
  const int t = threadIdx.x, wave = t>>6, lane = t&63;
  const int MT = 32, NT = 2;
  const int b = blockIdx.x, xcd = b&7, i = b>>3;
  const int nt = i % NT, mtl = i / NT;
  const int m0 = (xcd*(MT>>3) + mtl) << 7, n0 = nt << 7;
  const int wr = (wave>>1)*64, wc = (wave&1)*64;
  const int lr = lane&15, lh = lane>>4;

  f32x4 acc[4][4] = {};
  for(int kt=0; kt<9; ++kt){
    int ky = kt/3, kx = kt - ky*3;
    __syncthreads();
    #pragma unroll
    for(int q2=0;q2<4;q2++){
      int c = (wave*4+q2)*64 + lane;
      int row = c>>3; int k8 = (c&7) ^ (row&7);
      __hip_bfloat16* la = (__hip_bfloat16*)smem + (size_t)(wave*4+q2)*512;
      __hip_bfloat16* lb = (__hip_bfloat16*)(smem + 16384) + (size_t)(wave*4+q2)*512;
      int pix = m0+row, y = pix>>6, x = pix&63;
      int yy = y+ky-1, xx = x+kx-1;
      const __hip_bfloat16* src = ((unsigned)yy<64u && (unsigned)xx<64u) ?
          (featP + (size_t)(yy*64+xx)*64 + k8*8) : (zpage + k8*8);
      load_lds16(src, la);
      load_lds16(BT + (size_t)(n0+row)*640 + (kt*64 + k8*8), lb);
    }
    __syncthreads();
    const __hip_bfloat16* Ab = (const __hip_bfloat16*)smem;
    const __hip_bfloat16* Bb = (const __hip_bfloat16*)(smem + 16384);
    #pragma unroll
    for(int kk=0;kk<2;kk++){
      bf16x8 af[4], bfr[4];
      #pragma unroll
      for(int m=0;m<4;m++){
        int row = wr + m*16 + lr;
        int p = (kk*4 + lh) ^ (row&7);
        af[m] = *reinterpret_cast<const bf16x8*>(Ab + row*64 + p*8);
      }
      #pragma unroll
      for(int n=0;n<4;n++){
        int row = wc + n*16 + lr;
        int p = (kk*4 + lh) ^ (row&7);
        bfr[n] = *reinterpret_cast<const bf16x8*>(Bb + row*64 + p*8);
      }
      #pragma unroll
      for(int m=0;m<4;m++)
        #pragma unroll
        for(int n=0;n<4;n++)
          acc[m][n] = __builtin_amdgcn_mfma_f32_16x16x32_bf16(af[m], bfr[n], acc[m][n], 0,0,0);
    }
  }

  float* epi = (float*)smem;
  const int cg = t&3;
  #pragma unroll
  for(int hf=0; hf<2; ++hf){
    __syncthreads();
    if((wave>>1) == hf){
      #pragma unroll
      for(int m=0;m<4;m++)
        #pragma unroll
        for(int n=0;n<4;n++){
          int col = wc + n*16 + lr;
          #pragma unroll
          for(int j=0;j<4;j++)
            epi[(m*16 + lh*4 + j)*133 + col] = acc[m][n][j];
        }
    }
    __syncthreads();
    const int lrow = t>>2, c0 = cg*32;
    const size_t grow = (size_t)(m0 + hf*64 + lrow);
    const float* er = epi + lrow*133;
    #pragma unroll
    for(int g0=0; g0<4; g0++){
      int g = (g0 + cg) & 3;
      int cb = c0 + g*8;
      int gc = n0 + cb;
      float v[8];
      #pragma unroll
      for(int e=0;e<8;e++) v[e] = er[cb+e] + bias[gc+e];
      uint4 o;
      o.x = pack2bf(v[0],v[1]); o.y = pack2bf(v[2],v[3]);
      o.z = pack2bf(v[4],v[5]); o.w = pack2bf(v[6],v[7]);
      *reinterpret_cast<uint4*>(C + grow*256 + gc) = o;
    }
  }
}

// ---------------- fused kv: GEMM(N=512 reordered) + bias + LDS-transposed LN + per-head MFMA outer product ----
__global__ __launch_bounds__(256) void k_kvln(
    const __hip_bfloat16* __restrict__ A, const __hip_bfloat16* __restrict__ BT,
    const float* __restrict__ bias, const float* __restrict__ lnw, const float* __restrict__ lnb,
    float* __restrict__ kvpart){
  __shared__ __align__(1024) char smem[34816];
  const int t = threadIdx.x, wave = t>>6, lane = t&63;
  const int MT = 512, NT = 4;
  const int b = blockIdx.x, xcd = b&7, i = b>>3;
  const int nt = i % NT, mtl = i / NT;
  const int m0 = (xcd*(MT>>3) + mtl) << 7, n0 = nt << 7;
  const int wr = (wave>>1)*64, wc = (wave&1)*64;
  const int lr = lane&15, lh = lane>>4;

  f32x4 acc[4][4] = {};
  for(int kt=0; kt<4; ++kt){
    __syncthreads();
    #pragma unroll
    for(int q2=0;q2<4;q2++){
      int c = (wave*4+q2)*64 + lane;
      int row = c>>3; int k8 = (c&7) ^ (row&7);
      __hip_bfloat16* la = (__hip_bfloat16*)smem + (size_t)(wave*4+q2)*512;
      __hip_bfloat16* lb = (__hip_bfloat16*)(smem + 16384) + (size_t)(wave*4+q2)*512;
      load_lds16(A  + (size_t)(m0+row)*256 + (kt*64 + k8*8), la);
      load_lds16(BT + (size_t)(n0+row)*256 + (kt*64 + k8*8), lb);
    }
    __syncthreads();
    const __hip_bfloat16* Ab = (const __hip_bfloat16*)smem;
    const __hip_bfloat16* Bb = (const __hip_bfloat16*)(smem + 16384);
    #pragma unroll
    for(int kk=0;kk<2;kk++){
      bf16x8 af[4], bfr[4];
      #pragma unroll
      for(int m=0;m<4;m++){
        int row = wr + m*16 + lr;
        int p = (kk*4 + lh) ^ (row&7);
        af[m] = *reinterpret_cast<const bf16x8*>(Ab + row*64 + p*8);
      }
      #pragma unroll
      for(int n=0;n<4;n++){
        int row = wc + n*16 + lr;
        int p = (kk*4 + lh) ^ (row&7);
        bfr[n] = *reinterpret_cast<const bf16x8*>(Bb + row*64 + p*8);
      }
      #pragma unroll
      for(int m=0;m<4;m++)
        #pragma unroll
        for(int n=0;n<4;n++)
          acc[m][n] = __builtin_amdgcn_mfma_f32_16x16x32_bf16(af[m], bfr[n], acc[m][n], 0,0,0);
    }
  }
  __syncthreads();

  __hip_bfloat16* knT = (__hip_bfloat16*)smem;            // [4 heads][16 cols][136 rows]
  __hip_bfloat16* vnT = (__hip_bfloat16*)(smem + 17408);
  #pragma unroll
  for(int m=0;m<4;m++){
    #pragma unroll
    for(int n=0;n<4;n++){
      int cl = wc + n*16 + lr;
      int gcol = n0 + cl;
      float bs = bias[gcol];
      int h2 = cl>>5, isV = (cl>>4)&1;
      short4 pk;
      #pragma unroll
      for(int j=0;j<4;j++) ((__hip_bfloat16*)&pk)[j] = f2bf(acc[m][n][j] + bs);
      int r = wr + m*16 + lh*4;
      __hip_bfloat16* dst = (isV ? vnT : knT) + (h2*16 + lr)*136 + r;
      *reinterpret_cast<short4*>(dst) = pk;
    }
  }
  __syncthreads();
  #pragma unroll
  for(int i4=0; i4<4; ++i4){
    int task = i4*256 + t;
    int r = task & 127, hv = task >> 7;
    int h2 = hv >> 1, isV = hv & 1;
    __hip_bfloat16* base = (isV ? vnT : knT) + (h2*16)*136 + r;
    float xs[16];
    float s=0.0f, s2=0.0f;
    #pragma unroll
    for(int c=0;c<16;c++){ xs[c] = bf2f(base[c*136]); s += xs[c]; s2 += xs[c]*xs[c]; }
    float mean = s*0.0625f;
    float var = (s2 - 16.0f*mean*mean)*(1.0f/15.0f); var = var<0.0f?0.0f:var;
    float inv = 1.0f/(sqrtf(var) + 1e-5f);
    int gbase = n0 + h2*32 + isV*16;
    #pragma unroll
    for(int c=0;c<16;c++)
      base[c*136] = f2bf(lnw[gbase+c]*((xs[c]-mean)*inv) + lnb[gbase+c]);
  }
  __syncthreads();
  f32x4 kacc = {};
  #pragma unroll
  for(int kk=0;kk<4;kk++){
    bf16x8 af  = *reinterpret_cast<const bf16x8*>(knT + (wave*16 + lr)*136 + kk*32 + lh*8);
    bf16x8 bf_ = *reinterpret_cast<const bf16x8*>(vnT + (wave*16 + lr)*136 + kk*32 + lh*8);
    kacc = __builtin_amdgcn_mfma_f32_16x16x32_bf16(af, bf_, kacc, 0,0,0);
  }
  const int mt = m0>>7;
  const int hglob = nt*4 + wave;
  #pragma unroll
  for(int j=0;j<4;j++)
    kvpart[(size_t)mt*4096 + hglob*256 + (lh*4+j)*16 + lr] = kacc[j];
}

// ---------------- G12 fused v3 (8 waves): C = gelu(A@B1^T + c1) + (A@B2^T + b2) [+R] ----------------
template<int NRES>
__global__ __launch_bounds__(512) void k_gemm12(
    const __hip_bfloat16* __restrict__ A, const __hip_bfloat16* __restrict__ B1T,
    const float* __restrict__ c1, const __hip_bfloat16* __restrict__ B2T,
    const float* __restrict__ b2, const __hip_bfloat16* __restrict__ R,
    __hip_bfloat16* __restrict__ C){
  __shared__ __align__(1024) char smem[49152];
  const int t = threadIdx.x, wave = t>>6, lane = t&63;
  const int MT = 512, NT = 2;
  const int b = blockIdx.x, xcd = b&7, i = b>>3;
  const int nt = i % NT, mtl = i / NT;
  const int m0 = (xcd*(MT>>3) + mtl) << 7, n0 = nt << 7;
  const int wr = (wave>>2)*64, wc = (wave&3)*32;
  const int lr = lane&15, lh = lane>>4;
  f32x4 acc1[4][2] = {}, acc2[4][2] = {};
  for(int k0=0;k0<256;k0+=64){
    __syncthreads();
    #pragma unroll
    for(int q2=0;q2<2;q2++){
      int c = (wave*2+q2)*64 + lane;
      int row = c>>3; int k8 = (c&7) ^ (row&7);
      __hip_bfloat16* base = (__hip_bfloat16*)smem + (size_t)(wave*2+q2)*512;
      load_lds16(A   + (size_t)(m0+row)*256 + (k0 + k8*8), base);
      load_lds16(B1T + (size_t)(n0+row)*256 + (k0 + k8*8), base + 8192);
      load_lds16(B2T + (size_t)(n0+row)*256 + (k0 + k8*8), base + 16384);
    }
    __syncthreads();
    const __hip_bfloat16* Ab = (const __hip_bfloat16*)smem;
    #pragma unroll
    for(int kk=0;kk<2;kk++){
      bf16x8 af[4], bfr[2];
      #pragma unroll
      for(int m=0;m<4;m++){
        int row = wr + m*16 + lr;
        int p = (kk*4 + lh) ^ (row&7);
        af[m] = *reinterpret_cast<const bf16x8*>(Ab + row*64 + p*8);
      }
      #pragma unroll
      for(int n=0;n<2;n++){
        int row = wc + n*16 + lr;
        int p = (kk*4 + lh) ^ (row&7);
        bfr[n] = *reinterpret_cast<const bf16x8*>(Ab + 8192 + row*64 + p*8);
      }
      #pragma unroll
      for(int m=0;m<4;m++)
        #pragma unroll
        for(int n=0;n<2;n++)
          acc1[m][n] = __builtin_amdgcn_mfma_f32_16x16x32_bf16(af[m], bfr[n], acc1[m][n], 0,0,0);
      #pragma unroll
      for(int n=0;n<2;n++){
        int row = wc + n*16 + lr;
        int p = (kk*4 + lh) ^ (row&7);
        bfr[n] = *reinterpret_cast<const bf16x8*>(Ab + 16384 + row*64 + p*8);
      }
      #pragma unroll
      for(int m=0;m<4;m++)
        #pragma unroll
        for(int n=0;n<2;n++)
          acc2[m][n] = __builtin_amdgcn_mfma_f32_16x16x32_bf16(af[m], bfr[n], acc2[m][n], 0,0,0);
    }
  }
  float* epi = (float*)smem;
  #pragma unroll
  for(int hf=0; hf<2; ++hf){
    const int lrow = t>>3, c0 = (t&7)*16;
    const size_t grow = (size_t)(m0 + hf*64 + lrow);
    float v1[16];
    __syncthreads();
    if((wave>>2) == hf){
      #pragma unroll
      for(int m=0;m<4;m++)
        #pragma unroll
        for(int n=0;n<2;n++){
          int col = wc + n*16 + lr;
          #pragma unroll
          for(int j=0;j<4;j++)
            epi[(m*16 + lh*4 + j)*133 + col] = acc1[m][n][j];
        }
    }
    __syncthreads();
    {
      const float* er = epi + lrow*133;
      #pragma unroll
      for(int e=0;e<16;e++) v1[e] = gelu_f(er[c0+e] + c1[n0+c0+e]);
    }
    __syncthreads();
    if((wave>>2) == hf){
      #pragma unroll
      for(int m=0;m<4;m++)
        #pragma unroll
        for(int n=0;n<2;n++){
          int col = wc + n*16 + lr;
          #pragma unroll
          for(int j=0;j<4;j++)
            epi[(m*16 + lh*4 + j)*133 + col] = acc2[m][n][j];
        }
    }
    __syncthreads();
    {
      const float* er = epi + lrow*133;
      #pragma unroll
      for(int half=0; half<2; half++){
        int cb = c0 + half*8;
        int gc = n0 + cb;
        float v[8];
        #pragma unroll
        for(int e=0;e<8;e++) v[e] = v1[half*8+e] + er[cb+e] + b2[gc+e];
        if(NRES==1){
          uint4 r = *reinterpret_cast<const uint4*>(R + grow*256 + gc);
          unsigned rw[4] = {r.x,r.y,r.z,r.w};
          #pragma unroll
          for(int q2=0;q2<4;q2++){ v[2*q2] += bflo(rw[q2]); v[2*q2+1] += bfhi(rw[q2]); }
        }
        uint4 o;
        o.x = pack2bf(v[0],v[1]); o.y = pack2bf(v[2],v[3]);
        o.z = pack2bf(v[4],v[5]); o.w = pack2bf(v[6],v[7]);
        *reinterpret_cast<uint4*>(C + grow*256 + gc) = o;
      }
    }
  }
}

// ---------------- fc3+final fused v3 (8 waves): part[nt][row][3] ----------------
__global__ __launch_bounds__(512) void k_gemmF(
    const __hip_bfloat16* __restrict__ A, const __hip_bfloat16* __restrict__ BT,
    const float* __restrict__ bias, const float* __restrict__ W4,
    float* __restrict__ part){
  __shared__ __align__(1024) char smem[64*133*4];
  __shared__ float w4s[768];
  const int t = threadIdx.x, wave = t>>6, lane = t&63;
  const int MT = 512, NT = 2;
  const int b = blockIdx.x, xcd = b&7, i = b>>3;
  const int nt = i % NT, mtl = i / NT;
  const int m0 = (xcd*(MT>>3) + mtl) << 7, n0 = nt << 7;
  const int wr = (wave>>2)*64, wc = (wave&3)*32;
  const int lr = lane&15, lh = lane>>4;
  for(int l=t;l<768;l+=512) w4s[l] = W4[l];

  f32x4 acc[4][2] = {};
  for(int kt=0; kt<4; ++kt){
    __syncthreads();
    #pragma unroll
    for(int q2=0;q2<2;q2++){
      int c = (wave*2+q2)*64 + lane;
      int row = c>>3; int k8 = (c&7) ^ (row&7);
      __hip_bfloat16* la = (__hip_bfloat16*)smem + (size_t)(wave*2+q2)*512;
      __hip_bfloat16* lb = (__hip_bfloat16*)(smem + 16384) + (size_t)(wave*2+q2)*512;
      load_lds16(A  + (size_t)(m0+row)*256 + (kt*64 + k8*8), la);
      load_lds16(BT + (size_t)(n0+row)*256 + (kt*64 + k8*8), lb);
    }
    __syncthreads();
    const __hip_bfloat16* Ab = (const __hip_bfloat16*)smem;
    const __hip_bfloat16* Bb = (const __hip_bfloat16*)(smem + 16384);
    #pragma unroll
    for(int kk=0;kk<2;kk++){
      bf16x8 af[4], bfr[2];
      #pragma unroll
      for(int m=0;m<4;m++){
        int row = wr + m*16 + lr;
        int p = (kk*4 + lh) ^ (row&7);
        af[m] = *reinterpret_cast<const bf16x8*>(Ab + row*64 + p*8);
      }
      #pragma unroll
      for(int n=0;n<2;n++){
        int row = wc + n*16 + lr;
        int p = (kk*4 + lh) ^ (row&7);
        bfr[n] = *reinterpret_cast<const bf16x8*>(Bb + row*64 + p*8);
      }
      #pragma unroll
      for(int m=0;m<4;m++)
        #pragma unroll
        for(int n=0;n<2;n++)
          acc[m][n] = __builtin_amdgcn_mfma_f32_16x16x32_bf16(af[m], bfr[n], acc[m][n], 0,0,0);
    }
  }

  float* epi = (float*)smem;
  #pragma unroll
  for(int hf=0; hf<2; ++hf){
    __syncthreads();
    if((wave>>2) == hf){
      #pragma unroll
      for(int m=0;m<4;m++)
        #pragma unroll
        for(int n=0;n<2;n++){
          int col = wc + n*16 + lr;
          #pragma unroll
          for(int j=0;j<4;j++)
            epi[(m*16 + lh*4 + j)*133 + col] = acc[m][n][j];
        }
    }
    __syncthreads();
    {
      const int lrow = t>>3, c0 = (t&7)*16;
      const float* er = epi + lrow*133;
      float s0=0.f, s1=0.f, s2=0.f;
      #pragma unroll
      for(int e=0;e<16;e++){
        int gc = n0 + c0 + e;
        float v = gelu_f(er[c0+e] + bias[gc]);
        s0 += v*w4s[gc*3+0];
        s1 += v*w4s[gc*3+1];
        s2 += v*w4s[gc*3+2];
      }
      s0 += __shfl_xor(s0,1); s0 += __shfl_xor(s0,2); s0 += __shfl_xor(s0,4);
      s1 += __shfl_xor(s1,1); s1 += __shfl_xor(s1,2); s1 += __shfl_xor(s1,4);
      s2 += __shfl_xor(s2,1); s2 += __shfl_xor(s2,2); s2 += __shfl_xor(s2,4);
      if((t&7)==0){
        float* pp = part + (size_t)nt*196608 + (size_t)(m0 + hf*64 + lrow)*3;
        pp[0]=s0; pp[1]=s1; pp[2]=s2;
      }
    }
  }
}

__global__ __launch_bounds__(256) void k_combine(const float* __restrict__ part, const float* __restrict__ b4,
    const float* __restrict__ bil, float* __restrict__ out){
  int i = blockIdx.x*256 + threadIdx.x;
  int j = i - (i/3)*3;
  out[i] = part[i] + part[196608 + i] + b4[j] + bil[i];
}

__global__ __launch_bounds__(256) void k_kvred(const float* __restrict__ kvpart, float* __restrict__ kv){
  __shared__ float sm[256];
  int b = blockIdx.x, t = threadIdx.x;
  int d = t & 15, seg = t >> 4;
  float s = 0.0f;
  for(int k=0;k<32;k++) s += kvpart[(size_t)(seg*32+k)*4096 + b*16 + d];
  sm[t] = s;
  __syncthreads();
  if(t < 16){
    float r = 0.0f;
    #pragma unroll
    for(int g=0; g<16; g++) r += sm[g*16 + t];
    kv[b*16 + t] = r * (1.0f/65536.0f);
  }
}

// ---------------- fold q-projection through kv ----------------
__global__ __launch_bounds__(256) void k_fold(const __hip_bfloat16* __restrict__ qT,
    const float* __restrict__ biasq, const float* __restrict__ kv,
    __hip_bfloat16* __restrict__ WfoldT, float* __restrict__ bfold){
  int n = blockIdx.x, t = threadIdx.x;
  int h = n>>4, d = n&15;
  float s = 0.0f;
  #pragma unroll
  for(int c=0;c<16;c++)
    s += bf2f(qT[(size_t)(h*16+c)*256 + t]) * kv[h*256 + c*16 + d];
  WfoldT[(size_t)n*256 + t] = f2bf(s);
  if(t==0){
    float b=0.0f;
    #pragma unroll
    for(int c=0;c<16;c++) b += biasq[h*16+c]*kv[h*256+c*16+d];
    bfold[n]=b;
  }
}

extern "C" void kernel_launch(void* const* d_in, const int* in_sizes, int n_in,
                              void* d_out, int out_size, void* d_ws, size_t ws_size,
                              hipStream_t stream){
  (void)in_sizes; (void)n_in; (void)out_size;
  const float* inp     = (const float*)d_in[0];
  const float* coord   = (const float*)d_in[1];
  const float* cell    = (const float*)d_in[2];
  const float* enc_w   = (const float*)d_in[3];
  const float* enc_b   = (const float*)d_in[4];
  const float* freq_w  = (const float*)d_in[5];
  const float* freq_b  = (const float*)d_in[6];
  const float* out0_w1 = (const float*)d_in[7];
  const float* out0_b1 = (const float*)d_in[8];
  const float* out0_w2 = (const float*)d_in[9];
  const float* out0_b2 = (const float*)d_in[10];
  const float* out1_w1 = (const float*)d_in[11];
  const float* out1_b1 = (const float*)d_in[12];
  const float* out1_w2 = (const float*)d_in[13];
  const float* out1_b2 = (const float*)d_in[14];
  const float* fc1_w1  = (const float*)d_in[15];
  const float* fc1_b1  = (const float*)d_in[16];
  const float* fc1_w2  = (const float*)d_in[17];
  const float* fc1_b2  = (const float*)d_in[18];
  const float* fc2_w1  = (const float*)d_in[19];
  const float* fc2_b1  = (const float*)d_in[20];
  const float* fc2_w2  = (const float*)d_in[21];
  const float* fc2_b2  = (const float*)d_in[22];
  const float* qkv_w[2] = {(const float*)d_in[23], (const float*)d_in[31]};
  const float* qkv_b[2] = {(const float*)d_in[24], (const float*)d_in[32]};
  const float* kln_w[2] = {(const float*)d_in[25], (const float*)d_in[33]};
  const float* kln_b[2] = {(const float*)d_in[26], (const float*)d_in[34]};
  const float* vln_w[2] = {(const float*)d_in[27], (const float*)d_in[35]};
  const float* vln_b[2] = {(const float*)d_in[28], (const float*)d_in[36]};
  const float* proj_w[2] = {(const float*)d_in[29], (const float*)d_in[37]};
  const float* proj_b[2] = {(const float*)d_in[30], (const float*)d_in[38]};
  const float* b2arr[2] = {out0_b2, out1_b2};

  char* wsp = (char*)d_ws; size_t off = 0;
  auto alloc = [&](size_t bytes)->void*{ void* p = wsp + off; off += (bytes + 255) & ~(size_t)255; return p; };
  __hip_bfloat16* featP = (__hip_bfloat16*)alloc(262144ull*2);
  __hip_bfloat16* zpage = (__hip_bfloat16*)alloc(256ull*2);
  __hip_bfloat16* wtb = (__hip_bfloat16*)alloc(2097152ull*2);
  __hip_bfloat16* P = (__hip_bfloat16*)alloc(5242880ull*2);
  float* mf     = (float*)alloc(65536ull*16*4);
  int*   mi     = (int*)alloc(65536ull*8*4);
  float* bil    = (float*)alloc(65536ull*3*4);
  float* kvpart = (float*)alloc(512ull*4096*4);
  float* kv0    = (float*)alloc(4096ull*4);
  float* kv1    = (float*)alloc(4096ull*4);
  float* biasbuf= (float*)alloc(1536ull*4);
  float* lnbuf  = (float*)alloc(2048ull*4);
  float* bfold  = (float*)alloc(256ull*4);
  float* c1     = (float*)alloc(256ull*4);
  float* bkvh   = (float*)alloc(1024ull*4);
  float* part   = (float*)alloc(2ull*196608*4);
  __hip_bfloat16* wfoldT = (__hip_bfloat16*)alloc(65536ull*2);
  __hip_bfloat16* bufA = (__hip_bfloat16*)alloc(65536ull*256*2);
  __hip_bfloat16* bufB = (__hip_bfloat16*)alloc(65536ull*256*2);
  __hip_bfloat16* bufC = (__hip_bfloat16*)alloc(65536ull*256*2);
  if(off > ws_size) return;

  __hip_bfloat16* w2T[2]   = {wtb,          wtb + 65536};
  __hip_bfloat16* projT[2] = {wtb + 131072, wtb + 196608};
  __hip_bfloat16* fc1w1T   =  wtb + 262144;
  __hip_bfloat16* fc1w2T   =  wtb + 327680;
  __hip_bfloat16* fc2w1T   =  wtb + 393216;
  __hip_bfloat16* qT[2]    = {wtb + 458752, wtb + 655360};
  __hip_bfloat16* kvT[2]   = {wtb + 524288, wtb + 720896};
  __hip_bfloat16* wfreqT   =  wtb + 851968;   // 256 x 640
  __hip_bfloat16* wblkT    =  wtb + 1015808;  // 1280 x 256
  __hip_bfloat16* kvh2T[2] = {wtb + 1343488, wtb + 1474560};
  __hip_bfloat16* Ubuf     =  wtb + 1605632;
  __hip_bfloat16* M1T      =  wtb + 1671168;
  __hip_bfloat16* freqB = bufB;               // 4096 x 256

  k_conv1<<<1024,256,0,stream>>>(inp, enc_w, enc_b, featP);
  k_wfreq<<<256,256,0,stream>>>(freq_w, wfreqT);
  k_wblk<<<1280,256,0,stream>>>(out0_w1, out1_w1, wblkT);

  PrepArgs pa;
  pa.d[0]  = {out0_w2,   w2T[0],   0, 0};
  pa.d[1]  = {out1_w2,   w2T[1],   0, 0};
  pa.d[2]  = {proj_w[0], projT[0], 0, 0};
  pa.d[3]  = {proj_w[1], projT[1], 0, 0};
  pa.d[4]  = {fc1_w1,    fc1w1T,   0, 0};
  pa.d[5]  = {fc1_w2,    fc1w2T,   0, 0};
  pa.d[6]  = {fc2_w1,    fc2w1T,   0, 0};
  pa.d[7]  = {qkv_w[0],  qT[0],    1, 0};
  pa.d[8]  = {qkv_w[0],  kvT[0],   17, 0};
  pa.d[9]  = {qkv_w[0],  kvT[0]+65536, 33, 0};
  pa.d[10] = {qkv_w[1],  qT[1],    1, 0};
  pa.d[11] = {qkv_w[1],  kvT[1],   17, 0};
  pa.d[12] = {qkv_w[1],  kvT[1]+65536, 33, 0};
  k_prep<<<13*256,256,0,stream>>>(pa);
  k_biasperm<<<1,256,0,stream>>>(qkv_b[0], qkv_b[1],
      kln_w[0], kln_b[0], vln_w[0], vln_b[0], kln_w[1], kln_b[1], vln_w[1], vln_b[1],
      biasbuf, lnbuf, lnbuf + 1024, zpage);

  for(int br=0;br<2;br++){
    k_smallmmR<<<512,256,0,stream>>>(kvT[br], w2T[br], kvh2T[br]);
    k_bkv2R<<<2,256,0,stream>>>(b2arr[br], biasbuf + br*768 + 256, kvT[br], bkvh + br*512);
  }

  k_gfreq<<<64,256,0,stream>>>(featP, zpage, wfreqT, freq_b, freqB);
  k_gemm_mfma<0,0><<<320,512,0,stream>>>(freqB, wblkT, nullptr, nullptr,nullptr, P, 4096,1280,256, 1280);

  k_sample<<<256,256,0,stream>>>(coord, inp, mf, mi, bil);

  for(int br=0;br<2;br++){
    if(br==0) k_stage1<0><<<2048,256,0,stream>>>(P, mf, mi, coord, cell, out0_w1, out0_b1, bufA);
    else      k_stage1<1><<<2048,256,0,stream>>>(P, mf, mi, coord, cell, out1_w1, out1_b1, bufA);
    k_kvln<<<2048,256,0,stream>>>(bufA, kvh2T[br], bkvh + br*512, lnbuf + br*512, lnbuf + 1024 + br*512, kvpart);
    float* kvf = br ? kv1 : kv0;
    k_kvred<<<256,256,0,stream>>>(kvpart, kvf);
    k_fold<<<256,256,0,stream>>>(qT[br], biasbuf + br*768, kvf, wfoldT, bfold);
    k_smallmm<1><<<256,256,0,stream>>>(wfoldT, w2T[br], Ubuf);
    k_smallmm<0><<<256,256,0,stream>>>(projT[br], Ubuf, M1T);
    k_cvec<<<1,256,0,stream>>>(b2arr[br], bfold, wfoldT, projT[br], proj_b[br], c1);
    if(br==0)
      k_gemm12<0><<<1024,512,0,stream>>>(bufA, M1T, c1, w2T[0], b2arr[0], nullptr, bufC);
    else
      k_gemm12<1><<<1024,512,0,stream>>>(bufA, M1T, c1, w2T[1], b2arr[1], bufC, bufC);
  }
  // fc tail: bufC = f
  k_gemm_mfma<1,0><<<1024,512,0,stream>>>(bufC, fc1w1T, fc1_b1, nullptr,nullptr, bufA, 65536,256,256, 256);
  k_gemm_mfma<1,1><<<1024,512,0,stream>>>(bufA, fc1w2T, fc1_b2, bufC, nullptr, bufB, 65536,256,256, 256);
  k_gemmF<<<1024,512,0,stream>>>(bufB, fc2w1T, fc2_b1, fc2_w2, part);
  k_combine<<<768,256,0,stream>>>(part, fc2_b2, bil, (float*)d_out);
}

// Round 19
// 467.937 us; speedup vs baseline: 1.2823x; 1.0170x over previous
//
#include <hip/hip_runtime.h>
#include <hip/hip_bf16.h>

#define DI __device__ __forceinline__

DI float gelu_f(float x){ return 0.5f*x*(1.0f + erff(x*0.7071067811865476f)); }
DI float bf2f(__hip_bfloat16 b){ return __bfloat162float(b); }
DI __hip_bfloat16 f2bf(float f){ return __float2bfloat16(f); }
DI float bflo(unsigned u){ return __uint_as_float(u<<16); }
DI float bfhi(unsigned u){ return __uint_as_float(u & 0xffff0000u); }
DI unsigned pack2bf(float a, float b){
  __hip_bfloat16 ha = f2bf(a), hb = f2bf(b);
  unsigned short ua = *reinterpret_cast<unsigned short*>(&ha);
  unsigned short ub = *reinterpret_cast<unsigned short*>(&hb);
  return (unsigned)ua | ((unsigned)ub<<16);
}

typedef __attribute__((ext_vector_type(8))) short bf16x8;
typedef __attribute__((ext_vector_type(4))) float f32x4;

template<typename T>
DI void load_lds16(const T* g, T* l){
  __builtin_amdgcn_global_load_lds((const __attribute__((address_space(1))) void*)g,
                                   (__attribute__((address_space(3))) void*)l, 16, 0, 0);
}

DI int kvmap(int j){ int h=j>>5, idx=j&31; return idx<16 ? h*16+idx : 256+h*16+(idx-16); }

// ---------------- conv1: inp -> featP (4096 pix, 64 ch) bf16 pixel-major ----------------
__global__ __launch_bounds__(256) void k_conv1(const float* __restrict__ inp, const float* __restrict__ w,
                                               const float* __restrict__ b, __hip_bfloat16* __restrict__ featP){
  int idx = blockIdx.x*256 + threadIdx.x;
  int o = idx & 63, p = idx >> 6, y = p >> 6, x = p & 63;
  float acc = b[o];
  #pragma unroll
  for(int c=0;c<3;c++){
    #pragma unroll
    for(int ky=0;ky<3;ky++){
      int yy = y+ky-1; if((unsigned)yy >= 64u) continue;
      #pragma unroll
      for(int kx=0;kx<3;kx++){
        int xx = x+kx-1; if((unsigned)xx >= 64u) continue;
        acc += inp[c*4096 + yy*64 + xx] * w[o*27 + c*9 + ky*3 + kx];
      }
    }
  }
  featP[p*64 + o] = f2bf(acc);
}

// ---------------- wfreq permute ----------------
__global__ __launch_bounds__(256) void k_wfreq(const float* __restrict__ fw, __hip_bfloat16* __restrict__ wt){
  int o = blockIdx.x, t = threadIdx.x;
  #pragma unroll
  for(int it=0; it<3; it++){
    int k = it*256 + t;
    if(k >= 640) break;
    float v = 0.0f;
    if(k < 576){
      int tap = k>>6, c = k&63;
      v = fw[o*576 + c*9 + tap];
    }
    wt[(size_t)o*640 + k] = f2bf(v);
  }
}

// ---------------- wblkT ----------------
__global__ __launch_bounds__(256) void k_wblk(const float* __restrict__ w0, const float* __restrict__ w1,
                                              __hip_bfloat16* __restrict__ wt){
  int j = blockIdx.x, kk = threadIdx.x;
  float v;
  if(j < 1024){
    int s = j>>8, n = j&255;
    v = w0[(8 + 256*s + kk)*256 + n];
  } else {
    v = w1[(2 + kk)*256 + (j-1024)];
  }
  wt[(size_t)j*256 + kk] = f2bf(v);
}

// ---------------- batched weight transpose / qkv head-permute ----------------
struct PrepDesc { const float* src; __hip_bfloat16* dst; int mode; int pad; };
struct PrepArgs { PrepDesc d[13]; };
__global__ __launch_bounds__(256) void k_prep(PrepArgs a){
  int u = blockIdx.x >> 8, b = blockIdx.x & 255, t = threadIdx.x;
  PrepDesc d = a.d[u];
  float v;
  if(d.mode == 0) v = d.src[t*256 + b];
  else { int col = 48*(b>>4) + (d.mode-1) + (b&15); v = d.src[t*768 + col]; }
  d.dst[b*256 + t] = f2bf(v);
}

// permuted qkv biases + reordered LN params + zero guard page
__global__ __launch_bounds__(256) void k_biasperm(const float* __restrict__ b0, const float* __restrict__ b1,
    const float* kw0, const float* kb0, const float* vw0, const float* vb0,
    const float* kw1, const float* kb1, const float* vw1, const float* vb1,
    float* __restrict__ dstB, float* __restrict__ lnw2, float* __restrict__ lnb2,
    __hip_bfloat16* __restrict__ zpage){
  int t = threadIdx.x;
  zpage[t] = f2bf(0.0f);
  #pragma unroll
  for(int br=0;br<2;br++){
    const float* s = br ? b1 : b0;
    #pragma unroll
    for(int part=0;part<3;part++)
      dstB[br*768 + part*256 + t] = s[48*(t>>4) + part*16 + (t&15)];
  }
  #pragma unroll
  for(int br=0;br<2;br++){
    #pragma unroll
    for(int half=0;half<2;half++){
      int j = half*256 + t;
      int h = j>>5, idx = j&31;
      bool isK = idx<16;
      int c = isK ? idx : idx-16;
      const float* w = isK ? (br?kw1:kw0) : (br?vw1:vw0);
      const float* bb= isK ? (br?kb1:kb0) : (br?vb1:vb0);
      lnw2[br*512 + j] = w[h*16+c];
      lnb2[br*512 + j] = bb[h*16+c];
    }
  }
}

// ---------------- small row-major matmul: C = (A[+I]) @ B ----------------
template<int ADDI>
__global__ __launch_bounds__(256) void k_smallmm(const __hip_bfloat16* __restrict__ A,
    const __hip_bfloat16* __restrict__ B, __hip_bfloat16* __restrict__ C){
  __shared__ float ar[256];
  int i = blockIdx.x, t = threadIdx.x;
  float a = bf2f(A[(size_t)i*256 + t]);
  if(ADDI && t==i) a += 1.0f;
  ar[t] = a;
  __syncthreads();
  float a0=0.f,a1=0.f,a2=0.f,a3=0.f;
  for(int l=0;l<256;l+=4){
    a0 += ar[l+0]*bf2f(B[(l+0)*256 + t]);
    a1 += ar[l+1]*bf2f(B[(l+1)*256 + t]);
    a2 += ar[l+2]*bf2f(B[(l+2)*256 + t]);
    a3 += ar[l+3]*bf2f(B[(l+3)*256 + t]);
  }
  C[(size_t)i*256 + t] = f2bf((a0+a1)+(a2+a3));
}

__global__ __launch_bounds__(256) void k_smallmmR(const __hip_bfloat16* __restrict__ A,
    const __hip_bfloat16* __restrict__ B, __hip_bfloat16* __restrict__ C){
  __shared__ float ar[256];
  int j = blockIdx.x, t = threadIdx.x;
  int src = kvmap(j);
  ar[t] = bf2f(A[(size_t)src*256 + t]);
  __syncthreads();
  float a0=0.f,a1=0.f,a2=0.f,a3=0.f;
  for(int l=0;l<256;l+=4){
    a0 += ar[l+0]*bf2f(B[(l+0)*256 + t]);
    a1 += ar[l+1]*bf2f(B[(l+1)*256 + t]);
    a2 += ar[l+2]*bf2f(B[(l+2)*256 + t]);
    a3 += ar[l+3]*bf2f(B[(l+3)*256 + t]);
  }
  C[(size_t)j*256 + t] = f2bf((a0+a1)+(a2+a3));
}

__global__ __launch_bounds__(256) void k_bkv2R(const float* __restrict__ b2, const float* __restrict__ biaskv,
    const __hip_bfloat16* __restrict__ kvT_, float* __restrict__ outb){
  __shared__ float s_b2[256];
  int t = threadIdx.x; int n = blockIdx.x*256 + t;
  int src = kvmap(n);
  s_b2[t] = b2[t];
  __syncthreads();
  float v = biaskv[src];
  for(int l=0;l<256;l++) v += s_b2[l]*bf2f(kvT_[(size_t)src*256 + l]);
  outb[n] = v;
}

// ---------------- c1 = ((b2@(Wfold+I)+bfold) @ Wp) + bp ----------------
__global__ __launch_bounds__(256) void k_cvec(const float* __restrict__ b2, const float* __restrict__ bfold,
    const __hip_bfloat16* __restrict__ WfoldT, const __hip_bfloat16* __restrict__ projT_,
    const float* __restrict__ bp, float* __restrict__ c1){
  __shared__ float s_b2[256], s_r[256];
  int t = threadIdx.x;
  s_b2[t] = b2[t];
  __syncthreads();
  float r = s_b2[t] + bfold[t];
  for(int l=0;l<256;l++) r += s_b2[l]*bf2f(WfoldT[(size_t)t*256 + l]);
  s_r[t] = r;
  __syncthreads();
  float c = bp[t];
  for(int l=0;l<256;l++) c += s_r[l]*bf2f(projT_[(size_t)t*256 + l]);
  c1[t] = c;
}

// ---------------- per-query sampling geometry + result_bil ----------------
__global__ __launch_bounds__(256) void k_sample(const float* __restrict__ coord, const float* __restrict__ inp,
    float* __restrict__ mf, int* __restrict__ mi, float* __restrict__ bil){
  int q = blockIdx.x*256 + threadIdx.x;
  float cy = coord[2*q], cx = coord[2*q+1];
  const float LO = (float)(-1.0 + 1e-6), HI = (float)(1.0 - 1e-6);
  const float ONEG = (float)(-1.0/64.0 + 1e-6), OPOS = (float)(1.0/64.0 + 1e-6);
  float areas[4];
  #pragma unroll
  for(int s=0;s<4;s++){
    float oy = (s<2)?ONEG:OPOS;
    float ox = (s&1)?OPOS:ONEG;
    float csy = fminf(fmaxf(cy+oy, LO), HI);
    float csx = fminf(fmaxf(cx+ox, LO), HI);
    float fy = ((csy+1.0f)*64.0f - 1.0f)*0.5f;
    float fx = ((csx+1.0f)*64.0f - 1.0f)*0.5f;
    int iy = (int)rintf(fy); iy = iy<0?0:(iy>63?63:iy);
    int ix = (int)rintf(fx); ix = ix<0?0:(ix>63?63:ix);
    float qcy = -1.0f + (float)(2*iy+1)*0.015625f;
    float qcx = -1.0f + (float)(2*ix+1)*0.015625f;
    float ry = (cy-qcy)*64.0f, rx = (cx-qcx)*64.0f;
    mf[q*16 + 4 + 2*s] = ry; mf[q*16 + 5 + 2*s] = rx;
    areas[s] = fabsf(ry*rx) + 1e-9f;
    mi[q*8 + s] = iy*64 + ix;
  }
  float tot = areas[0]+areas[1]+areas[2]+areas[3];
  #pragma unroll
  for(int s=0;s<4;s++) mf[q*16 + s] = areas[3-s] / tot;

  float fy = ((cy+1.0f)*64.0f - 1.0f)*0.5f;
  float fx = ((cx+1.0f)*64.0f - 1.0f)*0.5f;
  {
    float y0 = floorf(fy), x0 = floorf(fx);
    float wy = fy-y0, wx = fx-x0;
    int y0i = (int)y0, x0i = (int)x0;
    float cw[4] = {(1.0f-wy)*(1.0f-wx), (1.0f-wy)*wx, wy*(1.0f-wx), wy*wx};
    #pragma unroll
    for(int c2=0;c2<4;c2++){
      int yi = y0i + (c2>>1), xi = x0i + (c2&1);
      bool ok = (yi>=0 && yi<64 && xi>=0 && xi<64);
      int yc = yi<0?0:(yi>63?63:yi), xc = xi<0?0:(xi>63?63:xi);
      mf[q*16 + 12 + c2] = ok ? cw[c2] : 0.0f;
      mi[q*8 + 4 + c2] = yc*64 + xc;
    }
  }
  {
    float fyb = fminf(fmaxf(fy, 0.0f), 63.0f);
    float fxb = fminf(fmaxf(fx, 0.0f), 63.0f);
    float y0 = floorf(fyb), x0 = floorf(fxb);
    float wy = fyb-y0, wx = fxb-x0;
    int y0i = (int)y0, x0i = (int)x0;
    float cw[4] = {(1.0f-wy)*(1.0f-wx), (1.0f-wy)*wx, wy*(1.0f-wx), wy*wx};
    float a0=0,a1=0,a2=0;
    #pragma unroll
    for(int c2=0;c2<4;c2++){
      int yi = y0i + (c2>>1), xi = x0i + (c2&1);
      if(yi>=0 && yi<64 && xi>=0 && xi<64){
        int idx = yi*64+xi; float wgt = cw[c2];
        a0 += inp[idx]*wgt; a1 += inp[4096+idx]*wgt; a2 += inp[8192+idx]*wgt;
      }
    }
    bil[q*3+0]=a0; bil[q*3+1]=a1; bil[q*3+2]=a2;
  }
}

// ---------------- stage-1 MLP via P-gather ----------------
template<int BR>
__global__ __launch_bounds__(256) void k_stage1(const __hip_bfloat16* __restrict__ P, const float* __restrict__ mf,
    const int* __restrict__ mi, const float* __restrict__ coord, const float* __restrict__ cell,
    const float* __restrict__ W1, const float* __restrict__ b1, __hip_bfloat16* __restrict__ out){
  __shared__ float wsm[11][256];
  int j = threadIdx.x;
  if(BR==0){
    #pragma unroll
    for(int r=0;r<8;r++) wsm[r][j] = W1[r*256 + j];
    wsm[8][j] = W1[1032*256 + j];
    wsm[9][j] = W1[1033*256 + j];
    wsm[10][j] = b1[j];
  } else {
    wsm[0][j] = W1[0*256 + j];
    wsm[1][j] = W1[1*256 + j];
    wsm[2][j] = W1[258*256 + j];
    wsm[3][j] = W1[259*256 + j];
    wsm[4][j] = b1[j];
  }
  __syncthreads();
  int q0 = blockIdx.x*32;
  for(int qq=0;qq<32;qq++){
    int q = q0+qq;
    float acc;
    const float* m = mf + q*16;
    const int* ii = mi + q*8;
    if(BR==0){
      acc = wsm[10][j];
      #pragma unroll
      for(int r=0;r<8;r++) acc += m[4+r]*wsm[r][j];
      float cly = cell[2*q]*64.0f, clx = cell[2*q+1]*64.0f;
      acc += cly*wsm[8][j] + clx*wsm[9][j];
      #pragma unroll
      for(int s=0;s<4;s++) acc += m[s]*bf2f(P[(size_t)ii[s]*1280 + s*256 + j]);
    } else {
      acc = wsm[4][j];
      float cy = coord[2*q], cx = coord[2*q+1];
      float cly = cell[2*q]*64.0f, clx = cell[2*q+1]*64.0f;
      acc += cy*wsm[0][j] + cx*wsm[1][j] + cly*wsm[2][j] + clx*wsm[3][j];
      #pragma unroll
      for(int c2=0;c2<4;c2++) acc += m[12+c2]*bf2f(P[(size_t)ii[4+c2]*1280 + 1024 + j]);
    }
    out[(size_t)q*256 + j] = f2bf(gelu_f(acc));
  }
}

// ---------------- MFMA bf16 GEMM v4: 8 waves, 34 KB LDS, half-tile epilogue ----------------
template<int ACT,int NRES>
__global__ __launch_bounds__(512) void k_gemm_mfma(
    const __hip_bfloat16* __restrict__ A, const __hip_bfloat16* __restrict__ BT,
    const float* __restrict__ bias, const __hip_bfloat16* __restrict__ R1,
    const __hip_bfloat16* __restrict__ R2, __hip_bfloat16* __restrict__ C,
    int M, int N, int K, int ldc){
  __shared__ __align__(1024) char smem[64*133*4];
  const int t = threadIdx.x, wave = t>>6, lane = t&63;
  const int MT = M>>7, NT = N>>7;
  const int b = blockIdx.x, xcd = b&7, i = b>>3;
  const int nt = i % NT, mtl = i / NT;
  const int m0 = (xcd*(MT>>3) + mtl) << 7, n0 = nt << 7;
  const int wr = (wave>>2)*64, wc = (wave&3)*32;
  const int lr = lane&15, lh = lane>>4;

  f32x4 acc[4][2] = {};
  const int ntiles = K>>6;
  for(int kt=0; kt<ntiles; ++kt){
    __syncthreads();
    #pragma unroll
    for(int q2=0;q2<2;q2++){
      int c = (wave*2+q2)*64 + lane;
      int row = c>>3; int k8 = (c&7) ^ (row&7);
      __hip_bfloat16* la = (__hip_bfloat16*)smem + (size_t)(wave*2+q2)*512;
      __hip_bfloat16* lb = (__hip_bfloat16*)(smem + 16384) + (size_t)(wave*2+q2)*512;
      load_lds16(A  + (size_t)(m0+row)*K + (kt*64 + k8*8), la);
      load_lds16(BT + (size_t)(n0+row)*K + (kt*64 + k8*8), lb);
    }
    __syncthreads();
    const __hip_bfloat16* Ab = (const __hip_bfloat16*)smem;
    const __hip_bfloat16* Bb = (const __hip_bfloat16*)(smem + 16384);
    #pragma unroll
    for(int kk=0;kk<2;kk++){
      bf16x8 af[4], bfr[2];
      #pragma unroll
      for(int m=0;m<4;m++){
        int row = wr + m*16 + lr;
        int p = (kk*4 + lh) ^ (row&7);
        af[m] = *reinterpret_cast<const bf16x8*>(Ab + row*64 + p*8);
      }
      #pragma unroll
      for(int n=0;n<2;n++){
        int row = wc + n*16 + lr;
        int p = (kk*4 + lh) ^ (row&7);
        bfr[n] = *reinterpret_cast<const bf16x8*>(Bb + row*64 + p*8);
      }
      #pragma unroll
      for(int m=0;m<4;m++)
        #pragma unroll
        for(int n=0;n<2;n++)
          acc[m][n] = __builtin_amdgcn_mfma_f32_16x16x32_bf16(af[m], bfr[n], acc[m][n], 0,0,0);
    }
  }

  float* epi = (float*)smem;
  #pragma unroll
  for(int hf=0; hf<2; ++hf){
    __syncthreads();
    if((wave>>2) == hf){
      #pragma unroll
      for(int m=0;m<4;m++)
        #pragma unroll
        for(int n=0;n<2;n++){
          int col = wc + n*16 + lr;
          #pragma unroll
          for(int j=0;j<4;j++)
            epi[(m*16 + lh*4 + j)*133 + col] = acc[m][n][j];
        }
    }
    __syncthreads();
    const int lrow = t>>3, c0 = (t&7)*16;
    const size_t grow = (size_t)(m0 + hf*64 + lrow);
    const float* er = epi + lrow*133;
    #pragma unroll
    for(int half=0; half<2; half++){
      int cb = c0 + half*8;
      int gc = n0 + cb;
      float v[8];
      #pragma unroll
      for(int e=0;e<8;e++) v[e] = er[cb+e];
      if(bias){
        #pragma unroll
        for(int e=0;e<8;e++) v[e] += bias[gc+e];
      }
      if(ACT==1){
        #pragma unroll
        for(int e=0;e<8;e++) v[e] = gelu_f(v[e]);
      }
      if(NRES==1 || NRES==2){
        uint4 r = *reinterpret_cast<const uint4*>(R1 + grow*ldc + gc);
        unsigned rw[4] = {r.x,r.y,r.z,r.w};
        #pragma unroll
        for(int q2=0;q2<4;q2++){ v[2*q2] += bflo(rw[q2]); v[2*q2+1] += bfhi(rw[q2]); }
      }
      if(NRES==2){
        uint4 r = *reinterpret_cast<const uint4*>(R2 + grow*ldc + gc);
        unsigned rw[4] = {r.x,r.y,r.z,r.w};
        #pragma unroll
        for(int q2=0;q2<4;q2++){ v[2*q2] += bflo(rw[q2]); v[2*q2+1] += bfhi(rw[q2]); }
      }
      uint4 o;
      o.x = pack2bf(v[0],v[1]); o.y = pack2bf(v[2],v[3]);
      o.z = pack2bf(v[4],v[5]); o.w = pack2bf(v[6],v[7]);
      *reinterpret_cast<uint4*>(C + grow*ldc + gc) = o;
    }
  }
}

// ---------------- freq conv GEMM: A gathered from featP via tap-offset (4-wave) ----------------
__global__ __launch_bounds__(256) void k_gfreq(
    const __hip_bfloat16* __restrict__ featP, const __hip_bfloat16* __restrict__ zpage,
    const __hip_bfloat16* __restrict__ BT, const float* __restrict__ bias,
    __hip_bfloat16* __restrict__ C){
  __shared__ __align__(1024) char smem[64*133*4];
  const int t = threadIdx.x, wave = t>>6, lane = t&63;
  const int MT = 32, NT = 2;
  const int b = blockIdx.x, xcd = b&7, i = b>>3;
  const int nt = i % NT, mtl = i / NT;
  const int m0 = (xcd*(MT>>3) + mtl) << 7, n0 = nt << 7;
  const int wr = (wave>>1)*64, wc = (wave&1)*64;
  const int lr = lane&15, lh = lane>>4;

  f32x4 acc[4][4] = {};
  for(int kt=0; kt<9; ++kt){
    int ky = kt/3, kx = kt - ky*3;
    __syncthreads();
    #pragma unroll
    for(int q2=0;q2<4;q2++){
      int c = (wave*4+q2)*64 + lane;
      int row = c>>3; int k8 = (c&7) ^ (row&7);
      __hip_bfloat16* la = (__hip_bfloat16*)smem + (size_t)(wave*4+q2)*512;
      __hip_bfloat16* lb = (__hip_bfloat16*)(smem + 16384) + (size_t)(wave*4+q2)*512;
      int pix = m0+row, y = pix>>6, x = pix&63;
      int yy = y+ky-1, xx = x+kx-1;
      const __hip_bfloat16* src = ((unsigned)yy<64u && (unsigned)xx<64u) ?
          (featP + (size_t)(yy*64+xx)*64 + k8*8) : (zpage + k8*8);
      load_lds16(src, la);
      load_lds16(BT + (size_t)(n0+row)*640 + (kt*64 + k8*8), lb);
    }
    __syncthreads();
    const __hip_bfloat16* Ab = (const __hip_bfloat16*)smem;
    const __hip_bfloat16* Bb = (const __hip_bfloat16*)(smem + 16384);
    #pragma unroll
    for(int kk=0;kk<2;kk++){
      bf16x8 af[4], bfr[4];
      #pragma unroll
      for(int m=0;m<4;m++){
        int row = wr + m*16 + lr;
        int p = (kk*4 + lh) ^ (row&7);
        af[m] = *reinterpret_cast<const bf16x8*>(Ab + row*64 + p*8);
      }
      #pragma unroll
      for(int n=0;n<4;n++){
        int row = wc + n*16 + lr;
        int p = (kk*4 + lh) ^ (row&7);
        bfr[n] = *reinterpret_cast<const bf16x8*>(Bb + row*64 + p*8);
      }
      #pragma unroll
      for(int m=0;m<4;m++)
        #pragma unroll
        for(int n=0;n<4;n++)
          acc[m][n] = __builtin_amdgcn_mfma_f32_16x16x32_bf16(af[m], bfr[n], acc[m][n], 0,0,0);
    }
  }

  float* epi = (float*)smem;
  const int cg = t&3;
  #pragma unroll
  for(int hf=0; hf<2; ++hf){
    __syncthreads();
    if((wave>>1) == hf){
      #pragma unroll
      for(int m=0;m<4;m++)
        #pragma unroll
        for(int n=0;n<4;n++){
          int col = wc + n*16 + lr;
          #pragma unroll
          for(int j=0;j<4;j++)
            epi[(m*16 + lh*4 + j)*133 + col] = acc[m][n][j];
        }
    }
    __syncthreads();
    const int lrow = t>>2, c0 = cg*32;
    const size_t grow = (size_t)(m0 + hf*64 + lrow);
    const float* er = epi + lrow*133;
    #pragma unroll
    for(int g0=0; g0<4; g0++){
      int g = (g0 + cg) & 3;
      int cb = c0 + g*8;
      int gc = n0 + cb;
      float v[8];
      #pragma unroll
      for(int e=0;e<8;e++) v[e] = er[cb+e] + bias[gc+e];
      uint4 o;
      o.x = pack2bf(v[0],v[1]); o.y = pack2bf(v[2],v[3]);
      o.z = pack2bf(v[4],v[5]); o.w = pack2bf(v[6],v[7]);
      *reinterpret_cast<uint4*>(C + grow*256 + gc) = o;
    }
  }
}

// ---------------- fused kv v2 (8 waves): GEMM + bias + LDS-transposed LN + split-K head outer product ----
__global__ __launch_bounds__(512) void k_kvln(
    const __hip_bfloat16* __restrict__ A, const __hip_bfloat16* __restrict__ BT,
    const float* __restrict__ bias, const float* __restrict__ lnw, const float* __restrict__ lnb,
    float* __restrict__ kvpart){
  __shared__ __align__(1024) char smem[34816];
  const int t = threadIdx.x, wave = t>>6, lane = t&63;
  const int MT = 512, NT = 4;
  const int b = blockIdx.x, xcd = b&7, i = b>>3;
  const int nt = i % NT, mtl = i / NT;
  const int m0 = (xcd*(MT>>3) + mtl) << 7, n0 = nt << 7;
  const int wr = (wave>>2)*64, wc = (wave&3)*32;
  const int lr = lane&15, lh = lane>>4;

  f32x4 acc[4][2] = {};
  for(int kt=0; kt<4; ++kt){
    __syncthreads();
    #pragma unroll
    for(int q2=0;q2<2;q2++){
      int c = (wave*2+q2)*64 + lane;
      int row = c>>3; int k8 = (c&7) ^ (row&7);
      __hip_bfloat16* la = (__hip_bfloat16*)smem + (size_t)(wave*2+q2)*512;
      __hip_bfloat16* lb = (__hip_bfloat16*)(smem + 16384) + (size_t)(wave*2+q2)*512;
      load_lds16(A  + (size_t)(m0+row)*256 + (kt*64 + k8*8), la);
      load_lds16(BT + (size_t)(n0+row)*256 + (kt*64 + k8*8), lb);
    }
    __syncthreads();
    const __hip_bfloat16* Ab = (const __hip_bfloat16*)smem;
    const __hip_bfloat16* Bb = (const __hip_bfloat16*)(smem + 16384);
    #pragma unroll
    for(int kk=0;kk<2;kk++){
      bf16x8 af[4], bfr[2];
      #pragma unroll
      for(int m=0;m<4;m++){
        int row = wr + m*16 + lr;
        int p = (kk*4 + lh) ^ (row&7);
        af[m] = *reinterpret_cast<const bf16x8*>(Ab + row*64 + p*8);
      }
      #pragma unroll
      for(int n=0;n<2;n++){
        int row = wc + n*16 + lr;
        int p = (kk*4 + lh) ^ (row&7);
        bfr[n] = *reinterpret_cast<const bf16x8*>(Bb + row*64 + p*8);
      }
      #pragma unroll
      for(int m=0;m<4;m++)
        #pragma unroll
        for(int n=0;n<2;n++)
          acc[m][n] = __builtin_amdgcn_mfma_f32_16x16x32_bf16(af[m], bfr[n], acc[m][n], 0,0,0);
    }
  }
  __syncthreads();

  __hip_bfloat16* knT = (__hip_bfloat16*)smem;            // [4 heads][16 cols][136 rows]
  __hip_bfloat16* vnT = (__hip_bfloat16*)(smem + 17408);
  #pragma unroll
  for(int m=0;m<4;m++){
    #pragma unroll
    for(int n=0;n<2;n++){
      int cl = wc + n*16 + lr;
      int gcol = n0 + cl;
      float bs = bias[gcol];
      int h2 = cl>>5, isV = (cl>>4)&1;
      short4 pk;
      #pragma unroll
      for(int j=0;j<4;j++) ((__hip_bfloat16*)&pk)[j] = f2bf(acc[m][n][j] + bs);
      int r = wr + m*16 + lh*4;
      __hip_bfloat16* dst = (isV ? vnT : knT) + (h2*16 + lr)*136 + r;
      *reinterpret_cast<short4*>(dst) = pk;
    }
  }
  __syncthreads();
  #pragma unroll
  for(int i4=0; i4<2; ++i4){
    int task = i4*512 + t;
    int r = task & 127, hv = task >> 7;
    int h2 = hv >> 1, isV = hv & 1;
    __hip_bfloat16* base = (isV ? vnT : knT) + (h2*16)*136 + r;
    float xs[16];
    float s=0.0f, s2=0.0f;
    #pragma unroll
    for(int c=0;c<16;c++){ xs[c] = bf2f(base[c*136]); s += xs[c]; s2 += xs[c]*xs[c]; }
    float mean = s*0.0625f;
    float var = (s2 - 16.0f*mean*mean)*(1.0f/15.0f); var = var<0.0f?0.0f:var;
    float inv = 1.0f/(sqrtf(var) + 1e-5f);
    int gbase = n0 + h2*32 + isV*16;
    #pragma unroll
    for(int c=0;c<16;c++)
      base[c*136] = f2bf(lnw[gbase+c]*((xs[c]-mean)*inv) + lnb[gbase+c]);
  }
  __syncthreads();
  // split-K outer product: wave w -> head (w>>1), K-half (w&1); 2 MFMAs over 64 rows
  {
    const int hloc = wave>>1, kh = wave&1;
    f32x4 kacc = {};
    #pragma unroll
    for(int kk=0;kk<2;kk++){
      int off = kh*64 + kk*32 + lh*8;
      bf16x8 af  = *reinterpret_cast<const bf16x8*>(knT + (hloc*16 + lr)*136 + off);
      bf16x8 bf_ = *reinterpret_cast<const bf16x8*>(vnT + (hloc*16 + lr)*136 + off);
      kacc = __builtin_amdgcn_mfma_f32_16x16x32_bf16(af, bf_, kacc, 0,0,0);
    }
    const int mt = m0>>7;
    const int hglob = nt*4 + hloc;
    #pragma unroll
    for(int j=0;j<4;j++)
      kvpart[((size_t)mt*2 + kh)*4096 + hglob*256 + (lh*4+j)*16 + lr] = kacc[j];
  }
}

// ---------------- G12 fused v3 (8 waves): C = gelu(A@B1^T + c1) + (A@B2^T + b2) [+R] ----------------
template<int NRES>
__global__ __launch_bounds__(512) void k_gemm12(
    const __hip_bfloat16* __restrict__ A, const __hip_bfloat16* __restrict__ B1T,
    const float* __restrict__ c1, const __hip_bfloat16* __restrict__ B2T,
    const float* __restrict__ b2, const __hip_bfloat16* __restrict__ R,
    __hip_bfloat16* __restrict__ C){
  __shared__ __align__(1024) char smem[49152];
  const int t = threadIdx.x, wave = t>>6, lane = t&63;
  const int MT = 512, NT = 2;
  const int b = blockIdx.x, xcd = b&7, i = b>>3;
  const int nt = i % NT, mtl = i / NT;
  const int m0 = (xcd*(MT>>3) + mtl) << 7, n0 = nt << 7;
  const int wr = (wave>>2)*64, wc = (wave&3)*32;
  const int lr = lane&15, lh = lane>>4;
  f32x4 acc1[4][2] = {}, acc2[4][2] = {};
  for(int k0=0;k0<256;k0+=64){
    __syncthreads();
    #pragma unroll
    for(int q2=0;q2<2;q2++){
      int c = (wave*2+q2)*64 + lane;
      int row = c>>3; int k8 = (c&7) ^ (row&7);
      __hip_bfloat16* base = (__hip_bfloat16*)smem + (size_t)(wave*2+q2)*512;
      load_lds16(A   + (size_t)(m0+row)*256 + (k0 + k8*8), base);
      load_lds16(B1T + (size_t)(n0+row)*256 + (k0 + k8*8), base + 8192);
      load_lds16(B2T + (size_t)(n0+row)*256 + (k0 + k8*8), base + 16384);
    }
    __syncthreads();
    const __hip_bfloat16* Ab = (const __hip_bfloat16*)smem;
    #pragma unroll
    for(int kk=0;kk<2;kk++){
      bf16x8 af[4], bfr[2];
      #pragma unroll
      for(int m=0;m<4;m++){
        int row = wr + m*16 + lr;
        int p = (kk*4 + lh) ^ (row&7);
        af[m] = *reinterpret_cast<const bf16x8*>(Ab + row*64 + p*8);
      }
      #pragma unroll
      for(int n=0;n<2;n++){
        int row = wc + n*16 + lr;
        int p = (kk*4 + lh) ^ (row&7);
        bfr[n] = *reinterpret_cast<const bf16x8*>(Ab + 8192 + row*64 + p*8);
      }
      #pragma unroll
      for(int m=0;m<4;m++)
        #pragma unroll
        for(int n=0;n<2;n++)
          acc1[m][n] = __builtin_amdgcn_mfma_f32_16x16x32_bf16(af[m], bfr[n], acc1[m][n], 0,0,0);
      #pragma unroll
      for(int n=0;n<2;n++){
        int row = wc + n*16 + lr;
        int p = (kk*4 + lh) ^ (row&7);
        bfr[n] = *reinterpret_cast<const bf16x8*>(Ab + 16384 + row*64 + p*8);
      }
      #pragma unroll
      for(int m=0;m<4;m++)
        #pragma unroll
        for(int n=0;n<2;n++)
          acc2[m][n] = __builtin_amdgcn_mfma_f32_16x16x32_bf16(af[m], bfr[n], acc2[m][n], 0,0,0);
    }
  }
  float* epi = (float*)smem;
  #pragma unroll
  for(int hf=0; hf<2; ++hf){
    const int lrow = t>>3, c0 = (t&7)*16;
    const size_t grow = (size_t)(m0 + hf*64 + lrow);
    float v1[16];
    __syncthreads();
    if((wave>>2) == hf){
      #pragma unroll
      for(int m=0;m<4;m++)
        #pragma unroll
        for(int n=0;n<2;n++){
          int col = wc + n*16 + lr;
          #pragma unroll
          for(int j=0;j<4;j++)
            epi[(m*16 + lh*4 + j)*133 + col] = acc1[m][n][j];
        }
    }
    __syncthreads();
    {
      const float* er = epi + lrow*133;
      #pragma unroll
      for(int e=0;e<16;e++) v1[e] = gelu_f(er[c0+e] + c1[n0+c0+e]);
    }
    __syncthreads();
    if((wave>>2) == hf){
      #pragma unroll
      for(int m=0;m<4;m++)
        #pragma unroll
        for(int n=0;n<2;n++){
          int col = wc + n*16 + lr;
          #pragma unroll
          for(int j=0;j<4;j++)
            epi[(m*16 + lh*4 + j)*133 + col] = acc2[m][n][j];
        }
    }
    __syncthreads();
    {
      const float* er = epi + lrow*133;
      #pragma unroll
      for(int half=0; half<2; half++){
        int cb = c0 + half*8;
        int gc = n0 + cb;
        float v[8];
        #pragma unroll
        for(int e=0;e<8;e++) v[e] = v1[half*8+e] + er[cb+e] + b2[gc+e];
        if(NRES==1){
          uint4 r = *reinterpret_cast<const uint4*>(R + grow*256 + gc);
          unsigned rw[4] = {r.x,r.y,r.z,r.w};
          #pragma unroll
          for(int q2=0;q2<4;q2++){ v[2*q2] += bflo(rw[q2]); v[2*q2+1] += bfhi(rw[q2]); }
        }
        uint4 o;
        o.x = pack2bf(v[0],v[1]); o.y = pack2bf(v[2],v[3]);
        o.z = pack2bf(v[4],v[5]); o.w = pack2bf(v[6],v[7]);
        *reinterpret_cast<uint4*>(C + grow*256 + gc) = o;
      }
    }
  }
}

// ---------------- fc3+final fused v3 (8 waves): part[nt][row][3] ----------------
__global__ __launch_bounds__(512) void k_gemmF(
    const __hip_bfloat16* __restrict__ A, const __hip_bfloat16* __restrict__ BT,
    const float* __restrict__ bias, const float* __restrict__ W4,
    float* __restrict__ part){
  __shared__ __align__(1024) char smem[64*133*4];
  __shared__ float w4s[768];
  const int t = threadIdx.x, wave = t>>6, lane = t&63;
  const int MT = 512, NT = 2;
  const int b = blockIdx.x, xcd = b&7, i = b>>3;
  const int nt = i % NT, mtl = i / NT;
  const int m0 = (xcd*(MT>>3) + mtl) << 7, n0 = nt << 7;
  const int wr = (wave>>2)*64, wc = (wave&3)*32;
  const int lr = lane&15, lh = lane>>4;
  for(int l=t;l<768;l+=512) w4s[l] = W4[l];

  f32x4 acc[4][2] = {};
  for(int kt=0; kt<4; ++kt){
    __syncthreads();
    #pragma unroll
    for(int q2=0;q2<2;q2++){
      int c = (wave*2+q2)*64 + lane;
      int row = c>>3; int k8 = (c&7) ^ (row&7);
      __hip_bfloat16* la = (__hip_bfloat16*)smem + (size_t)(wave*2+q2)*512;
      __hip_bfloat16* lb = (__hip_bfloat16*)(smem + 16384) + (size_t)(wave*2+q2)*512;
      load_lds16(A  + (size_t)(m0+row)*256 + (kt*64 + k8*8), la);
      load_lds16(BT + (size_t)(n0+row)*256 + (kt*64 + k8*8), lb);
    }
    __syncthreads();
    const __hip_bfloat16* Ab = (const __hip_bfloat16*)smem;
    const __hip_bfloat16* Bb = (const __hip_bfloat16*)(smem + 16384);
    #pragma unroll
    for(int kk=0;kk<2;kk++){
      bf16x8 af[4], bfr[2];
      #pragma unroll
      for(int m=0;m<4;m++){
        int row = wr + m*16 + lr;
        int p = (kk*4 + lh) ^ (row&7);
        af[m] = *reinterpret_cast<const bf16x8*>(Ab + row*64 + p*8);
      }
      #pragma unroll
      for(int n=0;n<2;n++){
        int row = wc + n*16 + lr;
        int p = (kk*4 + lh) ^ (row&7);
        bfr[n] = *reinterpret_cast<const bf16x8*>(Bb + row*64 + p*8);
      }
      #pragma unroll
      for(int m=0;m<4;m++)
        #pragma unroll
        for(int n=0;n<2;n++)
          acc[m][n] = __builtin_amdgcn_mfma_f32_16x16x32_bf16(af[m], bfr[n], acc[m][n], 0,0,0);
    }
  }

  float* epi = (float*)smem;
  #pragma unroll
  for(int hf=0; hf<2; ++hf){
    __syncthreads();
    if((wave>>2) == hf){
      #pragma unroll
      for(int m=0;m<4;m++)
        #pragma unroll
        for(int n=0;n<2;n++){
          int col = wc + n*16 + lr;
          #pragma unroll
          for(int j=0;j<4;j++)
            epi[(m*16 + lh*4 + j)*133 + col] = acc[m][n][j];
        }
    }
    __syncthreads();
    {
      const int lrow = t>>3, c0 = (t&7)*16;
      const float* er = epi + lrow*133;
      float s0=0.f, s1=0.f, s2=0.f;
      #pragma unroll
      for(int e=0;e<16;e++){
        int gc = n0 + c0 + e;
        float v = gelu_f(er[c0+e] + bias[gc]);
        s0 += v*w4s[gc*3+0];
        s1 += v*w4s[gc*3+1];
        s2 += v*w4s[gc*3+2];
      }
      s0 += __shfl_xor(s0,1); s0 += __shfl_xor(s0,2); s0 += __shfl_xor(s0,4);
      s1 += __shfl_xor(s1,1); s1 += __shfl_xor(s1,2); s1 += __shfl_xor(s1,4);
      s2 += __shfl_xor(s2,1); s2 += __shfl_xor(s2,2); s2 += __shfl_xor(s2,4);
      if((t&7)==0){
        float* pp = part + (size_t)nt*196608 + (size_t)(m0 + hf*64 + lrow)*3;
        pp[0]=s0; pp[1]=s1; pp[2]=s2;
      }
    }
  }
}

__global__ __launch_bounds__(256) void k_combine(const float* __restrict__ part, const float* __restrict__ b4,
    const float* __restrict__ bil, float* __restrict__ out){
  int i = blockIdx.x*256 + threadIdx.x;
  int j = i - (i/3)*3;
  out[i] = part[i] + part[196608 + i] + b4[j] + bil[i];
}

// kvred: 256 blocks; sums 1024 split-K partials per output element
__global__ __launch_bounds__(256) void k_kvred(const float* __restrict__ kvpart, float* __restrict__ kv){
  __shared__ float sm[256];
  int b = blockIdx.x, t = threadIdx.x;
  int d = t & 15, seg = t >> 4;
  float s = 0.0f;
  for(int k=0;k<64;k++) s += kvpart[(size_t)(seg*64+k)*4096 + b*16 + d];
  sm[t] = s;
  __syncthreads();
  if(t < 16){
    float r = 0.0f;
    #pragma unroll
    for(int g=0; g<16; g++) r += sm[g*16 + t];
    kv[b*16 + t] = r * (1.0f/65536.0f);
  }
}

// ---------------- fold q-projection through kv ----------------
__global__ __launch_bounds__(256) void k_fold(const __hip_bfloat16* __restrict__ qT,
    const float* __restrict__ biasq, const float* __restrict__ kv,
    __hip_bfloat16* __restrict__ WfoldT, float* __restrict__ bfold){
  int n = blockIdx.x, t = threadIdx.x;
  int h = n>>4, d = n&15;
  float s = 0.0f;
  #pragma unroll
  for(int c=0;c<16;c++)
    s += bf2f(qT[(size_t)(h*16+c)*256 + t]) * kv[h*256 + c*16 + d];
  WfoldT[(size_t)n*256 + t] = f2bf(s);
  if(t==0){
    float b=0.0f;
    #pragma unroll
    for(int c=0;c<16;c++) b += biasq[h*16+c]*kv[h*256+c*16+d];
    bfold[n]=b;
  }
}

extern "C" void kernel_launch(void* const* d_in, const int* in_sizes, int n_in,
                              void* d_out, int out_size, void* d_ws, size_t ws_size,
                              hipStream_t stream){
  (void)in_sizes; (void)n_in; (void)out_size;
  const float* inp     = (const float*)d_in[0];
  const float* coord   = (const float*)d_in[1];
  const float* cell    = (const float*)d_in[2];
  const float* enc_w   = (const float*)d_in[3];
  const float* enc_b   = (const float*)d_in[4];
  const float* freq_w  = (const float*)d_in[5];
  const float* freq_b  = (const float*)d_in[6];
  const float* out0_w1 = (const float*)d_in[7];
  const float* out0_b1 = (const float*)d_in[8];
  const float* out0_w2 = (const float*)d_in[9];
  const float* out0_b2 = (const float*)d_in[10];
  const float* out1_w1 = (const float*)d_in[11];
  const float* out1_b1 = (const float*)d_in[12];
  const float* out1_w2 = (const float*)d_in[13];
  const float* out1_b2 = (const float*)d_in[14];
  const float* fc1_w1  = (const float*)d_in[15];
  const float* fc1_b1  = (const float*)d_in[16];
  const float* fc1_w2  = (const float*)d_in[17];
  const float* fc1_b2  = (const float*)d_in[18];
  const float* fc2_w1  = (const float*)d_in[19];
  const float* fc2_b1  = (const float*)d_in[20];
  const float* fc2_w2  = (const float*)d_in[21];
  const float* fc2_b2  = (const float*)d_in[22];
  const float* qkv_w[2] = {(const float*)d_in[23], (const float*)d_in[31]};
  const float* qkv_b[2] = {(const float*)d_in[24], (const float*)d_in[32]};
  const float* kln_w[2] = {(const float*)d_in[25], (const float*)d_in[33]};
  const float* kln_b[2] = {(const float*)d_in[26], (const float*)d_in[34]};
  const float* vln_w[2] = {(const float*)d_in[27], (const float*)d_in[35]};
  const float* vln_b[2] = {(const float*)d_in[28], (const float*)d_in[36]};
  const float* proj_w[2] = {(const float*)d_in[29], (const float*)d_in[37]};
  const float* proj_b[2] = {(const float*)d_in[30], (const float*)d_in[38]};
  const float* b2arr[2] = {out0_b2, out1_b2};

  char* wsp = (char*)d_ws; size_t off = 0;
  auto alloc = [&](size_t bytes)->void*{ void* p = wsp + off; off += (bytes + 255) & ~(size_t)255; return p; };
  __hip_bfloat16* featP = (__hip_bfloat16*)alloc(262144ull*2);
  __hip_bfloat16* zpage = (__hip_bfloat16*)alloc(256ull*2);
  __hip_bfloat16* wtb = (__hip_bfloat16*)alloc(2097152ull*2);
  __hip_bfloat16* P = (__hip_bfloat16*)alloc(5242880ull*2);
  float* mf     = (float*)alloc(65536ull*16*4);
  int*   mi     = (int*)alloc(65536ull*8*4);
  float* bil    = (float*)alloc(65536ull*3*4);
  float* kvpart = (float*)alloc(1024ull*4096*4);
  float* kv0    = (float*)alloc(4096ull*4);
  float* kv1    = (float*)alloc(4096ull*4);
  float* biasbuf= (float*)alloc(1536ull*4);
  float* lnbuf  = (float*)alloc(2048ull*4);
  float* bfold  = (float*)alloc(256ull*4);
  float* c1     = (float*)alloc(256ull*4);
  float* bkvh   = (float*)alloc(1024ull*4);
  float* part   = (float*)alloc(2ull*196608*4);
  __hip_bfloat16* wfoldT = (__hip_bfloat16*)alloc(65536ull*2);
  __hip_bfloat16* bufA = (__hip_bfloat16*)alloc(65536ull*256*2);
  __hip_bfloat16* bufB = (__hip_bfloat16*)alloc(65536ull*256*2);
  __hip_bfloat16* bufC = (__hip_bfloat16*)alloc(65536ull*256*2);
  if(off > ws_size) return;

  __hip_bfloat16* w2T[2]   = {wtb,          wtb + 65536};
  __hip_bfloat16* projT[2] = {wtb + 131072, wtb + 196608};
  __hip_bfloat16* fc1w1T   =  wtb + 262144;
  __hip_bfloat16* fc1w2T   =  wtb + 327680;
  __hip_bfloat16* fc2w1T   =  wtb + 393216;
  __hip_bfloat16* qT[2]    = {wtb + 458752, wtb + 655360};
  __hip_bfloat16* kvT[2]   = {wtb + 524288, wtb + 720896};
  __hip_bfloat16* wfreqT   =  wtb + 851968;   // 256 x 640
  __hip_bfloat16* wblkT    =  wtb + 1015808;  // 1280 x 256
  __hip_bfloat16* kvh2T[2] = {wtb + 1343488, wtb + 1474560};
  __hip_bfloat16* Ubuf     =  wtb + 1605632;
  __hip_bfloat16* M1T      =  wtb + 1671168;
  __hip_bfloat16* freqB = bufB;               // 4096 x 256

  k_conv1<<<1024,256,0,stream>>>(inp, enc_w, enc_b, featP);
  k_wfreq<<<256,256,0,stream>>>(freq_w, wfreqT);
  k_wblk<<<1280,256,0,stream>>>(out0_w1, out1_w1, wblkT);

  PrepArgs pa;
  pa.d[0]  = {out0_w2,   w2T[0],   0, 0};
  pa.d[1]  = {out1_w2,   w2T[1],   0, 0};
  pa.d[2]  = {proj_w[0], projT[0], 0, 0};
  pa.d[3]  = {proj_w[1], projT[1], 0, 0};
  pa.d[4]  = {fc1_w1,    fc1w1T,   0, 0};
  pa.d[5]  = {fc1_w2,    fc1w2T,   0, 0};
  pa.d[6]  = {fc2_w1,    fc2w1T,   0, 0};
  pa.d[7]  = {qkv_w[0],  qT[0],    1, 0};
  pa.d[8]  = {qkv_w[0],  kvT[0],   17, 0};
  pa.d[9]  = {qkv_w[0],  kvT[0]+65536, 33, 0};
  pa.d[10] = {qkv_w[1],  qT[1],    1, 0};
  pa.d[11] = {qkv_w[1],  kvT[1],   17, 0};
  pa.d[12] = {qkv_w[1],  kvT[1]+65536, 33, 0};
  k_prep<<<13*256,256,0,stream>>>(pa);
  k_biasperm<<<1,256,0,stream>>>(qkv_b[0], qkv_b[1],
      kln_w[0], kln_b[0], vln_w[0], vln_b[0], kln_w[1], kln_b[1], vln_w[1], vln_b[1],
      biasbuf, lnbuf, lnbuf + 1024, zpage);

  for(int br=0;br<2;br++){
    k_smallmmR<<<512,256,0,stream>>>(kvT[br], w2T[br], kvh2T[br]);
    k_bkv2R<<<2,256,0,stream>>>(b2arr[br], biasbuf + br*768 + 256, kvT[br], bkvh + br*512);
  }

  k_gfreq<<<64,256,0,stream>>>(featP, zpage, wfreqT, freq_b, freqB);
  k_gemm_mfma<0,0><<<320,512,0,stream>>>(freqB, wblkT, nullptr, nullptr,nullptr, P, 4096,1280,256, 1280);

  k_sample<<<256,256,0,stream>>>(coord, inp, mf, mi, bil);

  for(int br=0;br<2;br++){
    if(br==0) k_stage1<0><<<2048,256,0,stream>>>(P, mf, mi, coord, cell, out0_w1, out0_b1, bufA);
    else      k_stage1<1><<<2048,256,0,stream>>>(P, mf, mi, coord, cell, out1_w1, out1_b1, bufA);
    k_kvln<<<2048,512,0,stream>>>(bufA, kvh2T[br], bkvh + br*512, lnbuf + br*512, lnbuf + 1024 + br*512, kvpart);
    float* kvf = br ? kv1 : kv0;
    k_kvred<<<256,256,0,stream>>>(kvpart, kvf);
    k_fold<<<256,256,0,stream>>>(qT[br], biasbuf + br*768, kvf, wfoldT, bfold);
    k_smallmm<1><<<256,256,0,stream>>>(wfoldT, w2T[br], Ubuf);
    k_smallmm<0><<<256,256,0,stream>>>(projT[br], Ubuf, M1T);
    k_cvec<<<1,256,0,stream>>>(b2arr[br], bfold, wfoldT, projT[br], proj_b[br], c1);
    if(br==0)
      k_gemm12<0><<<1024,512,0,stream>>>(bufA, M1T, c1, w2T[0], b2arr[0], nullptr, bufC);
    else
      k_gemm12<1><<<1024,512,0,stream>>>(bufA, M1T, c1, w2T[1], b2arr[1], bufC, bufC);
  }
  // fc tail: bufC = f
  k_gemm_mfma<1,0><<<1024,512,0,stream>>>(bufC, fc1w1T, fc1_b1, nullptr,nullptr, bufA, 65536,256,256, 256);
  k_gemm_mfma<1,1><<<1024,512,0,stream>>>(bufA, fc1w2T, fc1_b2, bufC, nullptr, bufB, 65536,256,256, 256);
  k_gemmF<<<1024,512,0,stream>>>(bufB, fc2w1T, fc2_b1, fc2_w2, part);
  k_combine<<<768,256,0,stream>>>(part, fc2_b2, bil, (float*)d_out);
}

// Round 20
// 439.636 us; speedup vs baseline: 1.3648x; 1.0644x over previous
//
#include <hip/hip_runtime.h>
#include <hip/hip_bf16.h>

#define DI __device__ __forceinline__

DI float gelu_f(float x){ return 0.5f*x*(1.0f + erff(x*0.7071067811865476f)); }
DI float bf2f(__hip_bfloat16 b){ return __bfloat162float(b); }
DI __hip_bfloat16 f2bf(float f){ return __float2bfloat16(f); }
DI float bflo(unsigned u){ return __uint_as_float(u<<16); }
DI float bfhi(unsigned u){ return __uint_as_float(u & 0xffff0000u); }
DI unsigned pack2bf(float a, float b){
  __hip_bfloat16 ha = f2bf(a), hb = f2bf(b);
  unsigned short ua = *reinterpret_cast<unsigned short*>(&ha);
  unsigned short ub = *reinterpret_cast<unsigned short*>(&hb);
  return (unsigned)ua | ((unsigned)ub<<16);
}

typedef __attribute__((ext_vector_type(8))) short bf16x8;
typedef __attribute__((ext_vector_type(4))) float f32x4;

template<typename T>
DI void load_lds16(const T* g, T* l){
  __builtin_amdgcn_global_load_lds((const __attribute__((address_space(1))) void*)g,
                                   (__attribute__((address_space(3))) void*)l, 16, 0, 0);
}

DI int kvmap(int j){ int h=j>>5, idx=j&31; return idx<16 ? h*16+idx : 256+h*16+(idx-16); }

// ---------------- conv1 ----------------
__global__ __launch_bounds__(256) void k_conv1(const float* __restrict__ inp, const float* __restrict__ w,
                                               const float* __restrict__ b, __hip_bfloat16* __restrict__ featP){
  int idx = blockIdx.x*256 + threadIdx.x;
  int o = idx & 63, p = idx >> 6, y = p >> 6, x = p & 63;
  float acc = b[o];
  #pragma unroll
  for(int c=0;c<3;c++){
    #pragma unroll
    for(int ky=0;ky<3;ky++){
      int yy = y+ky-1; if((unsigned)yy >= 64u) continue;
      #pragma unroll
      for(int kx=0;kx<3;kx++){
        int xx = x+kx-1; if((unsigned)xx >= 64u) continue;
        acc += inp[c*4096 + yy*64 + xx] * w[o*27 + c*9 + ky*3 + kx];
      }
    }
  }
  featP[p*64 + o] = f2bf(acc);
}

// ---------------- wfreq permute ----------------
__global__ __launch_bounds__(256) void k_wfreq(const float* __restrict__ fw, __hip_bfloat16* __restrict__ wt){
  int o = blockIdx.x, t = threadIdx.x;
  #pragma unroll
  for(int it=0; it<3; it++){
    int k = it*256 + t;
    if(k >= 640) break;
    float v = 0.0f;
    if(k < 576){
      int tap = k>>6, c = k&63;
      v = fw[o*576 + c*9 + tap];
    }
    wt[(size_t)o*640 + k] = f2bf(v);
  }
}

// ---------------- wblkT ----------------
__global__ __launch_bounds__(256) void k_wblk(const float* __restrict__ w0, const float* __restrict__ w1,
                                              __hip_bfloat16* __restrict__ wt){
  int j = blockIdx.x, kk = threadIdx.x;
  float v;
  if(j < 1024){
    int s = j>>8, n = j&255;
    v = w0[(8 + 256*s + kk)*256 + n];
  } else {
    v = w1[(2 + kk)*256 + (j-1024)];
  }
  wt[(size_t)j*256 + kk] = f2bf(v);
}

// ---------------- batched weight transpose / qkv head-permute ----------------
struct PrepDesc { const float* src; __hip_bfloat16* dst; int mode; int pad; };
struct PrepArgs { PrepDesc d[13]; };
__global__ __launch_bounds__(256) void k_prep(PrepArgs a){
  int u = blockIdx.x >> 8, b = blockIdx.x & 255, t = threadIdx.x;
  PrepDesc d = a.d[u];
  float v;
  if(d.mode == 0) v = d.src[t*256 + b];
  else { int col = 48*(b>>4) + (d.mode-1) + (b&15); v = d.src[t*768 + col]; }
  d.dst[b*256 + t] = f2bf(v);
}

// permuted qkv biases + reordered LN params + zero guard page
__global__ __launch_bounds__(256) void k_biasperm(const float* __restrict__ b0, const float* __restrict__ b1,
    const float* kw0, const float* kb0, const float* vw0, const float* vb0,
    const float* kw1, const float* kb1, const float* vw1, const float* vb1,
    float* __restrict__ dstB, float* __restrict__ lnw2, float* __restrict__ lnb2,
    __hip_bfloat16* __restrict__ zpage){
  int t = threadIdx.x;
  zpage[t] = f2bf(0.0f);
  #pragma unroll
  for(int br=0;br<2;br++){
    const float* s = br ? b1 : b0;
    #pragma unroll
    for(int part=0;part<3;part++)
      dstB[br*768 + part*256 + t] = s[48*(t>>4) + part*16 + (t&15)];
  }
  #pragma unroll
  for(int br=0;br<2;br++){
    #pragma unroll
    for(int half=0;half<2;half++){
      int j = half*256 + t;
      int h = j>>5, idx = j&31;
      bool isK = idx<16;
      int c = isK ? idx : idx-16;
      const float* w = isK ? (br?kw1:kw0) : (br?vw1:vw0);
      const float* bb= isK ? (br?kb1:kb0) : (br?vb1:vb0);
      lnw2[br*512 + j] = w[h*16+c];
      lnb2[br*512 + j] = bb[h*16+c];
    }
  }
}

// ---------------- batched small matmul pair: C = (A[+I]) @ B for both branches ----------------
template<int ADDI>
__global__ __launch_bounds__(256) void k_smallmm2(
    const __hip_bfloat16* __restrict__ A0, const __hip_bfloat16* __restrict__ A1,
    const __hip_bfloat16* __restrict__ B0, const __hip_bfloat16* __restrict__ B1,
    __hip_bfloat16* __restrict__ C0, __hip_bfloat16* __restrict__ C1){
  __shared__ float ar[256];
  int br = blockIdx.x >> 8, i = blockIdx.x & 255, t = threadIdx.x;
  const __hip_bfloat16* A = br ? A1 : A0;
  const __hip_bfloat16* B = br ? B1 : B0;
  __hip_bfloat16* C = br ? C1 : C0;
  float a = bf2f(A[(size_t)i*256 + t]);
  if(ADDI && t==i) a += 1.0f;
  ar[t] = a;
  __syncthreads();
  float a0=0.f,a1=0.f,a2=0.f,a3=0.f;
  for(int l=0;l<256;l+=4){
    a0 += ar[l+0]*bf2f(B[(l+0)*256 + t]);
    a1 += ar[l+1]*bf2f(B[(l+1)*256 + t]);
    a2 += ar[l+2]*bf2f(B[(l+2)*256 + t]);
    a3 += ar[l+3]*bf2f(B[(l+3)*256 + t]);
  }
  C[(size_t)i*256 + t] = f2bf((a0+a1)+(a2+a3));
}

// reordered composition (both branches): C[j] = kvT[kvmap(j)] @ B
__global__ __launch_bounds__(256) void k_smallmmR2(
    const __hip_bfloat16* __restrict__ A0, const __hip_bfloat16* __restrict__ A1,
    const __hip_bfloat16* __restrict__ B0, const __hip_bfloat16* __restrict__ B1,
    __hip_bfloat16* __restrict__ C0, __hip_bfloat16* __restrict__ C1){
  __shared__ float ar[256];
  int br = blockIdx.x >> 9, j = blockIdx.x & 511, t = threadIdx.x;
  const __hip_bfloat16* A = br ? A1 : A0;
  const __hip_bfloat16* B = br ? B1 : B0;
  __hip_bfloat16* C = br ? C1 : C0;
  int src = kvmap(j);
  ar[t] = bf2f(A[(size_t)src*256 + t]);
  __syncthreads();
  float a0=0.f,a1=0.f,a2=0.f,a3=0.f;
  for(int l=0;l<256;l+=4){
    a0 += ar[l+0]*bf2f(B[(l+0)*256 + t]);
    a1 += ar[l+1]*bf2f(B[(l+1)*256 + t]);
    a2 += ar[l+2]*bf2f(B[(l+2)*256 + t]);
    a3 += ar[l+3]*bf2f(B[(l+3)*256 + t]);
  }
  C[(size_t)j*256 + t] = f2bf((a0+a1)+(a2+a3));
}

__global__ __launch_bounds__(256) void k_bkv2R2(const float* __restrict__ b20, const float* __restrict__ b21,
    const float* __restrict__ biaskv,
    const __hip_bfloat16* __restrict__ kvT0, const __hip_bfloat16* __restrict__ kvT1,
    float* __restrict__ outb){
  __shared__ float s_b2[256];
  int br = blockIdx.x >> 1, nb = blockIdx.x & 1, t = threadIdx.x;
  int n = nb*256 + t;
  const float* b2 = br ? b21 : b20;
  const __hip_bfloat16* kvT_ = br ? kvT1 : kvT0;
  int src = kvmap(n);
  s_b2[t] = b2[t];
  __syncthreads();
  float v = biaskv[br*768 + 256 + src];
  for(int l=0;l<256;l++) v += s_b2[l]*bf2f(kvT_[(size_t)src*256 + l]);
  outb[br*512 + n] = v;
}

// ---------------- c1 (both branches) ----------------
__global__ __launch_bounds__(256) void k_cvec2(const float* __restrict__ b20, const float* __restrict__ b21,
    const float* __restrict__ bfold,
    const __hip_bfloat16* __restrict__ WfoldT,
    const __hip_bfloat16* __restrict__ projT0, const __hip_bfloat16* __restrict__ projT1,
    const float* __restrict__ bp0, const float* __restrict__ bp1, float* __restrict__ c1){
  __shared__ float s_b2[256], s_r[256];
  int br = blockIdx.x, t = threadIdx.x;
  const float* b2 = br ? b21 : b20;
  const __hip_bfloat16* Wf = WfoldT + (size_t)br*65536;
  const __hip_bfloat16* pj = br ? projT1 : projT0;
  const float* bp = br ? bp1 : bp0;
  s_b2[t] = b2[t];
  __syncthreads();
  float r = s_b2[t] + bfold[br*256 + t];
  for(int l=0;l<256;l++) r += s_b2[l]*bf2f(Wf[(size_t)t*256 + l]);
  s_r[t] = r;
  __syncthreads();
  float c = bp[t];
  for(int l=0;l<256;l++) c += s_r[l]*bf2f(pj[(size_t)t*256 + l]);
  c1[br*256 + t] = c;
}

// ---------------- per-query sampling geometry + result_bil ----------------
__global__ __launch_bounds__(256) void k_sample(const float* __restrict__ coord, const float* __restrict__ inp,
    float* __restrict__ mf, int* __restrict__ mi, float* __restrict__ bil){
  int q = blockIdx.x*256 + threadIdx.x;
  float cy = coord[2*q], cx = coord[2*q+1];
  const float LO = (float)(-1.0 + 1e-6), HI = (float)(1.0 - 1e-6);
  const float ONEG = (float)(-1.0/64.0 + 1e-6), OPOS = (float)(1.0/64.0 + 1e-6);
  float areas[4];
  #pragma unroll
  for(int s=0;s<4;s++){
    float oy = (s<2)?ONEG:OPOS;
    float ox = (s&1)?OPOS:ONEG;
    float csy = fminf(fmaxf(cy+oy, LO), HI);
    float csx = fminf(fmaxf(cx+ox, LO), HI);
    float fy = ((csy+1.0f)*64.0f - 1.0f)*0.5f;
    float fx = ((csx+1.0f)*64.0f - 1.0f)*0.5f;
    int iy = (int)rintf(fy); iy = iy<0?0:(iy>63?63:iy);
    int ix = (int)rintf(fx); ix = ix<0?0:(ix>63?63:ix);
    float qcy = -1.0f + (float)(2*iy+1)*0.015625f;
    float qcx = -1.0f + (float)(2*ix+1)*0.015625f;
    float ry = (cy-qcy)*64.0f, rx = (cx-qcx)*64.0f;
    mf[q*16 + 4 + 2*s] = ry; mf[q*16 + 5 + 2*s] = rx;
    areas[s] = fabsf(ry*rx) + 1e-9f;
    mi[q*8 + s] = iy*64 + ix;
  }
  float tot = areas[0]+areas[1]+areas[2]+areas[3];
  #pragma unroll
  for(int s=0;s<4;s++) mf[q*16 + s] = areas[3-s] / tot;

  float fy = ((cy+1.0f)*64.0f - 1.0f)*0.5f;
  float fx = ((cx+1.0f)*64.0f - 1.0f)*0.5f;
  {
    float y0 = floorf(fy), x0 = floorf(fx);
    float wy = fy-y0, wx = fx-x0;
    int y0i = (int)y0, x0i = (int)x0;
    float cw[4] = {(1.0f-wy)*(1.0f-wx), (1.0f-wy)*wx, wy*(1.0f-wx), wy*wx};
    #pragma unroll
    for(int c2=0;c2<4;c2++){
      int yi = y0i + (c2>>1), xi = x0i + (c2&1);
      bool ok = (yi>=0 && yi<64 && xi>=0 && xi<64);
      int yc = yi<0?0:(yi>63?63:yi), xc = xi<0?0:(xi>63?63:xi);
      mf[q*16 + 12 + c2] = ok ? cw[c2] : 0.0f;
      mi[q*8 + 4 + c2] = yc*64 + xc;
    }
  }
  {
    float fyb = fminf(fmaxf(fy, 0.0f), 63.0f);
    float fxb = fminf(fmaxf(fx, 0.0f), 63.0f);
    float y0 = floorf(fyb), x0 = floorf(fxb);
    float wy = fyb-y0, wx = fxb-x0;
    int y0i = (int)y0, x0i = (int)x0;
    float cw[4] = {(1.0f-wy)*(1.0f-wx), (1.0f-wy)*wx, wy*(1.0f-wx), wy*wx};
    float a0=0,a1=0,a2=0;
    #pragma unroll
    for(int c2=0;c2<4;c2++){
      int yi = y0i + (c2>>1), xi = x0i + (c2&1);
      if(yi>=0 && yi<64 && xi>=0 && xi<64){
        int idx = yi*64+xi; float wgt = cw[c2];
        a0 += inp[idx]*wgt; a1 += inp[4096+idx]*wgt; a2 += inp[8192+idx]*wgt;
      }
    }
    bil[q*3+0]=a0; bil[q*3+1]=a1; bil[q*3+2]=a2;
  }
}

// ---------------- stage-1 MLP via P-gather, both branches in one launch ----------------
__global__ __launch_bounds__(256) void k_stage1both(const __hip_bfloat16* __restrict__ P, const float* __restrict__ mf,
    const int* __restrict__ mi, const float* __restrict__ coord, const float* __restrict__ cell,
    const float* __restrict__ W1_0, const float* __restrict__ b1_0,
    const float* __restrict__ W1_1, const float* __restrict__ b1_1,
    __hip_bfloat16* __restrict__ outA0, __hip_bfloat16* __restrict__ outA1){
  __shared__ float wsm[11][256];
  const int br = blockIdx.x >> 11;
  const int blk = blockIdx.x & 2047;
  int j = threadIdx.x;
  if(br==0){
    #pragma unroll
    for(int r=0;r<8;r++) wsm[r][j] = W1_0[r*256 + j];
    wsm[8][j] = W1_0[1032*256 + j];
    wsm[9][j] = W1_0[1033*256 + j];
    wsm[10][j] = b1_0[j];
  } else {
    wsm[0][j] = W1_1[0*256 + j];
    wsm[1][j] = W1_1[1*256 + j];
    wsm[2][j] = W1_1[258*256 + j];
    wsm[3][j] = W1_1[259*256 + j];
    wsm[4][j] = b1_1[j];
  }
  __hip_bfloat16* out = br ? outA1 : outA0;
  __syncthreads();
  int q0 = blk*32;
  for(int qq=0;qq<32;qq++){
    int q = q0+qq;
    float acc;
    const float* m = mf + q*16;
    const int* ii = mi + q*8;
    if(br==0){
      acc = wsm[10][j];
      #pragma unroll
      for(int r=0;r<8;r++) acc += m[4+r]*wsm[r][j];
      float cly = cell[2*q]*64.0f, clx = cell[2*q+1]*64.0f;
      acc += cly*wsm[8][j] + clx*wsm[9][j];
      #pragma unroll
      for(int s=0;s<4;s++) acc += m[s]*bf2f(P[(size_t)ii[s]*1280 + s*256 + j]);
    } else {
      acc = wsm[4][j];
      float cy = coord[2*q], cx = coord[2*q+1];
      float cly = cell[2*q]*64.0f, clx = cell[2*q+1]*64.0f;
      acc += cy*wsm[0][j] + cx*wsm[1][j] + cly*wsm[2][j] + clx*wsm[3][j];
      #pragma unroll
      for(int c2=0;c2<4;c2++) acc += m[12+c2]*bf2f(P[(size_t)ii[4+c2]*1280 + 1024 + j]);
    }
    out[(size_t)q*256 + j] = f2bf(gelu_f(acc));
  }
}

// ---------------- MFMA bf16 GEMM v4: 8 waves, 34 KB LDS, half-tile epilogue ----------------
template<int ACT,int NRES>
__global__ __launch_bounds__(512) void k_gemm_mfma(
    const __hip_bfloat16* __restrict__ A, const __hip_bfloat16* __restrict__ BT,
    const float* __restrict__ bias, const __hip_bfloat16* __restrict__ R1,
    const __hip_bfloat16* __restrict__ R2, __hip_bfloat16* __restrict__ C,
    int M, int N, int K, int ldc){
  __shared__ __align__(1024) char smem[64*133*4];
  const int t = threadIdx.x, wave = t>>6, lane = t&63;
  const int MT = M>>7, NT = N>>7;
  const int b = blockIdx.x, xcd = b&7, i = b>>3;
  const int nt = i % NT, mtl = i / NT;
  const int m0 = (xcd*(MT>>3) + mtl) << 7, n0 = nt << 7;
  const int wr = (wave>>2)*64, wc = (wave&3)*32;
  const int lr = lane&15, lh = lane>>4;

  f32x4 acc[4][2] = {};
  const int ntiles = K>>6;
  for(int kt=0; kt<ntiles; ++kt){
    __syncthreads();
    #pragma unroll
    for(int q2=0;q2<2;q2++){
      int c = (wave*2+q2)*64 + lane;
      int row = c>>3; int k8 = (c&7) ^ (row&7);
      __hip_bfloat16* la = (__hip_bfloat16*)smem + (size_t)(wave*2+q2)*512;
      __hip_bfloat16* lb = (__hip_bfloat16*)(smem + 16384) + (size_t)(wave*2+q2)*512;
      load_lds16(A  + (size_t)(m0+row)*K + (kt*64 + k8*8), la);
      load_lds16(BT + (size_t)(n0+row)*K + (kt*64 + k8*8), lb);
    }
    __syncthreads();
    const __hip_bfloat16* Ab = (const __hip_bfloat16*)smem;
    const __hip_bfloat16* Bb = (const __hip_bfloat16*)(smem + 16384);
    #pragma unroll
    for(int kk=0;kk<2;kk++){
      bf16x8 af[4], bfr[2];
      #pragma unroll
      for(int m=0;m<4;m++){
        int row = wr + m*16 + lr;
        int p = (kk*4 + lh) ^ (row&7);
        af[m] = *reinterpret_cast<const bf16x8*>(Ab + row*64 + p*8);
      }
      #pragma unroll
      for(int n=0;n<2;n++){
        int row = wc + n*16 + lr;
        int p = (kk*4 + lh) ^ (row&7);
        bfr[n] = *reinterpret_cast<const bf16x8*>(Bb + row*64 + p*8);
      }
      #pragma unroll
      for(int m=0;m<4;m++)
        #pragma unroll
        for(int n=0;n<2;n++)
          acc[m][n] = __builtin_amdgcn_mfma_f32_16x16x32_bf16(af[m], bfr[n], acc[m][n], 0,0,0);
    }
  }

  float* epi = (float*)smem;
  #pragma unroll
  for(int hf=0; hf<2; ++hf){
    __syncthreads();
    if((wave>>2) == hf){
      #pragma unroll
      for(int m=0;m<4;m++)
        #pragma unroll
        for(int n=0;n<2;n++){
          int col = wc + n*16 + lr;
          #pragma unroll
          for(int j=0;j<4;j++)
            epi[(m*16 + lh*4 + j)*133 + col] = acc[m][n][j];
        }
    }
    __syncthreads();
    const int lrow = t>>3, c0 = (t&7)*16;
    const size_t grow = (size_t)(m0 + hf*64 + lrow);
    const float* er = epi + lrow*133;
    #pragma unroll
    for(int half=0; half<2; half++){
      int cb = c0 + half*8;
      int gc = n0 + cb;
      float v[8];
      #pragma unroll
      for(int e=0;e<8;e++) v[e] = er[cb+e];
      if(bias){
        #pragma unroll
        for(int e=0;e<8;e++) v[e] += bias[gc+e];
      }
      if(ACT==1){
        #pragma unroll
        for(int e=0;e<8;e++) v[e] = gelu_f(v[e]);
      }
      if(NRES==1 || NRES==2){
        uint4 r = *reinterpret_cast<const uint4*>(R1 + grow*ldc + gc);
        unsigned rw[4] = {r.x,r.y,r.z,r.w};
        #pragma unroll
        for(int q2=0;q2<4;q2++){ v[2*q2] += bflo(rw[q2]); v[2*q2+1] += bfhi(rw[q2]); }
      }
      if(NRES==2){
        uint4 r = *reinterpret_cast<const uint4*>(R2 + grow*ldc + gc);
        unsigned rw[4] = {r.x,r.y,r.z,r.w};
        #pragma unroll
        for(int q2=0;q2<4;q2++){ v[2*q2] += bflo(rw[q2]); v[2*q2+1] += bfhi(rw[q2]); }
      }
      uint4 o;
      o.x = pack2bf(v[0],v[1]); o.y = pack2bf(v[2],v[3]);
      o.z = pack2bf(v[4],v[5]); o.w = pack2bf(v[6],v[7]);
      *reinterpret_cast<uint4*>(C + grow*ldc + gc) = o;
    }
  }
}

// ---------------- freq conv GEMM (4-wave) ----------------
__global__ __launch_bounds__(256) void k_gfreq(
    const __hip_bfloat16* __restrict__ featP, const __hip_bfloat16* __restrict__ zpage,
    const __hip_bfloat16* __restrict__ BT, const float* __restrict__ bias,
    __hip_bfloat16* __restrict__ C){
  __shared__ __align__(1024) char smem[64*133*4];
  const int t = threadIdx.x, wave = t>>6, lane = t&63;
  const int MT = 32, NT = 2;
  const int b = blockIdx.x, xcd = b&7, i = b>>3;
  const int nt = i % NT, mtl = i / NT;
  const int m0 = (xcd*(MT>>3) + mtl) << 7, n0 = nt << 7;
  const int wr = (wave>>1)*64, wc = (wave&1)*64;
  const int lr = lane&15, lh = lane>>4;

  f32x4 acc[4][4] = {};
  for(int kt=0; kt<9; ++kt){
    int ky = kt/3, kx = kt - ky*3;
    __syncthreads();
    #pragma unroll
    for(int q2=0;q2<4;q2++){
      int c = (wave*4+q2)*64 + lane;
      int row = c>>3; int k8 = (c&7) ^ (row&7);
      __hip_bfloat16* la = (__hip_bfloat16*)smem + (size_t)(wave*4+q2)*512;
      __hip_bfloat16* lb = (__hip_bfloat16*)(smem + 16384) + (size_t)(wave*4+q2)*512;
      int pix = m0+row, y = pix>>6, x = pix&63;
      int yy = y+ky-1, xx = x+kx-1;
      const __hip_bfloat16* src = ((unsigned)yy<64u && (unsigned)xx<64u) ?
          (featP + (size_t)(yy*64+xx)*64 + k8*8) : (zpage + k8*8);
      load_lds16(src, la);
      load_lds16(BT + (size_t)(n0+row)*640 + (kt*64 + k8*8), lb);
    }
    __syncthreads();
    const __hip_bfloat16* Ab = (const __hip_bfloat16*)smem;
    const __hip_bfloat16* Bb = (const __hip_bfloat16*)(smem + 16384);
    #pragma unroll
    for(int kk=0;kk<2;kk++){
      bf16x8 af[4], bfr[4];
      #pragma unroll
      for(int m=0;m<4;m++){
        int row = wr + m*16 + lr;
        int p = (kk*4 + lh) ^ (row&7);
        af[m] = *reinterpret_cast<const bf16x8*>(Ab + row*64 + p*8);
      }
      #pragma unroll
      for(int n=0;n<4;n++){
        int row = wc + n*16 + lr;
        int p = (kk*4 + lh) ^ (row&7);
        bfr[n] = *reinterpret_cast<const bf16x8*>(Bb + row*64 + p*8);
      }
      #pragma unroll
      for(int m=0;m<4;m++)
        #pragma unroll
        for(int n=0;n<4;n++)
          acc[m][n] = __builtin_amdgcn_mfma_f32_16x16x32_bf16(af[m], bfr[n], acc[m][n], 0,0,0);
    }
  }

  float* epi = (float*)smem;
  const int cg = t&3;
  #pragma unroll
  for(int hf=0; hf<2; ++hf){
    __syncthreads();
    if((wave>>1) == hf){
      #pragma unroll
      for(int m=0;m<4;m++)
        #pragma unroll
        for(int n=0;n<4;n++){
          int col = wc + n*16 + lr;
          #pragma unroll
          for(int j=0;j<4;j++)
            epi[(m*16 + lh*4 + j)*133 + col] = acc[m][n][j];
        }
    }
    __syncthreads();
    const int lrow = t>>2, c0 = cg*32;
    const size_t grow = (size_t)(m0 + hf*64 + lrow);
    const float* er = epi + lrow*133;
    #pragma unroll
    for(int g0=0; g0<4; g0++){
      int g = (g0 + cg) & 3;
      int cb = c0 + g*8;
      int gc = n0 + cb;
      float v[8];
      #pragma unroll
      for(int e=0;e<8;e++) v[e] = er[cb+e] + bias[gc+e];
      uint4 o;
      o.x = pack2bf(v[0],v[1]); o.y = pack2bf(v[2],v[3]);
      o.z = pack2bf(v[4],v[5]); o.w = pack2bf(v[6],v[7]);
      *reinterpret_cast<uint4*>(C + grow*256 + gc) = o;
    }
  }
}

// ---------------- fused kv (8 waves, both branches): GEMM + LN + split-K head outer product ----------------
__global__ __launch_bounds__(512) void k_kvlnboth(
    const __hip_bfloat16* __restrict__ A0, const __hip_bfloat16* __restrict__ A1,
    const __hip_bfloat16* __restrict__ BT0, const __hip_bfloat16* __restrict__ BT1,
    const float* __restrict__ biasAll, const float* __restrict__ lnwAll, const float* __restrict__ lnbAll,
    float* __restrict__ kvpart){
  __shared__ __align__(1024) char smem[34816];
  const int t = threadIdx.x, wave = t>>6, lane = t&63;
  const int MT = 512, NT = 4;
  const int br = blockIdx.x >> 11;
  const int b = blockIdx.x & 2047, xcd = b&7, i = b>>3;
  const int nt = i % NT, mtl = i / NT;
  const int m0 = (xcd*(MT>>3) + mtl) << 7, n0 = nt << 7;
  const int wr = (wave>>2)*64, wc = (wave&3)*32;
  const int lr = lane&15, lh = lane>>4;
  const __hip_bfloat16* A = br ? A1 : A0;
  const __hip_bfloat16* BT = br ? BT1 : BT0;
  const float* bias = biasAll + br*512;
  const float* lnw = lnwAll + br*512;
  const float* lnb = lnbAll + br*512;

  f32x4 acc[4][2] = {};
  for(int kt=0; kt<4; ++kt){
    __syncthreads();
    #pragma unroll
    for(int q2=0;q2<2;q2++){
      int c = (wave*2+q2)*64 + lane;
      int row = c>>3; int k8 = (c&7) ^ (row&7);
      __hip_bfloat16* la = (__hip_bfloat16*)smem + (size_t)(wave*2+q2)*512;
      __hip_bfloat16* lb = (__hip_bfloat16*)(smem + 16384) + (size_t)(wave*2+q2)*512;
      load_lds16(A  + (size_t)(m0+row)*256 + (kt*64 + k8*8), la);
      load_lds16(BT + (size_t)(n0+row)*256 + (kt*64 + k8*8), lb);
    }
    __syncthreads();
    const __hip_bfloat16* Ab = (const __hip_bfloat16*)smem;
    const __hip_bfloat16* Bb = (const __hip_bfloat16*)(smem + 16384);
    #pragma unroll
    for(int kk=0;kk<2;kk++){
      bf16x8 af[4], bfr[2];
      #pragma unroll
      for(int m=0;m<4;m++){
        int row = wr + m*16 + lr;
        int p = (kk*4 + lh) ^ (row&7);
        af[m] = *reinterpret_cast<const bf16x8*>(Ab + row*64 + p*8);
      }
      #pragma unroll
      for(int n=0;n<2;n++){
        int row = wc + n*16 + lr;
        int p = (kk*4 + lh) ^ (row&7);
        bfr[n] = *reinterpret_cast<const bf16x8*>(Bb + row*64 + p*8);
      }
      #pragma unroll
      for(int m=0;m<4;m++)
        #pragma unroll
        for(int n=0;n<2;n++)
          acc[m][n] = __builtin_amdgcn_mfma_f32_16x16x32_bf16(af[m], bfr[n], acc[m][n], 0,0,0);
    }
  }
  __syncthreads();

  __hip_bfloat16* knT = (__hip_bfloat16*)smem;            // [4 heads][16 cols][136 rows]
  __hip_bfloat16* vnT = (__hip_bfloat16*)(smem + 17408);
  #pragma unroll
  for(int m=0;m<4;m++){
    #pragma unroll
    for(int n=0;n<2;n++){
      int cl = wc + n*16 + lr;
      int gcol = n0 + cl;
      float bs = bias[gcol];
      int h2 = cl>>5, isV = (cl>>4)&1;
      short4 pk;
      #pragma unroll
      for(int j=0;j<4;j++) ((__hip_bfloat16*)&pk)[j] = f2bf(acc[m][n][j] + bs);
      int r = wr + m*16 + lh*4;
      __hip_bfloat16* dst = (isV ? vnT : knT) + (h2*16 + lr)*136 + r;
      *reinterpret_cast<short4*>(dst) = pk;
    }
  }
  __syncthreads();
  #pragma unroll
  for(int i4=0; i4<2; ++i4){
    int task = i4*512 + t;
    int r = task & 127, hv = task >> 7;
    int h2 = hv >> 1, isV = hv & 1;
    __hip_bfloat16* base = (isV ? vnT : knT) + (h2*16)*136 + r;
    float xs[16];
    float s=0.0f, s2=0.0f;
    #pragma unroll
    for(int c=0;c<16;c++){ xs[c] = bf2f(base[c*136]); s += xs[c]; s2 += xs[c]*xs[c]; }
    float mean = s*0.0625f;
    float var = (s2 - 16.0f*mean*mean)*(1.0f/15.0f); var = var<0.0f?0.0f:var;
    float inv = 1.0f/(sqrtf(var) + 1e-5f);
    int gbase = n0 + h2*32 + isV*16;
    #pragma unroll
    for(int c=0;c<16;c++)
      base[c*136] = f2bf(lnw[gbase+c]*((xs[c]-mean)*inv) + lnb[gbase+c]);
  }
  __syncthreads();
  {
    const int hloc = wave>>1, kh = wave&1;
    f32x4 kacc = {};
    #pragma unroll
    for(int kk=0;kk<2;kk++){
      int off = kh*64 + kk*32 + lh*8;
      bf16x8 af  = *reinterpret_cast<const bf16x8*>(knT + (hloc*16 + lr)*136 + off);
      bf16x8 bf_ = *reinterpret_cast<const bf16x8*>(vnT + (hloc*16 + lr)*136 + off);
      kacc = __builtin_amdgcn_mfma_f32_16x16x32_bf16(af, bf_, kacc, 0,0,0);
    }
    const int mt = m0>>7;
    const int hglob = nt*4 + hloc;
    #pragma unroll
    for(int j=0;j<4;j++)
      kvpart[((size_t)br*1024 + (size_t)mt*2 + kh)*4096 + hglob*256 + (lh*4+j)*16 + lr] = kacc[j];
  }
}

// ---------------- G12 fused v3 (8 waves) ----------------
template<int NRES>
__global__ __launch_bounds__(512) void k_gemm12(
    const __hip_bfloat16* __restrict__ A, const __hip_bfloat16* __restrict__ B1T,
    const float* __restrict__ c1, const __hip_bfloat16* __restrict__ B2T,
    const float* __restrict__ b2, const __hip_bfloat16* __restrict__ R,
    __hip_bfloat16* __restrict__ C){
  __shared__ __align__(1024) char smem[49152];
  const int t = threadIdx.x, wave = t>>6, lane = t&63;
  const int MT = 512, NT = 2;
  const int b = blockIdx.x, xcd = b&7, i = b>>3;
  const int nt = i % NT, mtl = i / NT;
  const int m0 = (xcd*(MT>>3) + mtl) << 7, n0 = nt << 7;
  const int wr = (wave>>2)*64, wc = (wave&3)*32;
  const int lr = lane&15, lh = lane>>4;
  f32x4 acc1[4][2] = {}, acc2[4][2] = {};
  for(int k0=0;k0<256;k0+=64){
    __syncthreads();
    #pragma unroll
    for(int q2=0;q2<2;q2++){
      int c = (wave*2+q2)*64 + lane;
      int row = c>>3; int k8 = (c&7) ^ (row&7);
      __hip_bfloat16* base = (__hip_bfloat16*)smem + (size_t)(wave*2+q2)*512;
      load_lds16(A   + (size_t)(m0+row)*256 + (k0 + k8*8), base);
      load_lds16(B1T + (size_t)(n0+row)*256 + (k0 + k8*8), base + 8192);
      load_lds16(B2T + (size_t)(n0+row)*256 + (k0 + k8*8), base + 16384);
    }
    __syncthreads();
    const __hip_bfloat16* Ab = (const __hip_bfloat16*)smem;
    #pragma unroll
    for(int kk=0;kk<2;kk++){
      bf16x8 af[4], bfr[2];
      #pragma unroll
      for(int m=0;m<4;m++){
        int row = wr + m*16 + lr;
        int p = (kk*4 + lh) ^ (row&7);
        af[m] = *reinterpret_cast<const bf16x8*>(Ab + row*64 + p*8);
      }
      #pragma unroll
      for(int n=0;n<2;n++){
        int row = wc + n*16 + lr;
        int p = (kk*4 + lh) ^ (row&7);
        bfr[n] = *reinterpret_cast<const bf16x8*>(Ab + 8192 + row*64 + p*8);
      }
      #pragma unroll
      for(int m=0;m<4;m++)
        #pragma unroll
        for(int n=0;n<2;n++)
          acc1[m][n] = __builtin_amdgcn_mfma_f32_16x16x32_bf16(af[m], bfr[n], acc1[m][n], 0,0,0);
      #pragma unroll
      for(int n=0;n<2;n++){
        int row = wc + n*16 + lr;
        int p = (kk*4 + lh) ^ (row&7);
        bfr[n] = *reinterpret_cast<const bf16x8*>(Ab + 16384 + row*64 + p*8);
      }
      #pragma unroll
      for(int m=0;m<4;m++)
        #pragma unroll
        for(int n=0;n<2;n++)
          acc2[m][n] = __builtin_amdgcn_mfma_f32_16x16x32_bf16(af[m], bfr[n], acc2[m][n], 0,0,0);
    }
  }
  float* epi = (float*)smem;
  #pragma unroll
  for(int hf=0; hf<2; ++hf){
    const int lrow = t>>3, c0 = (t&7)*16;
    const size_t grow = (size_t)(m0 + hf*64 + lrow);
    float v1[16];
    __syncthreads();
    if((wave>>2) == hf){
      #pragma unroll
      for(int m=0;m<4;m++)
        #pragma unroll
        for(int n=0;n<2;n++){
          int col = wc + n*16 + lr;
          #pragma unroll
          for(int j=0;j<4;j++)
            epi[(m*16 + lh*4 + j)*133 + col] = acc1[m][n][j];
        }
    }
    __syncthreads();
    {
      const float* er = epi + lrow*133;
      #pragma unroll
      for(int e=0;e<16;e++) v1[e] = gelu_f(er[c0+e] + c1[n0+c0+e]);
    }
    __syncthreads();
    if((wave>>2) == hf){
      #pragma unroll
      for(int m=0;m<4;m++)
        #pragma unroll
        for(int n=0;n<2;n++){
          int col = wc + n*16 + lr;
          #pragma unroll
          for(int j=0;j<4;j++)
            epi[(m*16 + lh*4 + j)*133 + col] = acc2[m][n][j];
        }
    }
    __syncthreads();
    {
      const float* er = epi + lrow*133;
      #pragma unroll
      for(int half=0; half<2; half++){
        int cb = c0 + half*8;
        int gc = n0 + cb;
        float v[8];
        #pragma unroll
        for(int e=0;e<8;e++) v[e] = v1[half*8+e] + er[cb+e] + b2[gc+e];
        if(NRES==1){
          uint4 r = *reinterpret_cast<const uint4*>(R + grow*256 + gc);
          unsigned rw[4] = {r.x,r.y,r.z,r.w};
          #pragma unroll
          for(int q2=0;q2<4;q2++){ v[2*q2] += bflo(rw[q2]); v[2*q2+1] += bfhi(rw[q2]); }
        }
        uint4 o;
        o.x = pack2bf(v[0],v[1]); o.y = pack2bf(v[2],v[3]);
        o.z = pack2bf(v[4],v[5]); o.w = pack2bf(v[6],v[7]);
        *reinterpret_cast<uint4*>(C + grow*256 + gc) = o;
      }
    }
  }
}

// ---------------- fc3+final fused v3 (8 waves) ----------------
__global__ __launch_bounds__(512) void k_gemmF(
    const __hip_bfloat16* __restrict__ A, const __hip_bfloat16* __restrict__ BT,
    const float* __restrict__ bias, const float* __restrict__ W4,
    float* __restrict__ part){
  __shared__ __align__(1024) char smem[64*133*4];
  __shared__ float w4s[768];
  const int t = threadIdx.x, wave = t>>6, lane = t&63;
  const int MT = 512, NT = 2;
  const int b = blockIdx.x, xcd = b&7, i = b>>3;
  const int nt = i % NT, mtl = i / NT;
  const int m0 = (xcd*(MT>>3) + mtl) << 7, n0 = nt << 7;
  const int wr = (wave>>2)*64, wc = (wave&3)*32;
  const int lr = lane&15, lh = lane>>4;
  for(int l=t;l<768;l+=512) w4s[l] = W4[l];

  f32x4 acc[4][2] = {};
  for(int kt=0; kt<4; ++kt){
    __syncthreads();
    #pragma unroll
    for(int q2=0;q2<2;q2++){
      int c = (wave*2+q2)*64 + lane;
      int row = c>>3; int k8 = (c&7) ^ (row&7);
      __hip_bfloat16* la = (__hip_bfloat16*)smem + (size_t)(wave*2+q2)*512;
      __hip_bfloat16* lb = (__hip_bfloat16*)(smem + 16384) + (size_t)(wave*2+q2)*512;
      load_lds16(A  + (size_t)(m0+row)*256 + (kt*64 + k8*8), la);
      load_lds16(BT + (size_t)(n0+row)*256 + (kt*64 + k8*8), lb);
    }
    __syncthreads();
    const __hip_bfloat16* Ab = (const __hip_bfloat16*)smem;
    const __hip_bfloat16* Bb = (const __hip_bfloat16*)(smem + 16384);
    #pragma unroll
    for(int kk=0;kk<2;kk++){
      bf16x8 af[4], bfr[2];
      #pragma unroll
      for(int m=0;m<4;m++){
        int row = wr + m*16 + lr;
        int p = (kk*4 + lh) ^ (row&7);
        af[m] = *reinterpret_cast<const bf16x8*>(Ab + row*64 + p*8);
      }
      #pragma unroll
      for(int n=0;n<2;n++){
        int row = wc + n*16 + lr;
        int p = (kk*4 + lh) ^ (row&7);
        bfr[n] = *reinterpret_cast<const bf16x8*>(Bb + row*64 + p*8);
      }
      #pragma unroll
      for(int m=0;m<4;m++)
        #pragma unroll
        for(int n=0;n<2;n++)
          acc[m][n] = __builtin_amdgcn_mfma_f32_16x16x32_bf16(af[m], bfr[n], acc[m][n], 0,0,0);
    }
  }

  float* epi = (float*)smem;
  #pragma unroll
  for(int hf=0; hf<2; ++hf){
    __syncthreads();
    if((wave>>2) == hf){
      #pragma unroll
      for(int m=0;m<4;m++)
        #pragma unroll
        for(int n=0;n<2;n++){
          int col = wc + n*16 + lr;
          #pragma unroll
          for(int j=0;j<4;j++)
            epi[(m*16 + lh*4 + j)*133 + col] = acc[m][n][j];
        }
    }
    __syncthreads();
    {
      const int lrow = t>>3, c0 = (t&7)*16;
      const float* er = epi + lrow*133;
      float s0=0.f, s1=0.f, s2=0.f;
      #pragma unroll
      for(int e=0;e<16;e++){
        int gc = n0 + c0 + e;
        float v = gelu_f(er[c0+e] + bias[gc]);
        s0 += v*w4s[gc*3+0];
        s1 += v*w4s[gc*3+1];
        s2 += v*w4s[gc*3+2];
      }
      s0 += __shfl_xor(s0,1); s0 += __shfl_xor(s0,2); s0 += __shfl_xor(s0,4);
      s1 += __shfl_xor(s1,1); s1 += __shfl_xor(s1,2); s1 += __shfl_xor(s1,4);
      s2 += __shfl_xor(s2,1); s2 += __shfl_xor(s2,2); s2 += __shfl_xor(s2,4);
      if((t&7)==0){
        float* pp = part + (size_t)nt*196608 + (size_t)(m0 + hf*64 + lrow)*3;
        pp[0]=s0; pp[1]=s1; pp[2]=s2;
      }
    }
  }
}

__global__ __launch_bounds__(256) void k_combine(const float* __restrict__ part, const float* __restrict__ b4,
    const float* __restrict__ bil, float* __restrict__ out){
  int i = blockIdx.x*256 + threadIdx.x;
  int j = i - (i/3)*3;
  out[i] = part[i] + part[196608 + i] + b4[j] + bil[i];
}

// kvred (both branches): 512 blocks
__global__ __launch_bounds__(256) void k_kvredboth(const float* __restrict__ kvpart,
    float* __restrict__ kv0, float* __restrict__ kv1){
  __shared__ float sm[256];
  int br = blockIdx.x >> 8, b = blockIdx.x & 255, t = threadIdx.x;
  int d = t & 15, seg = t >> 4;
  const float* src = kvpart + (size_t)br*1024*4096;
  float s = 0.0f;
  for(int k=0;k<64;k++) s += src[(size_t)(seg*64+k)*4096 + b*16 + d];
  sm[t] = s;
  __syncthreads();
  if(t < 16){
    float r = 0.0f;
    #pragma unroll
    for(int g=0; g<16; g++) r += sm[g*16 + t];
    (br ? kv1 : kv0)[b*16 + t] = r * (1.0f/65536.0f);
  }
}

// ---------------- fold q-projection through kv (both branches) ----------------
__global__ __launch_bounds__(256) void k_foldboth(
    const __hip_bfloat16* __restrict__ qT0, const __hip_bfloat16* __restrict__ qT1,
    const float* __restrict__ biasqAll, const float* __restrict__ kv0, const float* __restrict__ kv1,
    __hip_bfloat16* __restrict__ WfoldT, float* __restrict__ bfold){
  int br = blockIdx.x >> 8, n = blockIdx.x & 255, t = threadIdx.x;
  const __hip_bfloat16* qT = br ? qT1 : qT0;
  const float* biasq = biasqAll + br*768;
  const float* kv = br ? kv1 : kv0;
  int h = n>>4, d = n&15;
  float s = 0.0f;
  #pragma unroll
  for(int c=0;c<16;c++)
    s += bf2f(qT[(size_t)(h*16+c)*256 + t]) * kv[h*256 + c*16 + d];
  WfoldT[(size_t)br*65536 + (size_t)n*256 + t] = f2bf(s);
  if(t==0){
    float b=0.0f;
    #pragma unroll
    for(int c=0;c<16;c++) b += biasq[h*16+c]*kv[h*256+c*16+d];
    bfold[br*256 + n]=b;
  }
}

// (Wfold+I)@w2 for both branches (reads WfoldT region, ADDI on diagonal)
__global__ __launch_bounds__(256) void k_smallmmI2(
    const __hip_bfloat16* __restrict__ WfoldT,
    const __hip_bfloat16* __restrict__ B0, const __hip_bfloat16* __restrict__ B1,
    __hip_bfloat16* __restrict__ C0, __hip_bfloat16* __restrict__ C1){
  __shared__ float ar[256];
  int br = blockIdx.x >> 8, i = blockIdx.x & 255, t = threadIdx.x;
  const __hip_bfloat16* A = WfoldT + (size_t)br*65536;
  const __hip_bfloat16* B = br ? B1 : B0;
  __hip_bfloat16* C = br ? C1 : C0;
  float a = bf2f(A[(size_t)i*256 + t]);
  if(t==i) a += 1.0f;
  ar[t] = a;
  __syncthreads();
  float a0=0.f,a1=0.f,a2=0.f,a3=0.f;
  for(int l=0;l<256;l+=4){
    a0 += ar[l+0]*bf2f(B[(l+0)*256 + t]);
    a1 += ar[l+1]*bf2f(B[(l+1)*256 + t]);
    a2 += ar[l+2]*bf2f(B[(l+2)*256 + t]);
    a3 += ar[l+3]*bf2f(B[(l+3)*256 + t]);
  }
  C[(size_t)i*256 + t] = f2bf((a0+a1)+(a2+a3));
}

extern "C" void kernel_launch(void* const* d_in, const int* in_sizes, int n_in,
                              void* d_out, int out_size, void* d_ws, size_t ws_size,
                              hipStream_t stream){
  (void)in_sizes; (void)n_in; (void)out_size;
  const float* inp     = (const float*)d_in[0];
  const float* coord   = (const float*)d_in[1];
  const float* cell    = (const float*)d_in[2];
  const float* enc_w   = (const float*)d_in[3];
  const float* enc_b   = (const float*)d_in[4];
  const float* freq_w  = (const float*)d_in[5];
  const float* freq_b  = (const float*)d_in[6];
  const float* out0_w1 = (const float*)d_in[7];
  const float* out0_b1 = (const float*)d_in[8];
  const float* out0_w2 = (const float*)d_in[9];
  const float* out0_b2 = (const float*)d_in[10];
  const float* out1_w1 = (const float*)d_in[11];
  const float* out1_b1 = (const float*)d_in[12];
  const float* out1_w2 = (const float*)d_in[13];
  const float* out1_b2 = (const float*)d_in[14];
  const float* fc1_w1  = (const float*)d_in[15];
  const float* fc1_b1  = (const float*)d_in[16];
  const float* fc1_w2  = (const float*)d_in[17];
  const float* fc1_b2  = (const float*)d_in[18];
  const float* fc2_w1  = (const float*)d_in[19];
  const float* fc2_b1  = (const float*)d_in[20];
  const float* fc2_w2  = (const float*)d_in[21];
  const float* fc2_b2  = (const float*)d_in[22];
  const float* qkv_w[2] = {(const float*)d_in[23], (const float*)d_in[31]};
  const float* qkv_b[2] = {(const float*)d_in[24], (const float*)d_in[32]};
  const float* kln_w[2] = {(const float*)d_in[25], (const float*)d_in[33]};
  const float* kln_b[2] = {(const float*)d_in[26], (const float*)d_in[34]};
  const float* vln_w[2] = {(const float*)d_in[27], (const float*)d_in[35]};
  const float* vln_b[2] = {(const float*)d_in[28], (const float*)d_in[36]};
  const float* proj_w[2] = {(const float*)d_in[29], (const float*)d_in[37]};
  const float* proj_b[2] = {(const float*)d_in[30], (const float*)d_in[38]};

  char* wsp = (char*)d_ws; size_t off = 0;
  auto alloc = [&](size_t bytes)->void*{ void* p = wsp + off; off += (bytes + 255) & ~(size_t)255; return p; };
  __hip_bfloat16* featP = (__hip_bfloat16*)alloc(262144ull*2);
  __hip_bfloat16* zpage = (__hip_bfloat16*)alloc(256ull*2);
  __hip_bfloat16* wtb = (__hip_bfloat16*)alloc(2097152ull*2);
  __hip_bfloat16* P = (__hip_bfloat16*)alloc(5242880ull*2);
  float* mf     = (float*)alloc(65536ull*16*4);
  int*   mi     = (int*)alloc(65536ull*8*4);
  float* bil    = (float*)alloc(65536ull*3*4);
  float* kvpart = (float*)alloc(2048ull*4096*4);
  float* kv0    = (float*)alloc(4096ull*4);
  float* kv1    = (float*)alloc(4096ull*4);
  float* biasbuf= (float*)alloc(1536ull*4);
  float* lnbuf  = (float*)alloc(2048ull*4);
  float* bfold  = (float*)alloc(512ull*4);
  float* c1     = (float*)alloc(512ull*4);
  float* bkvh   = (float*)alloc(1024ull*4);
  float* part   = (float*)alloc(2ull*196608*4);
  __hip_bfloat16* wfoldT = (__hip_bfloat16*)alloc(131072ull*2);
  __hip_bfloat16* bufA0 = (__hip_bfloat16*)alloc(65536ull*256*2);
  __hip_bfloat16* bufA1 = (__hip_bfloat16*)alloc(65536ull*256*2);
  __hip_bfloat16* bufB = (__hip_bfloat16*)alloc(65536ull*256*2);
  __hip_bfloat16* bufC = (__hip_bfloat16*)alloc(65536ull*256*2);
  if(off > ws_size) return;

  __hip_bfloat16* w2T[2]   = {wtb,          wtb + 65536};
  __hip_bfloat16* projT[2] = {wtb + 131072, wtb + 196608};
  __hip_bfloat16* fc1w1T   =  wtb + 262144;
  __hip_bfloat16* fc1w2T   =  wtb + 327680;
  __hip_bfloat16* fc2w1T   =  wtb + 393216;
  __hip_bfloat16* qT[2]    = {wtb + 458752, wtb + 655360};
  __hip_bfloat16* kvT[2]   = {wtb + 524288, wtb + 720896};
  __hip_bfloat16* wfreqT   =  wtb + 851968;   // 256 x 640
  __hip_bfloat16* wblkT    =  wtb + 1015808;  // 1280 x 256
  __hip_bfloat16* kvh2T[2] = {wtb + 1343488, wtb + 1474560};
  __hip_bfloat16* Ubuf[2]  = {wtb + 1605632, wtb + 1671168};
  __hip_bfloat16* M1T[2]   = {wtb + 1736704, wtb + 1802240};
  __hip_bfloat16* freqB = bufB;               // 4096 x 256

  k_conv1<<<1024,256,0,stream>>>(inp, enc_w, enc_b, featP);
  k_wfreq<<<256,256,0,stream>>>(freq_w, wfreqT);
  k_wblk<<<1280,256,0,stream>>>(out0_w1, out1_w1, wblkT);

  PrepArgs pa;
  pa.d[0]  = {out0_w2,   w2T[0],   0, 0};
  pa.d[1]  = {out1_w2,   w2T[1],   0, 0};
  pa.d[2]  = {proj_w[0], projT[0], 0, 0};
  pa.d[3]  = {proj_w[1], projT[1], 0, 0};
  pa.d[4]  = {fc1_w1,    fc1w1T,   0, 0};
  pa.d[5]  = {fc1_w2,    fc1w2T,   0, 0};
  pa.d[6]  = {fc2_w1,    fc2w1T,   0, 0};
  pa.d[7]  = {qkv_w[0],  qT[0],    1, 0};
  pa.d[8]  = {qkv_w[0],  kvT[0],   17, 0};
  pa.d[9]  = {qkv_w[0],  kvT[0]+65536, 33, 0};
  pa.d[10] = {qkv_w[1],  qT[1],    1, 0};
  pa.d[11] = {qkv_w[1],  kvT[1],   17, 0};
  pa.d[12] = {qkv_w[1],  kvT[1]+65536, 33, 0};
  k_prep<<<13*256,256,0,stream>>>(pa);
  k_biasperm<<<1,256,0,stream>>>(qkv_b[0], qkv_b[1],
      kln_w[0], kln_b[0], vln_w[0], vln_b[0], kln_w[1], kln_b[1], vln_w[1], vln_b[1],
      biasbuf, lnbuf, lnbuf + 1024, zpage);

  // composed kv weights (both branches), reordered
  k_smallmmR2<<<1024,256,0,stream>>>(kvT[0], kvT[1], w2T[0], w2T[1], kvh2T[0], kvh2T[1]);
  k_bkv2R2<<<4,256,0,stream>>>(out0_b2, out1_b2, biasbuf, kvT[0], kvT[1], bkvh);

  k_gfreq<<<64,256,0,stream>>>(featP, zpage, wfreqT, freq_b, freqB);
  k_gemm_mfma<0,0><<<320,512,0,stream>>>(freqB, wblkT, nullptr, nullptr,nullptr, P, 4096,1280,256, 1280);

  k_sample<<<256,256,0,stream>>>(coord, inp, mf, mi, bil);

  // both branches batched
  k_stage1both<<<4096,256,0,stream>>>(P, mf, mi, coord, cell, out0_w1, out0_b1, out1_w1, out1_b1, bufA0, bufA1);
  k_kvlnboth<<<4096,512,0,stream>>>(bufA0, bufA1, kvh2T[0], kvh2T[1], bkvh, lnbuf, lnbuf + 1024, kvpart);
  k_kvredboth<<<512,256,0,stream>>>(kvpart, kv0, kv1);
  k_foldboth<<<512,256,0,stream>>>(qT[0], qT[1], biasbuf, kv0, kv1, wfoldT, bfold);
  k_smallmmI2<<<512,256,0,stream>>>(wfoldT, w2T[0], w2T[1], Ubuf[0], Ubuf[1]);
  k_smallmm2<0><<<512,256,0,stream>>>(projT[0], projT[1], Ubuf[0], Ubuf[1], M1T[0], M1T[1]);
  k_cvec2<<<2,256,0,stream>>>(out0_b2, out1_b2, bfold, wfoldT, projT[0], projT[1], proj_b[0], proj_b[1], c1);

  k_gemm12<0><<<1024,512,0,stream>>>(bufA0, M1T[0], c1,       w2T[0], out0_b2, nullptr, bufC);
  k_gemm12<1><<<1024,512,0,stream>>>(bufA1, M1T[1], c1 + 256, w2T[1], out1_b2, bufC, bufC);

  // fc tail: bufC = f
  k_gemm_mfma<1,0><<<1024,512,0,stream>>>(bufC, fc1w1T, fc1_b1, nullptr,nullptr, bufA0, 65536,256,256, 256);
  k_gemm_mfma<1,1><<<1024,512,0,stream>>>(bufA0, fc1w2T, fc1_b2, bufC, nullptr, bufB, 65536,256,256, 256);
  k_gemmF<<<1024,512,0,stream>>>(bufB, fc2w1T, fc2_b1, fc2_w2, part);
  k_combine<<<768,256,0,stream>>>(part, fc2_b2, bil, (float*)d_out);
}

// Round 21
// 408.559 us; speedup vs baseline: 1.4686x; 1.0761x over previous
//
#include <hip/hip_runtime.h>
#include <hip/hip_bf16.h>

#define DI __device__ __forceinline__

DI float gelu_f(float x){ return 0.5f*x*(1.0f + erff(x*0.7071067811865476f)); }
DI float bf2f(__hip_bfloat16 b){ return __bfloat162float(b); }
DI __hip_bfloat16 f2bf(float f){ return __float2bfloat16(f); }
DI float bflo(unsigned u){ return __uint_as_float(u<<16); }
DI float bfhi(unsigned u){ return __uint_as_float(u & 0xffff0000u); }
DI float bfe2f(short s){ return __uint_as_float(((unsigned)(unsigned short)s)<<16); }
DI unsigned pack2bf(float a, float b){
  __hip_bfloat16 ha = f2bf(a), hb = f2bf(b);
  unsigned short ua = *reinterpret_cast<unsigned short*>(&ha);
  unsigned short ub = *reinterpret_cast<unsigned short*>(&hb);
  return (unsigned)ua | ((unsigned)ub<<16);
}

typedef __attribute__((ext_vector_type(8))) short bf16x8;
typedef __attribute__((ext_vector_type(4))) float f32x4;

template<typename T>
DI void load_lds16(const T* g, T* l){
  __builtin_amdgcn_global_load_lds((const __attribute__((address_space(1))) void*)g,
                                   (__attribute__((address_space(3))) void*)l, 16, 0, 0);
}

DI int kvmap(int j){ int h=j>>5, idx=j&31; return idx<16 ? h*16+idx : 256+h*16+(idx-16); }

// ---------------- conv1 ----------------
__global__ __launch_bounds__(256) void k_conv1(const float* __restrict__ inp, const float* __restrict__ w,
                                               const float* __restrict__ b, __hip_bfloat16* __restrict__ featP){
  int idx = blockIdx.x*256 + threadIdx.x;
  int o = idx & 63, p = idx >> 6, y = p >> 6, x = p & 63;
  float acc = b[o];
  #pragma unroll
  for(int c=0;c<3;c++){
    #pragma unroll
    for(int ky=0;ky<3;ky++){
      int yy = y+ky-1; if((unsigned)yy >= 64u) continue;
      #pragma unroll
      for(int kx=0;kx<3;kx++){
        int xx = x+kx-1; if((unsigned)xx >= 64u) continue;
        acc += inp[c*4096 + yy*64 + xx] * w[o*27 + c*9 + ky*3 + kx];
      }
    }
  }
  featP[p*64 + o] = f2bf(acc);
}

// ---------------- wfreq permute ----------------
__global__ __launch_bounds__(256) void k_wfreq(const float* __restrict__ fw, __hip_bfloat16* __restrict__ wt){
  int o = blockIdx.x, t = threadIdx.x;
  #pragma unroll
  for(int it=0; it<3; it++){
    int k = it*256 + t;
    if(k >= 640) break;
    float v = 0.0f;
    if(k < 576){
      int tap = k>>6, c = k&63;
      v = fw[o*576 + c*9 + tap];
    }
    wt[(size_t)o*640 + k] = f2bf(v);
  }
}

// ---------------- wblkT ----------------
__global__ __launch_bounds__(256) void k_wblk(const float* __restrict__ w0, const float* __restrict__ w1,
                                              __hip_bfloat16* __restrict__ wt){
  int j = blockIdx.x, kk = threadIdx.x;
  float v;
  if(j < 1024){
    int s = j>>8, n = j&255;
    v = w0[(8 + 256*s + kk)*256 + n];
  } else {
    v = w1[(2 + kk)*256 + (j-1024)];
  }
  wt[(size_t)j*256 + kk] = f2bf(v);
}

// ---------------- batched weight transpose / qkv head-permute ----------------
struct PrepDesc { const float* src; __hip_bfloat16* dst; int mode; int pad; };
struct PrepArgs { PrepDesc d[13]; };
__global__ __launch_bounds__(256) void k_prep(PrepArgs a){
  int u = blockIdx.x >> 8, b = blockIdx.x & 255, t = threadIdx.x;
  PrepDesc d = a.d[u];
  float v;
  if(d.mode == 0) v = d.src[t*256 + b];
  else { int col = 48*(b>>4) + (d.mode-1) + (b&15); v = d.src[t*768 + col]; }
  d.dst[b*256 + t] = f2bf(v);
}

// permuted qkv biases + reordered LN params + zero guard page
__global__ __launch_bounds__(256) void k_biasperm(const float* __restrict__ b0, const float* __restrict__ b1,
    const float* kw0, const float* kb0, const float* vw0, const float* vb0,
    const float* kw1, const float* kb1, const float* vw1, const float* vb1,
    float* __restrict__ dstB, float* __restrict__ lnw2, float* __restrict__ lnb2,
    __hip_bfloat16* __restrict__ zpage){
  int t = threadIdx.x;
  zpage[t] = f2bf(0.0f);
  #pragma unroll
  for(int br=0;br<2;br++){
    const float* s = br ? b1 : b0;
    #pragma unroll
    for(int part=0;part<3;part++)
      dstB[br*768 + part*256 + t] = s[48*(t>>4) + part*16 + (t&15)];
  }
  #pragma unroll
  for(int br=0;br<2;br++){
    #pragma unroll
    for(int half=0;half<2;half++){
      int j = half*256 + t;
      int h = j>>5, idx = j&31;
      bool isK = idx<16;
      int c = isK ? idx : idx-16;
      const float* w = isK ? (br?kw1:kw0) : (br?vw1:vw0);
      const float* bb= isK ? (br?kb1:kb0) : (br?vb1:vb0);
      lnw2[br*512 + j] = w[h*16+c];
      lnb2[br*512 + j] = bb[h*16+c];
    }
  }
}

// ---------------- batched small matmul pair ----------------
template<int ADDI>
__global__ __launch_bounds__(256) void k_smallmm2(
    const __hip_bfloat16* __restrict__ A0, const __hip_bfloat16* __restrict__ A1,
    const __hip_bfloat16* __restrict__ B0, const __hip_bfloat16* __restrict__ B1,
    __hip_bfloat16* __restrict__ C0, __hip_bfloat16* __restrict__ C1){
  __shared__ float ar[256];
  int br = blockIdx.x >> 8, i = blockIdx.x & 255, t = threadIdx.x;
  const __hip_bfloat16* A = br ? A1 : A0;
  const __hip_bfloat16* B = br ? B1 : B0;
  __hip_bfloat16* C = br ? C1 : C0;
  float a = bf2f(A[(size_t)i*256 + t]);
  if(ADDI && t==i) a += 1.0f;
  ar[t] = a;
  __syncthreads();
  float a0=0.f,a1=0.f,a2=0.f,a3=0.f;
  for(int l=0;l<256;l+=4){
    a0 += ar[l+0]*bf2f(B[(l+0)*256 + t]);
    a1 += ar[l+1]*bf2f(B[(l+1)*256 + t]);
    a2 += ar[l+2]*bf2f(B[(l+2)*256 + t]);
    a3 += ar[l+3]*bf2f(B[(l+3)*256 + t]);
  }
  C[(size_t)i*256 + t] = f2bf((a0+a1)+(a2+a3));
}

__global__ __launch_bounds__(256) void k_smallmmR2(
    const __hip_bfloat16* __restrict__ A0, const __hip_bfloat16* __restrict__ A1,
    const __hip_bfloat16* __restrict__ B0, const __hip_bfloat16* __restrict__ B1,
    __hip_bfloat16* __restrict__ C0, __hip_bfloat16* __restrict__ C1){
  __shared__ float ar[256];
  int br = blockIdx.x >> 9, j = blockIdx.x & 511, t = threadIdx.x;
  const __hip_bfloat16* A = br ? A1 : A0;
  const __hip_bfloat16* B = br ? B1 : B0;
  __hip_bfloat16* C = br ? C1 : C0;
  int src = kvmap(j);
  ar[t] = bf2f(A[(size_t)src*256 + t]);
  __syncthreads();
  float a0=0.f,a1=0.f,a2=0.f,a3=0.f;
  for(int l=0;l<256;l+=4){
    a0 += ar[l+0]*bf2f(B[(l+0)*256 + t]);
    a1 += ar[l+1]*bf2f(B[(l+1)*256 + t]);
    a2 += ar[l+2]*bf2f(B[(l+2)*256 + t]);
    a3 += ar[l+3]*bf2f(B[(l+3)*256 + t]);
  }
  C[(size_t)j*256 + t] = f2bf((a0+a1)+(a2+a3));
}

__global__ __launch_bounds__(256) void k_bkv2R2(const float* __restrict__ b20, const float* __restrict__ b21,
    const float* __restrict__ biaskv,
    const __hip_bfloat16* __restrict__ kvT0, const __hip_bfloat16* __restrict__ kvT1,
    float* __restrict__ outb){
  __shared__ float s_b2[256];
  int br = blockIdx.x >> 1, nb = blockIdx.x & 1, t = threadIdx.x;
  int n = nb*256 + t;
  const float* b2 = br ? b21 : b20;
  const __hip_bfloat16* kvT_ = br ? kvT1 : kvT0;
  int src = kvmap(n);
  s_b2[t] = b2[t];
  __syncthreads();
  float v = biaskv[br*768 + 256 + src];
  for(int l=0;l<256;l++) v += s_b2[l]*bf2f(kvT_[(size_t)src*256 + l]);
  outb[br*512 + n] = v;
}

// ---------------- c1 (both branches) ----------------
__global__ __launch_bounds__(256) void k_cvec2(const float* __restrict__ b20, const float* __restrict__ b21,
    const float* __restrict__ bfold,
    const __hip_bfloat16* __restrict__ WfoldT,
    const __hip_bfloat16* __restrict__ projT0, const __hip_bfloat16* __restrict__ projT1,
    const float* __restrict__ bp0, const float* __restrict__ bp1, float* __restrict__ c1){
  __shared__ float s_b2[256], s_r[256];
  int br = blockIdx.x, t = threadIdx.x;
  const float* b2 = br ? b21 : b20;
  const __hip_bfloat16* Wf = WfoldT + (size_t)br*65536;
  const __hip_bfloat16* pj = br ? projT1 : projT0;
  const float* bp = br ? bp1 : bp0;
  s_b2[t] = b2[t];
  __syncthreads();
  float r = s_b2[t] + bfold[br*256 + t];
  for(int l=0;l<256;l++) r += s_b2[l]*bf2f(Wf[(size_t)t*256 + l]);
  s_r[t] = r;
  __syncthreads();
  float c = bp[t];
  for(int l=0;l<256;l++) c += s_r[l]*bf2f(pj[(size_t)t*256 + l]);
  c1[br*256 + t] = c;
}

// ---------------- per-query sampling geometry + result_bil ----------------
__global__ __launch_bounds__(256) void k_sample(const float* __restrict__ coord, const float* __restrict__ inp,
    float* __restrict__ mf, int* __restrict__ mi, float* __restrict__ bil){
  int q = blockIdx.x*256 + threadIdx.x;
  float cy = coord[2*q], cx = coord[2*q+1];
  const float LO = (float)(-1.0 + 1e-6), HI = (float)(1.0 - 1e-6);
  const float ONEG = (float)(-1.0/64.0 + 1e-6), OPOS = (float)(1.0/64.0 + 1e-6);
  float areas[4];
  #pragma unroll
  for(int s=0;s<4;s++){
    float oy = (s<2)?ONEG:OPOS;
    float ox = (s&1)?OPOS:ONEG;
    float csy = fminf(fmaxf(cy+oy, LO), HI);
    float csx = fminf(fmaxf(cx+ox, LO), HI);
    float fy = ((csy+1.0f)*64.0f - 1.0f)*0.5f;
    float fx = ((csx+1.0f)*64.0f - 1.0f)*0.5f;
    int iy = (int)rintf(fy); iy = iy<0?0:(iy>63?63:iy);
    int ix = (int)rintf(fx); ix = ix<0?0:(ix>63?63:ix);
    float qcy = -1.0f + (float)(2*iy+1)*0.015625f;
    float qcx = -1.0f + (float)(2*ix+1)*0.015625f;
    float ry = (cy-qcy)*64.0f, rx = (cx-qcx)*64.0f;
    mf[q*16 + 4 + 2*s] = ry; mf[q*16 + 5 + 2*s] = rx;
    areas[s] = fabsf(ry*rx) + 1e-9f;
    mi[q*8 + s] = iy*64 + ix;
  }
  float tot = areas[0]+areas[1]+areas[2]+areas[3];
  #pragma unroll
  for(int s=0;s<4;s++) mf[q*16 + s] = areas[3-s] / tot;

  float fy = ((cy+1.0f)*64.0f - 1.0f)*0.5f;
  float fx = ((cx+1.0f)*64.0f - 1.0f)*0.5f;
  {
    float y0 = floorf(fy), x0 = floorf(fx);
    float wy = fy-y0, wx = fx-x0;
    int y0i = (int)y0, x0i = (int)x0;
    float cw[4] = {(1.0f-wy)*(1.0f-wx), (1.0f-wy)*wx, wy*(1.0f-wx), wy*wx};
    #pragma unroll
    for(int c2=0;c2<4;c2++){
      int yi = y0i + (c2>>1), xi = x0i + (c2&1);
      bool ok = (yi>=0 && yi<64 && xi>=0 && xi<64);
      int yc = yi<0?0:(yi>63?63:yi), xc = xi<0?0:(xi>63?63:xi);
      mf[q*16 + 12 + c2] = ok ? cw[c2] : 0.0f;
      mi[q*8 + 4 + c2] = yc*64 + xc;
    }
  }
  {
    float fyb = fminf(fmaxf(fy, 0.0f), 63.0f);
    float fxb = fminf(fmaxf(fx, 0.0f), 63.0f);
    float y0 = floorf(fyb), x0 = floorf(fxb);
    float wy = fyb-y0, wx = fxb-x0;
    int y0i = (int)y0, x0i = (int)x0;
    float cw[4] = {(1.0f-wy)*(1.0f-wx), (1.0f-wy)*wx, wy*(1.0f-wx), wy*wx};
    float a0=0,a1=0,a2=0;
    #pragma unroll
    for(int c2=0;c2<4;c2++){
      int yi = y0i + (c2>>1), xi = x0i + (c2&1);
      if(yi>=0 && yi<64 && xi>=0 && xi<64){
        int idx = yi*64+xi; float wgt = cw[c2];
        a0 += inp[idx]*wgt; a1 += inp[4096+idx]*wgt; a2 += inp[8192+idx]*wgt;
      }
    }
    bil[q*3+0]=a0; bil[q*3+1]=a1; bil[q*3+2]=a2;
  }
}

// ---------------- stage-1 MLP v2: vectorized gathers, 8 q-groups/block, padded-LDS weights ----------------
__global__ __launch_bounds__(256) void k_stage1both(const __hip_bfloat16* __restrict__ P, const float* __restrict__ mf,
    const int* __restrict__ mi, const float* __restrict__ coord, const float* __restrict__ cell,
    const float* __restrict__ W1_0, const float* __restrict__ b1_0,
    const float* __restrict__ W1_1, const float* __restrict__ b1_1,
    __hip_bfloat16* __restrict__ outA0, __hip_bfloat16* __restrict__ outA1){
  __shared__ float wsm[11*288];          // padded: idx = r*288 + c + (c>>3)  (lane addr l*9+e -> conflict-free)
  const int br = blockIdx.x >> 11;
  const int blk = blockIdx.x & 2047;
  const int t = threadIdx.x;
  {
    int c = t, cp = c + (c>>3);
    if(br==0){
      #pragma unroll
      for(int r=0;r<8;r++) wsm[r*288 + cp] = W1_0[r*256 + c];
      wsm[8*288 + cp] = W1_0[1032*256 + c];
      wsm[9*288 + cp] = W1_0[1033*256 + c];
      wsm[10*288 + cp] = b1_0[c];
    } else {
      wsm[0*288 + cp] = W1_1[0*256 + c];
      wsm[1*288 + cp] = W1_1[1*256 + c];
      wsm[2*288 + cp] = W1_1[258*256 + c];
      wsm[3*288 + cp] = W1_1[259*256 + c];
      wsm[4*288 + cp] = b1_1[c];
    }
  }
  __syncthreads();
  const int g = t>>5, l = t&31;
  __hip_bfloat16* out = br ? outA1 : outA0;
  #pragma unroll
  for(int qq=0; qq<4; ++qq){
    int q = blk*32 + g*4 + qq;
    const float* m = mf + q*16;
    const int* ii = mi + q*8;
    float acc[8];
    if(br==0){
      float cly = cell[2*q]*64.0f, clx = cell[2*q+1]*64.0f;
      #pragma unroll
      for(int e=0;e<8;e++){
        int cp = l*9 + e;
        float a = wsm[10*288 + cp];
        #pragma unroll
        for(int r=0;r<8;r++) a += m[4+r]*wsm[r*288 + cp];
        a += cly*wsm[8*288 + cp] + clx*wsm[9*288 + cp];
        acc[e] = a;
      }
      #pragma unroll
      for(int s=0;s<4;s++){
        bf16x8 pv = *reinterpret_cast<const bf16x8*>(P + (size_t)ii[s]*1280 + s*256 + l*8);
        float w = m[s];
        #pragma unroll
        for(int e=0;e<8;e++) acc[e] += w*bfe2f(pv[e]);
      }
    } else {
      float cy = coord[2*q], cx = coord[2*q+1];
      float cly = cell[2*q]*64.0f, clx = cell[2*q+1]*64.0f;
      #pragma unroll
      for(int e=0;e<8;e++){
        int cp = l*9 + e;
        acc[e] = wsm[4*288 + cp] + cy*wsm[0*288 + cp] + cx*wsm[1*288 + cp]
               + cly*wsm[2*288 + cp] + clx*wsm[3*288 + cp];
      }
      #pragma unroll
      for(int c2=0;c2<4;c2++){
        bf16x8 pv = *reinterpret_cast<const bf16x8*>(P + (size_t)ii[4+c2]*1280 + 1024 + l*8);
        float w = m[12+c2];
        #pragma unroll
        for(int e=0;e<8;e++) acc[e] += w*bfe2f(pv[e]);
      }
    }
    uint4 o;
    o.x = pack2bf(gelu_f(acc[0]), gelu_f(acc[1]));
    o.y = pack2bf(gelu_f(acc[2]), gelu_f(acc[3]));
    o.z = pack2bf(gelu_f(acc[4]), gelu_f(acc[5]));
    o.w = pack2bf(gelu_f(acc[6]), gelu_f(acc[7]));
    *reinterpret_cast<uint4*>(out + (size_t)q*256 + l*8) = o;
  }
}

// ---------------- MFMA bf16 GEMM v4: 8 waves, 34 KB LDS, half-tile epilogue ----------------
template<int ACT,int NRES>
__global__ __launch_bounds__(512) void k_gemm_mfma(
    const __hip_bfloat16* __restrict__ A, const __hip_bfloat16* __restrict__ BT,
    const float* __restrict__ bias, const __hip_bfloat16* __restrict__ R1,
    const __hip_bfloat16* __restrict__ R2, __hip_bfloat16* __restrict__ C,
    int M, int N, int K, int ldc){
  __shared__ __align__(1024) char smem[64*133*4];
  const int t = threadIdx.x, wave = t>>6, lane = t&63;
  const int MT = M>>7, NT = N>>7;
  const int b = blockIdx.x, xcd = b&7, i = b>>3;
  const int nt = i % NT, mtl = i / NT;
  const int m0 = (xcd*(MT>>3) + mtl) << 7, n0 = nt << 7;
  const int wr = (wave>>2)*64, wc = (wave&3)*32;
  const int lr = lane&15, lh = lane>>4;

  f32x4 acc[4][2] = {};
  const int ntiles = K>>6;
  for(int kt=0; kt<ntiles; ++kt){
    __syncthreads();
    #pragma unroll
    for(int q2=0;q2<2;q2++){
      int c = (wave*2+q2)*64 + lane;
      int row = c>>3; int k8 = (c&7) ^ (row&7);
      __hip_bfloat16* la = (__hip_bfloat16*)smem + (size_t)(wave*2+q2)*512;
      __hip_bfloat16* lb = (__hip_bfloat16*)(smem + 16384) + (size_t)(wave*2+q2)*512;
      load_lds16(A  + (size_t)(m0+row)*K + (kt*64 + k8*8), la);
      load_lds16(BT + (size_t)(n0+row)*K + (kt*64 + k8*8), lb);
    }
    __syncthreads();
    const __hip_bfloat16* Ab = (const __hip_bfloat16*)smem;
    const __hip_bfloat16* Bb = (const __hip_bfloat16*)(smem + 16384);
    #pragma unroll
    for(int kk=0;kk<2;kk++){
      bf16x8 af[4], bfr[2];
      #pragma unroll
      for(int m=0;m<4;m++){
        int row = wr + m*16 + lr;
        int p = (kk*4 + lh) ^ (row&7);
        af[m] = *reinterpret_cast<const bf16x8*>(Ab + row*64 + p*8);
      }
      #pragma unroll
      for(int n=0;n<2;n++){
        int row = wc + n*16 + lr;
        int p = (kk*4 + lh) ^ (row&7);
        bfr[n] = *reinterpret_cast<const bf16x8*>(Bb + row*64 + p*8);
      }
      #pragma unroll
      for(int m=0;m<4;m++)
        #pragma unroll
        for(int n=0;n<2;n++)
          acc[m][n] = __builtin_amdgcn_mfma_f32_16x16x32_bf16(af[m], bfr[n], acc[m][n], 0,0,0);
    }
  }

  float* epi = (float*)smem;
  #pragma unroll
  for(int hf=0; hf<2; ++hf){
    __syncthreads();
    if((wave>>2) == hf){
      #pragma unroll
      for(int m=0;m<4;m++)
        #pragma unroll
        for(int n=0;n<2;n++){
          int col = wc + n*16 + lr;
          #pragma unroll
          for(int j=0;j<4;j++)
            epi[(m*16 + lh*4 + j)*133 + col] = acc[m][n][j];
        }
    }
    __syncthreads();
    const int lrow = t>>3, c0 = (t&7)*16;
    const size_t grow = (size_t)(m0 + hf*64 + lrow);
    const float* er = epi + lrow*133;
    #pragma unroll
    for(int half=0; half<2; half++){
      int cb = c0 + half*8;
      int gc = n0 + cb;
      float v[8];
      #pragma unroll
      for(int e=0;e<8;e++) v[e] = er[cb+e];
      if(bias){
        #pragma unroll
        for(int e=0;e<8;e++) v[e] += bias[gc+e];
      }
      if(ACT==1){
        #pragma unroll
        for(int e=0;e<8;e++) v[e] = gelu_f(v[e]);
      }
      if(NRES==1 || NRES==2){
        uint4 r = *reinterpret_cast<const uint4*>(R1 + grow*ldc + gc);
        unsigned rw[4] = {r.x,r.y,r.z,r.w};
        #pragma unroll
        for(int q2=0;q2<4;q2++){ v[2*q2] += bflo(rw[q2]); v[2*q2+1] += bfhi(rw[q2]); }
      }
      if(NRES==2){
        uint4 r = *reinterpret_cast<const uint4*>(R2 + grow*ldc + gc);
        unsigned rw[4] = {r.x,r.y,r.z,r.w};
        #pragma unroll
        for(int q2=0;q2<4;q2++){ v[2*q2] += bflo(rw[q2]); v[2*q2+1] += bfhi(rw[q2]); }
      }
      uint4 o;
      o.x = pack2bf(v[0],v[1]); o.y = pack2bf(v[2],v[3]);
      o.z = pack2bf(v[4],v[5]); o.w = pack2bf(v[6],v[7]);
      *reinterpret_cast<uint4*>(C + grow*ldc + gc) = o;
    }
  }
}

// ---------------- freq conv GEMM (4-wave) ----------------
__global__ __launch_bounds__(256) void k_gfreq(
    const __hip_bfloat16* __restrict__ featP, const __hip_bfloat16* __restrict__ zpage,
    const __hip_bfloat16* __restrict__ BT, const float* __restrict__ bias,
    __hip_bfloat16* __restrict__ C){
  __shared__ __align__(1024) char smem[64*133*4];
  const int t = threadIdx.x, wave = t>>6, lane = t&63;
  const int MT = 32, NT = 2;
  const int b = blockIdx.x, xcd = b&7, i = b>>3;
  const int nt = i % NT, mtl = i / NT;
  const int m0 = (xcd*(MT>>3) + mtl) << 7, n0 = nt << 7;
  const int wr = (wave>>1)*64, wc = (wave&1)*64;
  const int lr = lane&15, lh = lane>>4;

  f32x4 acc[4][4] = {};
  for(int kt=0; kt<9; ++kt){
    int ky = kt/3, kx = kt - ky*3;
    __syncthreads();
    #pragma unroll
    for(int q2=0;q2<4;q2++){
      int c = (wave*4+q2)*64 + lane;
      int row = c>>3; int k8 = (c&7) ^ (row&7);
      __hip_bfloat16* la = (__hip_bfloat16*)smem + (size_t)(wave*4+q2)*512;
      __hip_bfloat16* lb = (__hip_bfloat16*)(smem + 16384) + (size_t)(wave*4+q2)*512;
      int pix = m0+row, y = pix>>6, x = pix&63;
      int yy = y+ky-1, xx = x+kx-1;
      const __hip_bfloat16* src = ((unsigned)yy<64u && (unsigned)xx<64u) ?
          (featP + (size_t)(yy*64+xx)*64 + k8*8) : (zpage + k8*8);
      load_lds16(src, la);
      load_lds16(BT + (size_t)(n0+row)*640 + (kt*64 + k8*8), lb);
    }
    __syncthreads();
    const __hip_bfloat16* Ab = (const __hip_bfloat16*)smem;
    const __hip_bfloat16* Bb = (const __hip_bfloat16*)(smem + 16384);
    #pragma unroll
    for(int kk=0;kk<2;kk++){
      bf16x8 af[4], bfr[4];
      #pragma unroll
      for(int m=0;m<4;m++){
        int row = wr + m*16 + lr;
        int p = (kk*4 + lh) ^ (row&7);
        af[m] = *reinterpret_cast<const bf16x8*>(Ab + row*64 + p*8);
      }
      #pragma unroll
      for(int n=0;n<4;n++){
        int row = wc + n*16 + lr;
        int p = (kk*4 + lh) ^ (row&7);
        bfr[n] = *reinterpret_cast<const bf16x8*>(Bb + row*64 + p*8);
      }
      #pragma unroll
      for(int m=0;m<4;m++)
        #pragma unroll
        for(int n=0;n<4;n++)
          acc[m][n] = __builtin_amdgcn_mfma_f32_16x16x32_bf16(af[m], bfr[n], acc[m][n], 0,0,0);
    }
  }

  float* epi = (float*)smem;
  const int cg = t&3;
  #pragma unroll
  for(int hf=0; hf<2; ++hf){
    __syncthreads();
    if((wave>>1) == hf){
      #pragma unroll
      for(int m=0;m<4;m++)
        #pragma unroll
        for(int n=0;n<4;n++){
          int col = wc + n*16 + lr;
          #pragma unroll
          for(int j=0;j<4;j++)
            epi[(m*16 + lh*4 + j)*133 + col] = acc[m][n][j];
        }
    }
    __syncthreads();
    const int lrow = t>>2, c0 = cg*32;
    const size_t grow = (size_t)(m0 + hf*64 + lrow);
    const float* er = epi + lrow*133;
    #pragma unroll
    for(int g0=0; g0<4; g0++){
      int g = (g0 + cg) & 3;
      int cb = c0 + g*8;
      int gc = n0 + cb;
      float v[8];
      #pragma unroll
      for(int e=0;e<8;e++) v[e] = er[cb+e] + bias[gc+e];
      uint4 o;
      o.x = pack2bf(v[0],v[1]); o.y = pack2bf(v[2],v[3]);
      o.z = pack2bf(v[4],v[5]); o.w = pack2bf(v[6],v[7]);
      *reinterpret_cast<uint4*>(C + grow*256 + gc) = o;
    }
  }
}

// ---------------- fused kv (8 waves, both branches): GEMM + LN + split-K head outer product ----------------
__global__ __launch_bounds__(512) void k_kvlnboth(
    const __hip_bfloat16* __restrict__ A0, const __hip_bfloat16* __restrict__ A1,
    const __hip_bfloat16* __restrict__ BT0, const __hip_bfloat16* __restrict__ BT1,
    const float* __restrict__ biasAll, const float* __restrict__ lnwAll, const float* __restrict__ lnbAll,
    float* __restrict__ kvpart){
  __shared__ __align__(1024) char smem[34816];
  const int t = threadIdx.x, wave = t>>6, lane = t&63;
  const int MT = 512, NT = 4;
  const int br = blockIdx.x >> 11;
  const int b = blockIdx.x & 2047, xcd = b&7, i = b>>3;
  const int nt = i % NT, mtl = i / NT;
  const int m0 = (xcd*(MT>>3) + mtl) << 7, n0 = nt << 7;
  const int wr = (wave>>2)*64, wc = (wave&3)*32;
  const int lr = lane&15, lh = lane>>4;
  const __hip_bfloat16* A = br ? A1 : A0;
  const __hip_bfloat16* BT = br ? BT1 : BT0;
  const float* bias = biasAll + br*512;
  const float* lnw = lnwAll + br*512;
  const float* lnb = lnbAll + br*512;

  f32x4 acc[4][2] = {};
  for(int kt=0; kt<4; ++kt){
    __syncthreads();
    #pragma unroll
    for(int q2=0;q2<2;q2++){
      int c = (wave*2+q2)*64 + lane;
      int row = c>>3; int k8 = (c&7) ^ (row&7);
      __hip_bfloat16* la = (__hip_bfloat16*)smem + (size_t)(wave*2+q2)*512;
      __hip_bfloat16* lb = (__hip_bfloat16*)(smem + 16384) + (size_t)(wave*2+q2)*512;
      load_lds16(A  + (size_t)(m0+row)*256 + (kt*64 + k8*8), la);
      load_lds16(BT + (size_t)(n0+row)*256 + (kt*64 + k8*8), lb);
    }
    __syncthreads();
    const __hip_bfloat16* Ab = (const __hip_bfloat16*)smem;
    const __hip_bfloat16* Bb = (const __hip_bfloat16*)(smem + 16384);
    #pragma unroll
    for(int kk=0;kk<2;kk++){
      bf16x8 af[4], bfr[2];
      #pragma unroll
      for(int m=0;m<4;m++){
        int row = wr + m*16 + lr;
        int p = (kk*4 + lh) ^ (row&7);
        af[m] = *reinterpret_cast<const bf16x8*>(Ab + row*64 + p*8);
      }
      #pragma unroll
      for(int n=0;n<2;n++){
        int row = wc + n*16 + lr;
        int p = (kk*4 + lh) ^ (row&7);
        bfr[n] = *reinterpret_cast<const bf16x8*>(Bb + row*64 + p*8);
      }
      #pragma unroll
      for(int m=0;m<4;m++)
        #pragma unroll
        for(int n=0;n<2;n++)
          acc[m][n] = __builtin_amdgcn_mfma_f32_16x16x32_bf16(af[m], bfr[n], acc[m][n], 0,0,0);
    }
  }
  __syncthreads();

  __hip_bfloat16* knT = (__hip_bfloat16*)smem;            // [4 heads][16 cols][136 rows]
  __hip_bfloat16* vnT = (__hip_bfloat16*)(smem + 17408);
  #pragma unroll
  for(int m=0;m<4;m++){
    #pragma unroll
    for(int n=0;n<2;n++){
      int cl = wc + n*16 + lr;
      int gcol = n0 + cl;
      float bs = bias[gcol];
      int h2 = cl>>5, isV = (cl>>4)&1;
      short4 pk;
      #pragma unroll
      for(int j=0;j<4;j++) ((__hip_bfloat16*)&pk)[j] = f2bf(acc[m][n][j] + bs);
      int r = wr + m*16 + lh*4;
      __hip_bfloat16* dst = (isV ? vnT : knT) + (h2*16 + lr)*136 + r;
      *reinterpret_cast<short4*>(dst) = pk;
    }
  }
  __syncthreads();
  #pragma unroll
  for(int i4=0; i4<2; ++i4){
    int task = i4*512 + t;
    int r = task & 127, hv = task >> 7;
    int h2 = hv >> 1, isV = hv & 1;
    __hip_bfloat16* base = (isV ? vnT : knT) + (h2*16)*136 + r;
    float xs[16];
    float s=0.0f, s2=0.0f;
    #pragma unroll
    for(int c=0;c<16;c++){ xs[c] = bf2f(base[c*136]); s += xs[c]; s2 += xs[c]*xs[c]; }
    float mean = s*0.0625f;
    float var = (s2 - 16.0f*mean*mean)*(1.0f/15.0f); var = var<0.0f?0.0f:var;
    float inv = 1.0f/(sqrtf(var) + 1e-5f);
    int gbase = n0 + h2*32 + isV*16;
    #pragma unroll
    for(int c=0;c<16;c++)
      base[c*136] = f2bf(lnw[gbase+c]*((xs[c]-mean)*inv) + lnb[gbase+c]);
  }
  __syncthreads();
  {
    const int hloc = wave>>1, kh = wave&1;
    f32x4 kacc = {};
    #pragma unroll
    for(int kk=0;kk<2;kk++){
      int off = kh*64 + kk*32 + lh*8;
      bf16x8 af  = *reinterpret_cast<const bf16x8*>(knT + (hloc*16 + lr)*136 + off);
      bf16x8 bf_ = *reinterpret_cast<const bf16x8*>(vnT + (hloc*16 + lr)*136 + off);
      kacc = __builtin_amdgcn_mfma_f32_16x16x32_bf16(af, bf_, kacc, 0,0,0);
    }
    const int mt = m0>>7;
    const int hglob = nt*4 + hloc;
    #pragma unroll
    for(int j=0;j<4;j++)
      kvpart[((size_t)br*1024 + (size_t)mt*2 + kh)*4096 + hglob*256 + (lh*4+j)*16 + lr] = kacc[j];
  }
}

// ---------------- G12 fused v3 (8 waves) ----------------
template<int NRES>
__global__ __launch_bounds__(512) void k_gemm12(
    const __hip_bfloat16* __restrict__ A, const __hip_bfloat16* __restrict__ B1T,
    const float* __restrict__ c1, const __hip_bfloat16* __restrict__ B2T,
    const float* __restrict__ b2, const __hip_bfloat16* __restrict__ R,
    __hip_bfloat16* __restrict__ C){
  __shared__ __align__(1024) char smem[49152];
  const int t = threadIdx.x, wave = t>>6, lane = t&63;
  const int MT = 512, NT = 2;
  const int b = blockIdx.x, xcd = b&7, i = b>>3;
  const int nt = i % NT, mtl = i / NT;
  const int m0 = (xcd*(MT>>3) + mtl) << 7, n0 = nt << 7;
  const int wr = (wave>>2)*64, wc = (wave&3)*32;
  const int lr = lane&15, lh = lane>>4;
  f32x4 acc1[4][2] = {}, acc2[4][2] = {};
  for(int k0=0;k0<256;k0+=64){
    __syncthreads();
    #pragma unroll
    for(int q2=0;q2<2;q2++){
      int c = (wave*2+q2)*64 + lane;
      int row = c>>3; int k8 = (c&7) ^ (row&7);
      __hip_bfloat16* base = (__hip_bfloat16*)smem + (size_t)(wave*2+q2)*512;
      load_lds16(A   + (size_t)(m0+row)*256 + (k0 + k8*8), base);
      load_lds16(B1T + (size_t)(n0+row)*256 + (k0 + k8*8), base + 8192);
      load_lds16(B2T + (size_t)(n0+row)*256 + (k0 + k8*8), base + 16384);
    }
    __syncthreads();
    const __hip_bfloat16* Ab = (const __hip_bfloat16*)smem;
    #pragma unroll
    for(int kk=0;kk<2;kk++){
      bf16x8 af[4], bfr[2];
      #pragma unroll
      for(int m=0;m<4;m++){
        int row = wr + m*16 + lr;
        int p = (kk*4 + lh) ^ (row&7);
        af[m] = *reinterpret_cast<const bf16x8*>(Ab + row*64 + p*8);
      }
      #pragma unroll
      for(int n=0;n<2;n++){
        int row = wc + n*16 + lr;
        int p = (kk*4 + lh) ^ (row&7);
        bfr[n] = *reinterpret_cast<const bf16x8*>(Ab + 8192 + row*64 + p*8);
      }
      #pragma unroll
      for(int m=0;m<4;m++)
        #pragma unroll
        for(int n=0;n<2;n++)
          acc1[m][n] = __builtin_amdgcn_mfma_f32_16x16x32_bf16(af[m], bfr[n], acc1[m][n], 0,0,0);
      #pragma unroll
      for(int n=0;n<2;n++){
        int row = wc + n*16 + lr;
        int p = (kk*4 + lh) ^ (row&7);
        bfr[n] = *reinterpret_cast<const bf16x8*>(Ab + 16384 + row*64 + p*8);
      }
      #pragma unroll
      for(int m=0;m<4;m++)
        #pragma unroll
        for(int n=0;n<2;n++)
          acc2[m][n] = __builtin_amdgcn_mfma_f32_16x16x32_bf16(af[m], bfr[n], acc2[m][n], 0,0,0);
    }
  }
  float* epi = (float*)smem;
  #pragma unroll
  for(int hf=0; hf<2; ++hf){
    const int lrow = t>>3, c0 = (t&7)*16;
    const size_t grow = (size_t)(m0 + hf*64 + lrow);
    float v1[16];
    __syncthreads();
    if((wave>>2) == hf){
      #pragma unroll
      for(int m=0;m<4;m++)
        #pragma unroll
        for(int n=0;n<2;n++){
          int col = wc + n*16 + lr;
          #pragma unroll
          for(int j=0;j<4;j++)
            epi[(m*16 + lh*4 + j)*133 + col] = acc1[m][n][j];
        }
    }
    __syncthreads();
    {
      const float* er = epi + lrow*133;
      #pragma unroll
      for(int e=0;e<16;e++) v1[e] = gelu_f(er[c0+e] + c1[n0+c0+e]);
    }
    __syncthreads();
    if((wave>>2) == hf){
      #pragma unroll
      for(int m=0;m<4;m++)
        #pragma unroll
        for(int n=0;n<2;n++){
          int col = wc + n*16 + lr;
          #pragma unroll
          for(int j=0;j<4;j++)
            epi[(m*16 + lh*4 + j)*133 + col] = acc2[m][n][j];
        }
    }
    __syncthreads();
    {
      const float* er = epi + lrow*133;
      #pragma unroll
      for(int half=0; half<2; half++){
        int cb = c0 + half*8;
        int gc = n0 + cb;
        float v[8];
        #pragma unroll
        for(int e=0;e<8;e++) v[e] = v1[half*8+e] + er[cb+e] + b2[gc+e];
        if(NRES==1){
          uint4 r = *reinterpret_cast<const uint4*>(R + grow*256 + gc);
          unsigned rw[4] = {r.x,r.y,r.z,r.w};
          #pragma unroll
          for(int q2=0;q2<4;q2++){ v[2*q2] += bflo(rw[q2]); v[2*q2+1] += bfhi(rw[q2]); }
        }
        uint4 o;
        o.x = pack2bf(v[0],v[1]); o.y = pack2bf(v[2],v[3]);
        o.z = pack2bf(v[4],v[5]); o.w = pack2bf(v[6],v[7]);
        *reinterpret_cast<uint4*>(C + grow*256 + gc) = o;
      }
    }
  }
}

// ---------------- fc3+final fused v3 (8 waves) ----------------
__global__ __launch_bounds__(512) void k_gemmF(
    const __hip_bfloat16* __restrict__ A, const __hip_bfloat16* __restrict__ BT,
    const float* __restrict__ bias, const float* __restrict__ W4,
    float* __restrict__ part){
  __shared__ __align__(1024) char smem[64*133*4];
  __shared__ float w4s[768];
  const int t = threadIdx.x, wave = t>>6, lane = t&63;
  const int MT = 512, NT = 2;
  const int b = blockIdx.x, xcd = b&7, i = b>>3;
  const int nt = i % NT, mtl = i / NT;
  const int m0 = (xcd*(MT>>3) + mtl) << 7, n0 = nt << 7;
  const int wr = (wave>>2)*64, wc = (wave&3)*32;
  const int lr = lane&15, lh = lane>>4;
  for(int l=t;l<768;l+=512) w4s[l] = W4[l];

  f32x4 acc[4][2] = {};
  for(int kt=0; kt<4; ++kt){
    __syncthreads();
    #pragma unroll
    for(int q2=0;q2<2;q2++){
      int c = (wave*2+q2)*64 + lane;
      int row = c>>3; int k8 = (c&7) ^ (row&7);
      __hip_bfloat16* la = (__hip_bfloat16*)smem + (size_t)(wave*2+q2)*512;
      __hip_bfloat16* lb = (__hip_bfloat16*)(smem + 16384) + (size_t)(wave*2+q2)*512;
      load_lds16(A  + (size_t)(m0+row)*256 + (kt*64 + k8*8), la);
      load_lds16(BT + (size_t)(n0+row)*256 + (kt*64 + k8*8), lb);
    }
    __syncthreads();
    const __hip_bfloat16* Ab = (const __hip_bfloat16*)smem;
    const __hip_bfloat16* Bb = (const __hip_bfloat16*)(smem + 16384);
    #pragma unroll
    for(int kk=0;kk<2;kk++){
      bf16x8 af[4], bfr[2];
      #pragma unroll
      for(int m=0;m<4;m++){
        int row = wr + m*16 + lr;
        int p = (kk*4 + lh) ^ (row&7);
        af[m] = *reinterpret_cast<const bf16x8*>(Ab + row*64 + p*8);
      }
      #pragma unroll
      for(int n=0;n<2;n++){
        int row = wc + n*16 + lr;
        int p = (kk*4 + lh) ^ (row&7);
        bfr[n] = *reinterpret_cast<const bf16x8*>(Bb + row*64 + p*8);
      }
      #pragma unroll
      for(int m=0;m<4;m++)
        #pragma unroll
        for(int n=0;n<2;n++)
          acc[m][n] = __builtin_amdgcn_mfma_f32_16x16x32_bf16(af[m], bfr[n], acc[m][n], 0,0,0);
    }
  }

  float* epi = (float*)smem;
  #pragma unroll
  for(int hf=0; hf<2; ++hf){
    __syncthreads();
    if((wave>>2) == hf){
      #pragma unroll
      for(int m=0;m<4;m++)
        #pragma unroll
        for(int n=0;n<2;n++){
          int col = wc + n*16 + lr;
          #pragma unroll
          for(int j=0;j<4;j++)
            epi[(m*16 + lh*4 + j)*133 + col] = acc[m][n][j];
        }
    }
    __syncthreads();
    {
      const int lrow = t>>3, c0 = (t&7)*16;
      const float* er = epi + lrow*133;
      float s0=0.f, s1=0.f, s2=0.f;
      #pragma unroll
      for(int e=0;e<16;e++){
        int gc = n0 + c0 + e;
        float v = gelu_f(er[c0+e] + bias[gc]);
        s0 += v*w4s[gc*3+0];
        s1 += v*w4s[gc*3+1];
        s2 += v*w4s[gc*3+2];
      }
      s0 += __shfl_xor(s0,1); s0 += __shfl_xor(s0,2); s0 += __shfl_xor(s0,4);
      s1 += __shfl_xor(s1,1); s1 += __shfl_xor(s1,2); s1 += __shfl_xor(s1,4);
      s2 += __shfl_xor(s2,1); s2 += __shfl_xor(s2,2); s2 += __shfl_xor(s2,4);
      if((t&7)==0){
        float* pp = part + (size_t)nt*196608 + (size_t)(m0 + hf*64 + lrow)*3;
        pp[0]=s0; pp[1]=s1; pp[2]=s2;
      }
    }
  }
}

__global__ __launch_bounds__(256) void k_combine(const float* __restrict__ part, const float* __restrict__ b4,
    const float* __restrict__ bil, float* __restrict__ out){
  int i = blockIdx.x*256 + threadIdx.x;
  int j = i - (i/3)*3;
  out[i] = part[i] + part[196608 + i] + b4[j] + bil[i];
}

// kvred (both branches): 512 blocks
__global__ __launch_bounds__(256) void k_kvredboth(const float* __restrict__ kvpart,
    float* __restrict__ kv0, float* __restrict__ kv1){
  __shared__ float sm[256];
  int br = blockIdx.x >> 8, b = blockIdx.x & 255, t = threadIdx.x;
  int d = t & 15, seg = t >> 4;
  const float* src = kvpart + (size_t)br*1024*4096;
  float s = 0.0f;
  for(int k=0;k<64;k++) s += src[(size_t)(seg*64+k)*4096 + b*16 + d];
  sm[t] = s;
  __syncthreads();
  if(t < 16){
    float r = 0.0f;
    #pragma unroll
    for(int g=0; g<16; g++) r += sm[g*16 + t];
    (br ? kv1 : kv0)[b*16 + t] = r * (1.0f/65536.0f);
  }
}

// ---------------- fold q-projection through kv (both branches) ----------------
__global__ __launch_bounds__(256) void k_foldboth(
    const __hip_bfloat16* __restrict__ qT0, const __hip_bfloat16* __restrict__ qT1,
    const float* __restrict__ biasqAll, const float* __restrict__ kv0, const float* __restrict__ kv1,
    __hip_bfloat16* __restrict__ WfoldT, float* __restrict__ bfold){
  int br = blockIdx.x >> 8, n = blockIdx.x & 255, t = threadIdx.x;
  const __hip_bfloat16* qT = br ? qT1 : qT0;
  const float* biasq = biasqAll + br*768;
  const float* kv = br ? kv1 : kv0;
  int h = n>>4, d = n&15;
  float s = 0.0f;
  #pragma unroll
  for(int c=0;c<16;c++)
    s += bf2f(qT[(size_t)(h*16+c)*256 + t]) * kv[h*256 + c*16 + d];
  WfoldT[(size_t)br*65536 + (size_t)n*256 + t] = f2bf(s);
  if(t==0){
    float b=0.0f;
    #pragma unroll
    for(int c=0;c<16;c++) b += biasq[h*16+c]*kv[h*256+c*16+d];
    bfold[br*256 + n]=b;
  }
}

// (Wfold+I)@w2 for both branches
__global__ __launch_bounds__(256) void k_smallmmI2(
    const __hip_bfloat16* __restrict__ WfoldT,
    const __hip_bfloat16* __restrict__ B0, const __hip_bfloat16* __restrict__ B1,
    __hip_bfloat16* __restrict__ C0, __hip_bfloat16* __restrict__ C1){
  __shared__ float ar[256];
  int br = blockIdx.x >> 8, i = blockIdx.x & 255, t = threadIdx.x;
  const __hip_bfloat16* A = WfoldT + (size_t)br*65536;
  const __hip_bfloat16* B = br ? B1 : B0;
  __hip_bfloat16* C = br ? C1 : C0;
  float a = bf2f(A[(size_t)i*256 + t]);
  if(t==i) a += 1.0f;
  ar[t] = a;
  __syncthreads();
  float a0=0.f,a1=0.f,a2=0.f,a3=0.f;
  for(int l=0;l<256;l+=4){
    a0 += ar[l+0]*bf2f(B[(l+0)*256 + t]);
    a1 += ar[l+1]*bf2f(B[(l+1)*256 + t]);
    a2 += ar[l+2]*bf2f(B[(l+2)*256 + t]);
    a3 += ar[l+3]*bf2f(B[(l+3)*256 + t]);
  }
  C[(size_t)i*256 + t] = f2bf((a0+a1)+(a2+a3));
}

extern "C" void kernel_launch(void* const* d_in, const int* in_sizes, int n_in,
                              void* d_out, int out_size, void* d_ws, size_t ws_size,
                              hipStream_t stream){
  (void)in_sizes; (void)n_in; (void)out_size;
  const float* inp     = (const float*)d_in[0];
  const float* coord   = (const float*)d_in[1];
  const float* cell    = (const float*)d_in[2];
  const float* enc_w   = (const float*)d_in[3];
  const float* enc_b   = (const float*)d_in[4];
  const float* freq_w  = (const float*)d_in[5];
  const float* freq_b  = (const float*)d_in[6];
  const float* out0_w1 = (const float*)d_in[7];
  const float* out0_b1 = (const float*)d_in[8];
  const float* out0_w2 = (const float*)d_in[9];
  const float* out0_b2 = (const float*)d_in[10];
  const float* out1_w1 = (const float*)d_in[11];
  const float* out1_b1 = (const float*)d_in[12];
  const float* out1_w2 = (const float*)d_in[13];
  const float* out1_b2 = (const float*)d_in[14];
  const float* fc1_w1  = (const float*)d_in[15];
  const float* fc1_b1  = (const float*)d_in[16];
  const float* fc1_w2  = (const float*)d_in[17];
  const float* fc1_b2  = (const float*)d_in[18];
  const float* fc2_w1  = (const float*)d_in[19];
  const float* fc2_b1  = (const float*)d_in[20];
  const float* fc2_w2  = (const float*)d_in[21];
  const float* fc2_b2  = (const float*)d_in[22];
  const float* qkv_w[2] = {(const float*)d_in[23], (const float*)d_in[31]};
  const float* qkv_b[2] = {(const float*)d_in[24], (const float*)d_in[32]};
  const float* kln_w[2] = {(const float*)d_in[25], (const float*)d_in[33]};
  const float* kln_b[2] = {(const float*)d_in[26], (const float*)d_in[34]};
  const float* vln_w[2] = {(const float*)d_in[27], (const float*)d_in[35]};
  const float* vln_b[2] = {(const float*)d_in[28], (const float*)d_in[36]};
  const float* proj_w[2] = {(const float*)d_in[29], (const float*)d_in[37]};
  const float* proj_b[2] = {(const float*)d_in[30], (const float*)d_in[38]};

  char* wsp = (char*)d_ws; size_t off = 0;
  auto alloc = [&](size_t bytes)->void*{ void* p = wsp + off; off += (bytes + 255) & ~(size_t)255; return p; };
  __hip_bfloat16* featP = (__hip_bfloat16*)alloc(262144ull*2);
  __hip_bfloat16* zpage = (__hip_bfloat16*)alloc(256ull*2);
  __hip_bfloat16* wtb = (__hip_bfloat16*)alloc(2097152ull*2);
  __hip_bfloat16* P = (__hip_bfloat16*)alloc(5242880ull*2);
  float* mf     = (float*)alloc(65536ull*16*4);
  int*   mi     = (int*)alloc(65536ull*8*4);
  float* bil    = (float*)alloc(65536ull*3*4);
  float* kvpart = (float*)alloc(2048ull*4096*4);
  float* kv0    = (float*)alloc(4096ull*4);
  float* kv1    = (float*)alloc(4096ull*4);
  float* biasbuf= (float*)alloc(1536ull*4);
  float* lnbuf  = (float*)alloc(2048ull*4);
  float* bfold  = (float*)alloc(512ull*4);
  float* c1     = (float*)alloc(512ull*4);
  float* bkvh   = (float*)alloc(1024ull*4);
  float* part   = (float*)alloc(2ull*196608*4);
  __hip_bfloat16* wfoldT = (__hip_bfloat16*)alloc(131072ull*2);
  __hip_bfloat16* bufA0 = (__hip_bfloat16*)alloc(65536ull*256*2);
  __hip_bfloat16* bufA1 = (__hip_bfloat16*)alloc(65536ull*256*2);
  __hip_bfloat16* bufB = (__hip_bfloat16*)alloc(65536ull*256*2);
  __hip_bfloat16* bufC = (__hip_bfloat16*)alloc(65536ull*256*2);
  if(off > ws_size) return;

  __hip_bfloat16* w2T[2]   = {wtb,          wtb + 65536};
  __hip_bfloat16* projT[2] = {wtb + 131072, wtb + 196608};
  __hip_bfloat16* fc1w1T   =  wtb + 262144;
  __hip_bfloat16* fc1w2T   =  wtb + 327680;
  __hip_bfloat16* fc2w1T   =  wtb + 393216;
  __hip_bfloat16* qT[2]    = {wtb + 458752, wtb + 655360};
  __hip_bfloat16* kvT[2]   = {wtb + 524288, wtb + 720896};
  __hip_bfloat16* wfreqT   =  wtb + 851968;   // 256 x 640
  __hip_bfloat16* wblkT    =  wtb + 1015808;  // 1280 x 256
  __hip_bfloat16* kvh2T[2] = {wtb + 1343488, wtb + 1474560};
  __hip_bfloat16* Ubuf[2]  = {wtb + 1605632, wtb + 1671168};
  __hip_bfloat16* M1T[2]   = {wtb + 1736704, wtb + 1802240};
  __hip_bfloat16* freqB = bufB;               // 4096 x 256

  k_conv1<<<1024,256,0,stream>>>(inp, enc_w, enc_b, featP);
  k_wfreq<<<256,256,0,stream>>>(freq_w, wfreqT);
  k_wblk<<<1280,256,0,stream>>>(out0_w1, out1_w1, wblkT);

  PrepArgs pa;
  pa.d[0]  = {out0_w2,   w2T[0],   0, 0};
  pa.d[1]  = {out1_w2,   w2T[1],   0, 0};
  pa.d[2]  = {proj_w[0], projT[0], 0, 0};
  pa.d[3]  = {proj_w[1], projT[1], 0, 0};
  pa.d[4]  = {fc1_w1,    fc1w1T,   0, 0};
  pa.d[5]  = {fc1_w2,    fc1w2T,   0, 0};
  pa.d[6]  = {fc2_w1,    fc2w1T,   0, 0};
  pa.d[7]  = {qkv_w[0],  qT[0],    1, 0};
  pa.d[8]  = {qkv_w[0],  kvT[0],   17, 0};
  pa.d[9]  = {qkv_w[0],  kvT[0]+65536, 33, 0};
  pa.d[10] = {qkv_w[1],  qT[1],    1, 0};
  pa.d[11] = {qkv_w[1],  kvT[1],   17, 0};
  pa.d[12] = {qkv_w[1],  kvT[1]+65536, 33, 0};
  k_prep<<<13*256,256,0,stream>>>(pa);
  k_biasperm<<<1,256,0,stream>>>(qkv_b[0], qkv_b[1],
      kln_w[0], kln_b[0], vln_w[0], vln_b[0], kln_w[1], kln_b[1], vln_w[1], vln_b[1],
      biasbuf, lnbuf, lnbuf + 1024, zpage);

  k_smallmmR2<<<1024,256,0,stream>>>(kvT[0], kvT[1], w2T[0], w2T[1], kvh2T[0], kvh2T[1]);
  k_bkv2R2<<<4,256,0,stream>>>(out0_b2, out1_b2, biasbuf, kvT[0], kvT[1], bkvh);

  k_gfreq<<<64,256,0,stream>>>(featP, zpage, wfreqT, freq_b, freqB);
  k_gemm_mfma<0,0><<<320,512,0,stream>>>(freqB, wblkT, nullptr, nullptr,nullptr, P, 4096,1280,256, 1280);

  k_sample<<<256,256,0,stream>>>(coord, inp, mf, mi, bil);

  k_stage1both<<<4096,256,0,stream>>>(P, mf, mi, coord, cell, out0_w1, out0_b1, out1_w1, out1_b1, bufA0, bufA1);
  k_kvlnboth<<<4096,512,0,stream>>>(bufA0, bufA1, kvh2T[0], kvh2T[1], bkvh, lnbuf, lnbuf + 1024, kvpart);
  k_kvredboth<<<512,256,0,stream>>>(kvpart, kv0, kv1);
  k_foldboth<<<512,256,0,stream>>>(qT[0], qT[1], biasbuf, kv0, kv1, wfoldT, bfold);
  k_smallmmI2<<<512,256,0,stream>>>(wfoldT, w2T[0], w2T[1], Ubuf[0], Ubuf[1]);
  k_smallmm2<0><<<512,256,0,stream>>>(projT[0], projT[1], Ubuf[0], Ubuf[1], M1T[0], M1T[1]);
  k_cvec2<<<2,256,0,stream>>>(out0_b2, out1_b2, bfold, wfoldT, projT[0], projT[1], proj_b[0], proj_b[1], c1);

  k_gemm12<0><<<1024,512,0,stream>>>(bufA0, M1T[0], c1,       w2T[0], out0_b2, nullptr, bufC);
  k_gemm12<1><<<1024,512,0,stream>>>(bufA1, M1T[1], c1 + 256, w2T[1], out1_b2, bufC, bufC);

  k_gemm_mfma<1,0><<<1024,512,0,stream>>>(bufC, fc1w1T, fc1_b1, nullptr,nullptr, bufA0, 65536,256,256, 256);
  k_gemm_mfma<1,1><<<1024,512,0,stream>>>(bufA0, fc1w2T, fc1_b2, bufC, nullptr, bufB, 65536,256,256, 256);
  k_gemmF<<<1024,512,0,stream>>>(bufB, fc2w1T, fc2_b1, fc2_w2, part);
  k_combine<<<768,256,0,stream>>>(part, fc2_b2, bil, (float*)d_out);
}